// Round 15
// baseline (266.437 us; speedup 1.0000x reference)
//
#include <hip/hip_runtime.h>
#include <math.h>

#define NWIN_TOTAL (256 * 128)
#define NTH 256
#define CDIV(a, b) (((a) + (b) - 1) / (b))

typedef _Float16 f16x8 __attribute__((ext_vector_type(8)));
typedef float f32x4 __attribute__((ext_vector_type(4)));

__device__ __forceinline__ void mma2(f16x8 a, f16x8 bh, f16x8 bl, f32x4& c) {
    c = __builtin_amdgcn_mfma_f32_16x16x32_f16(a, bl, c, 0, 0, 0);
    c = __builtin_amdgcn_mfma_f32_16x16x32_f16(a, bh, c, 0, 0, 0);
}

__device__ __forceinline__ f16x8 cvt8(const float* v) {
    f16x8 h;
#pragma unroll
    for (int e = 0; e < 8; ++e) h[e] = (_Float16)v[e];
    return h;
}

// ---------------- global std ----------------
__global__ __launch_bounds__(NTH) void k_std(const float* __restrict__ time_idx,
                                             const float* __restrict__ cut,
                                             double* __restrict__ acc) {
    int tid = threadIdx.x;
    const int n = NWIN_TOTAL * 2;
    double s = 0.0, s2 = 0.0;
    for (int i = blockIdx.x * blockDim.x + tid; i < n; i += gridDim.x * blockDim.x) {
        int j = i & 1;
        int bw = i >> 1;
        float d = fabsf(cut[bw >> 7] - time_idx[bw * 3 + j]);
        s += (double)d;
        s2 += (double)d * (double)d;
    }
    __shared__ double ls[NTH], ls2[NTH];
    ls[tid] = s; ls2[tid] = s2;
    __syncthreads();
    for (int st = NTH / 2; st > 0; st >>= 1) {
        if (tid < st) { ls[tid] += ls[tid + st]; ls2[tid] += ls2[tid + st]; }
        __syncthreads();
    }
    if (tid == 0) { atomicAdd(&acc[0], ls[0]); atomicAdd(&acc[1], ls2[0]); }
}

// ---------------- all weights -> B-fragment hi/lo planes (one launch) ----------------
struct WEnt { const float* src; _Float16* dH; _Float16* dL; int Kt, Nt, Kp, Np, off; };
struct WAll { WEnt w[9]; int grand; };

__global__ __launch_bounds__(NTH) void k_wprep_all(WAll a) {
    int idx = blockIdx.x * NTH + threadIdx.x;
    if (idx >= a.grand) return;
    int i = 0;
#pragma unroll
    for (int t = 0; t < 8; ++t)
        if (i + 1 < 9 && idx >= a.w[i + 1].off) ++i;
    const WEnt& e = a.w[i];
    int lidx = idx - e.off;
    int nks = e.Kp / 32;
    int cg = lidx / (nks * 64);
    int rem = lidx - cg * nks * 64;
    int ks = rem >> 6, lane = rem & 63;
    int col = cg * 16 + (lane & 15);
    for (int j = 0; j < 8; ++j) {
        int k = ks * 32 + ((lane >> 4) << 3) + j;
        float v = (k < e.Kt && col < e.Nt) ? e.src[(size_t)k * e.Nt + col] : 0.f;
        _Float16 h = (_Float16)v;
        float r = v - (float)h;
        e.dH[(size_t)lidx * 8 + j] = h;
        e.dL[(size_t)lidx * 8 + j] = (_Float16)r;
    }
}

// ---------------- frag helpers (swizzled: B ^= (B>>4)&7) ----------------
// A-operand hi-only fp16 everywhere (measured round 10: absmax identical to split-A;
// error floor set by fp16 storage of upd/wq, not A rounding)
template <int RG>
__device__ __forceinline__ void frag_store_hf(_Float16* AH, int r, int o,
                                              const float* v) {
    int B = ((o >> 2) * RG + (r >> 4)) * 64 + ((r & 15) | ((o & 3) << 4));
    int off = (B ^ ((B >> 4) & 7)) * 8;
    f16x8 h8;
#pragma unroll
    for (int e = 0; e < 8; ++e) h8[e] = (_Float16)v[e];
    *(f16x8*)&AH[off] = h8;
}

template <int RG>
__device__ __forceinline__ void frag_store_h(_Float16* AH, int r, int o, f16x8 v) {
    int B = ((o >> 2) * RG + (r >> 4)) * 64 + ((r & 15) | ((o & 3) << 4));
    int off = (B ^ ((B >> 4) & 7)) * 8;
    *(f16x8*)&AH[off] = v;
}

// A hi-only staged, B hi+lo: 2 MFMA per (rg,j)
template <int RG, int NREP>
__device__ __forceinline__ void mfma_step_h(const _Float16* AH,
                                            const _Float16* __restrict__ Wh,
                                            const _Float16* __restrict__ Wl,
                                            int nks, int ks, int k2, int wv, int lane,
                                            f32x4 (&acc)[RG][NREP]) {
    f16x8 ah[RG];
#pragma unroll
    for (int rg = 0; rg < RG; ++rg) {
        int B = (k2 * RG + rg) * 64 + lane;
        int off = (B ^ ((B >> 4) & 7)) * 8;
        ah[rg] = *(const f16x8*)&AH[off];
    }
#pragma unroll
    for (int j = 0; j < NREP; ++j) {
        int cg = wv * NREP + j;
        size_t boff = ((size_t)(cg * nks + ks) * 64 + lane) * 8;
        f16x8 bh = *(const f16x8*)&Wh[boff];
        f16x8 bl = *(const f16x8*)&Wl[boff];
#pragma unroll
        for (int rg = 0; rg < RG; ++rg) mma2(ah[rg], bh, bl, acc[rg][j]);
    }
}

// ---------------- K1: fused G1 + conv (dual-dir GEMM1, hi-only A) ----------------
struct GCP {
    const _Float16 *W0h, *W0l, *W1h, *W1l, *W2h, *W2l;
    const float *b0, *b1, *b2;
    _Float16* upd; int M; int win0;
    const float* edge_table; const float* node_table;
    const float* basis_freq; const float* phase;
    const float* time_idx; const float* cut;
    const int* edge_idx; const int* node_idx; const float* eid;
};

__global__ __launch_bounds__(NTH) void k_gc(GCP p) {
    __shared__ _Float16 AH[2][2048];     // phase1: double-buffer; conv: per-dir
    __shared__ _Float16 evL[32 * 184];   // ev fp16
    __shared__ _Float16 h1L[32 * 136];   // h1 fp16 row-major = direct frag
    __shared__ float ldsBF[176], ldsPH[176];
    const int tid = threadIdx.x, wv = tid >> 6, lane = tid & 63;
    const int mtile = blockIdx.x * 32;
    const int o = tid & 7, r = tid >> 3;   // r: 0..31

    if (tid < 172) { ldsBF[tid] = p.basis_freq[tid]; ldsPH[tid] = p.phase[tid]; }

    // ---- hoisted metadata + edge gathers for row mtile+r ----
    int grow = mtile + r; if (grow >= p.M) grow = p.M - 1;
    int w3 = grow / 3, l = grow - w3 * 3;
    int gw = p.win0 + w3;
    int nb = gw * 6 + 2 * l;
    const float* er = p.edge_table + (size_t)p.edge_idx[gw * 3 + l] * 172;
    const float* S0 = p.node_table + (size_t)p.node_idx[nb] * 172;
    const float* T0 = p.node_table + (size_t)p.node_idx[nb + 1] * 172;
    float dlt = p.cut[gw >> 7] - p.time_idx[gw * 3 + l];
    float g[3][8]; float eidv[3];
#pragma unroll
    for (int kc = 0; kc < 3; ++kc) {
        int k0 = kc * 64 + o * 8;
        if (k0 + 7 < 172) {
            float4 x = *(const float4*)&er[k0];
            float4 y = *(const float4*)&er[k0 + 4];
            g[kc][0]=x.x; g[kc][1]=x.y; g[kc][2]=x.z; g[kc][3]=x.w;
            g[kc][4]=y.x; g[kc][5]=y.y; g[kc][6]=y.z; g[kc][7]=y.w;
        } else if (k0 == 168) {
            float4 x = *(const float4*)&er[168];
            g[kc][0]=x.x; g[kc][1]=x.y; g[kc][2]=x.z; g[kc][3]=x.w;
            eidv[0] = p.eid[(gw * 3 + l) * 3 + 0];
            eidv[1] = p.eid[(gw * 3 + l) * 3 + 1];
            eidv[2] = p.eid[(gw * 3 + l) * 3 + 2];
        }
    }
    __syncthreads();   // ldsBF/PH ready

    // ---- Phase 1: ev = evt @ ev_W  (K=384, N=192), double-buffered, hi-only A ----
    {
        f32x4 acc[2][3];
#pragma unroll
        for (int rg = 0; rg < 2; ++rg)
#pragma unroll
            for (int j = 0; j < 3; ++j)
#pragma unroll
                for (int i = 0; i < 4; ++i) acc[rg][j][i] = 0.f;
        const int ord[6] = {3, 4, 5, 0, 1, 2};
#pragma unroll
        for (int x = 0; x < 6; ++x) {
            const int kc = ord[x];
            {
                int k0 = kc * 64 + o * 8;
                float v[8];
                if (kc >= 3 || k0 >= 176) {
#pragma unroll
                    for (int e = 0; e < 8; ++e) {
                        int k = k0 + e;
                        int q = k - 175;
                        v[e] = (k < 347) ? cosf(fmaf(dlt, ldsBF[q], ldsPH[q])) : 0.f;
                    }
                } else if (k0 + 7 < 172) {
#pragma unroll
                    for (int e = 0; e < 8; ++e) v[e] = g[kc][e];
                } else {  // k0 == 168: edge[168..171], id[0..2], time_feat[0]
                    v[0]=g[2][0]; v[1]=g[2][1]; v[2]=g[2][2]; v[3]=g[2][3];
                    v[4]=eidv[0]; v[5]=eidv[1]; v[6]=eidv[2];
                    v[7]=cosf(fmaf(dlt, ldsBF[0], ldsPH[0]));
                }
                frag_store_hf<2>(AH[x & 1], r, o, v);
            }
            __syncthreads();
#pragma unroll
            for (int k2 = 0; k2 < 2; ++k2)
                mfma_step_h<2, 3>(AH[x & 1], p.W0h, p.W0l, 12,
                                  kc * 2 + k2, k2, wv, lane, acc);
        }
        // ev -> LDS fp16 (cols 172..175 exact zeros from W pad)
#pragma unroll
        for (int j = 0; j < 3; ++j) {
            int col = (wv * 3 + j) * 16 + (lane & 15);
            if (col < 176) {
                float b = (col < 172) ? p.b0[col] : 0.f;
#pragma unroll
                for (int rg = 0; rg < 2; ++rg)
#pragma unroll
                    for (int i = 0; i < 4; ++i) {
                        int row = rg * 16 + ((lane >> 4) << 2) + i;
                        evL[row * 184 + col] = (_Float16)(acc[rg][j][i] + b);
                    }
            }
        }
    }
    __syncthreads();

    // ---- GEMM1 dual-dir: am0 = S+relu(T+ev), am1 = T+relu(S+ev); shared loads ----
    f32x4 a1[2][2][2];   // [dir][rg][j]
#pragma unroll
    for (int d = 0; d < 2; ++d)
#pragma unroll
        for (int rg = 0; rg < 2; ++rg)
#pragma unroll
            for (int j = 0; j < 2; ++j)
#pragma unroll
                for (int i = 0; i < 4; ++i) a1[d][rg][j][i] = 0.f;
    {
        float Ps[8], Pt[8];
        auto loadST = [&](int kc) {
            int k0 = kc * 64 + o * 8;
            if (k0 + 7 < 172) {
                *(float4*)&Ps[0] = *(const float4*)&S0[k0];
                *(float4*)&Ps[4] = *(const float4*)&S0[k0 + 4];
                *(float4*)&Pt[0] = *(const float4*)&T0[k0];
                *(float4*)&Pt[4] = *(const float4*)&T0[k0 + 4];
            } else if (k0 == 168) {
                *(float4*)&Ps[0] = *(const float4*)&S0[168];
                *(float4*)&Pt[0] = *(const float4*)&T0[168];
            }
        };
        loadST(0);
#pragma unroll
        for (int kc = 0; kc < 3; ++kc) {
            {
                int k0 = kc * 64 + o * 8;
                float v0[8], v1[8];
                if (k0 + 7 < 172) {
                    f16x8 e8 = *(const f16x8*)&evL[r * 184 + k0];
#pragma unroll
                    for (int e = 0; e < 8; ++e) {
                        float ev = (float)e8[e];
                        v0[e] = Ps[e] + fmaxf(Pt[e] + ev, 0.f);
                        v1[e] = Pt[e] + fmaxf(Ps[e] + ev, 0.f);
                    }
                } else if (k0 == 168) {
                    f16x8 e8 = *(const f16x8*)&evL[r * 184 + 168];
#pragma unroll
                    for (int e = 0; e < 8; ++e) {
                        if (e < 4) {
                            float ev = (float)e8[e];
                            v0[e] = Ps[e] + fmaxf(Pt[e] + ev, 0.f);
                            v1[e] = Pt[e] + fmaxf(Ps[e] + ev, 0.f);
                        } else { v0[e] = 0.f; v1[e] = 0.f; }
                    }
                } else {
#pragma unroll
                    for (int e = 0; e < 8; ++e) { v0[e] = 0.f; v1[e] = 0.f; }
                }
                frag_store_hf<2>(AH[0], r, o, v0);
                frag_store_hf<2>(AH[1], r, o, v1);
            }
            if (kc < 2) loadST(kc + 1);
            __syncthreads();
#pragma unroll
            for (int k2 = 0; k2 < 2; ++k2) {
                const int ks = kc * 2 + k2;
                f16x8 ah[2][2];
#pragma unroll
                for (int d = 0; d < 2; ++d)
#pragma unroll
                    for (int rg = 0; rg < 2; ++rg) {
                        int B = (k2 * 2 + rg) * 64 + lane;
                        int off = (B ^ ((B >> 4) & 7)) * 8;
                        ah[d][rg] = *(const f16x8*)&AH[d][off];
                    }
#pragma unroll
                for (int j = 0; j < 2; ++j) {
                    size_t boff = ((size_t)((wv * 2 + j) * 6 + ks) * 64 + lane) * 8;
                    f16x8 bh = *(const f16x8*)&p.W1h[boff];
                    f16x8 bl = *(const f16x8*)&p.W1l[boff];
#pragma unroll
                    for (int d = 0; d < 2; ++d)
#pragma unroll
                        for (int rg = 0; rg < 2; ++rg)
                            mma2(ah[d][rg], bh, bl, a1[d][rg][j]);
                }
            }
            __syncthreads();
        }
    }

    // ---- per dir: h1 -> LDS fp16, then GEMM2 (direct frag loads) ----
    for (int dir = 0; dir < 2; ++dir) {
#pragma unroll
        for (int j = 0; j < 2; ++j) {
            int col = (wv * 2 + j) * 16 + (lane & 15);
            float b = p.b1[col];
#pragma unroll
            for (int rg = 0; rg < 2; ++rg)
#pragma unroll
                for (int i = 0; i < 4; ++i) {
                    int row = rg * 16 + ((lane >> 4) << 2) + i;
                    float x = a1[dir][rg][j][i] + b;
                    h1L[row * 136 + col] = (_Float16)(x > 0.f ? x : 0.f);
                }
        }
        __syncthreads();

        f32x4 a2[2][2];
#pragma unroll
        for (int rg = 0; rg < 2; ++rg)
#pragma unroll
            for (int j = 0; j < 2; ++j)
#pragma unroll
                for (int i = 0; i < 4; ++i) a2[rg][j][i] = 0.f;
#pragma unroll
        for (int ks = 0; ks < 4; ++ks) {
            const int k0 = ks * 32 + ((lane >> 4) << 3);
            f16x8 a4[2];
#pragma unroll
            for (int rg = 0; rg < 2; ++rg)
                a4[rg] = *(const f16x8*)&h1L[(rg * 16 + (lane & 15)) * 136 + k0];
#pragma unroll
            for (int j = 0; j < 2; ++j) {
                size_t boff = ((size_t)((wv * 2 + j) * 4 + ks) * 64 + lane) * 8;
                f16x8 bh = *(const f16x8*)&p.W2h[boff];
                f16x8 bl = *(const f16x8*)&p.W2l[boff];
#pragma unroll
                for (int rg = 0; rg < 2; ++rg) mma2(a4[rg], bh, bl, a2[rg][j]);
            }
        }
#pragma unroll
        for (int j = 0; j < 2; ++j) {
            int col = (wv * 2 + j) * 16 + (lane & 15);
            float b = p.b2[col];
#pragma unroll
            for (int rg = 0; rg < 2; ++rg)
#pragma unroll
                for (int i = 0; i < 4; ++i) {
                    int row = mtile + rg * 16 + ((lane >> 4) << 2) + i;
                    if (row < p.M)
                        p.upd[(size_t)row * 256 + dir * 128 + col] = (_Float16)(a2[rg][j][i] + b);
                }
        }
        if (dir == 0) __syncthreads();   // h1L reads done before dir1 overwrite
    }
}

// ---------------- K2: fused attention + head (32 windows / block) ----------------
struct AttnP {
    const _Float16* upd;
    const _Float16 *W1h,*W1l,*W2h,*W2l,*M1h,*M1l,*M2h,*M2l,*F1h,*F1l,*F2h,*F2l;
    const float *ab1,*ab2,*am1b,*am2b,*fb1,*fb2,*fW3,*fb3;
    const float *time_idx,*cut,*cat; const double* acc;
    float* out; int nw; int win0;
};

__global__ __launch_bounds__(NTH) void k_attn(AttnP p) {
    __shared__ float R1[32 * 260];
    __shared__ _Float16 R2h[64 * 264];
    __shared__ _Float16 AH[2048];
    __shared__ float scoreL[64], aL[64], finL[32];
    float* R2f = (float*)R2h;
    const int tid = threadIdx.x, wv = tid >> 6, lane = tid & 63;
    const int w0 = blockIdx.x * 32;
    const int rr = tid >> 3, o = tid & 7;
    if (tid < 64) scoreL[tid] = 0.f;
    if (tid < 32) finL[tid] = 0.f;

    // ---- Phase A: wp = upd[w*3+2] @ at_W1 (A exact fp16, staged + prefetch) ----
    {
        int lw = w0 + rr; if (lw >= p.nw) lw = p.nw - 1;
        const _Float16* Ar = p.upd + ((size_t)lw * 3 + 2) * 256;
        f32x4 acc[2][4];
#pragma unroll
        for (int rg = 0; rg < 2; ++rg)
#pragma unroll
            for (int j = 0; j < 4; ++j)
#pragma unroll
                for (int i = 0; i < 4; ++i) acc[rg][j][i] = 0.f;
        f16x8 P = *(const f16x8*)&Ar[o * 8];
        for (int kc = 0; kc < 4; ++kc) {
            __syncthreads();
            frag_store_h<2>(AH, rr, o, P);
            if (kc < 3) P = *(const f16x8*)&Ar[(kc + 1) * 64 + o * 8];
            __syncthreads();
#pragma unroll
            for (int k2 = 0; k2 < 2; ++k2)
                mfma_step_h<2, 4>(AH, p.W1h, p.W1l, 8, kc * 2 + k2, k2, wv, lane, acc);
        }
#pragma unroll
        for (int j = 0; j < 4; ++j) {
            int col = (wv * 4 + j) * 16 + (lane & 15);
            float b = p.ab1[col];
#pragma unroll
            for (int rg = 0; rg < 2; ++rg)
#pragma unroll
                for (int i = 0; i < 4; ++i) {
                    int row = rg * 16 + ((lane >> 4) << 2) + i;
                    R1[row * 260 + col] = acc[rg][j][i] + b;
                }
        }
    }

    // ---- Phase B: wq (two 32-row subtiles) + score partials ----
    for (int st = 0; st < 2; ++st) {
        int g = st * 32 + rr;
        int lw = w0 + (g >> 1); if (lw >= p.nw) lw = p.nw - 1;
        const _Float16* Ar = p.upd + ((size_t)lw * 3 + (g & 1)) * 256;
        f32x4 acc[2][4];
#pragma unroll
        for (int rg = 0; rg < 2; ++rg)
#pragma unroll
            for (int j = 0; j < 4; ++j)
#pragma unroll
                for (int i = 0; i < 4; ++i) acc[rg][j][i] = 0.f;
        f16x8 P = *(const f16x8*)&Ar[o * 8];
        for (int kc = 0; kc < 4; ++kc) {
            __syncthreads();
            frag_store_h<2>(AH, rr, o, P);
            if (kc < 3) P = *(const f16x8*)&Ar[(kc + 1) * 64 + o * 8];
            __syncthreads();
#pragma unroll
            for (int k2 = 0; k2 < 2; ++k2)
                mfma_step_h<2, 4>(AH, p.W2h, p.W2l, 8, kc * 2 + k2, k2, wv, lane, acc);
        }
        float scp[2][4];
#pragma unroll
        for (int rg = 0; rg < 2; ++rg)
#pragma unroll
            for (int i = 0; i < 4; ++i) scp[rg][i] = 0.f;
#pragma unroll
        for (int j = 0; j < 4; ++j) {
            int col = (wv * 4 + j) * 16 + (lane & 15);
            float b = p.ab2[col];
#pragma unroll
            for (int rg = 0; rg < 2; ++rg)
#pragma unroll
                for (int i = 0; i < 4; ++i) {
                    int row = rg * 16 + ((lane >> 4) << 2) + i;
                    int gg = st * 32 + row;
                    float v = acc[rg][j][i] + b;
                    R2h[gg * 264 + col] = (_Float16)v;
                    scp[rg][i] += v * R1[(gg >> 1) * 260 + col];
                }
        }
#pragma unroll
        for (int rg = 0; rg < 2; ++rg)
#pragma unroll
            for (int i = 0; i < 4; ++i) {
                float sv = scp[rg][i];
#pragma unroll
                for (int off = 1; off < 16; off <<= 1) sv += __shfl_xor(sv, off);
                if ((lane & 15) == 0) {
                    int gg = st * 32 + rg * 16 + ((lane >> 4) << 2) + i;
                    atomicAdd(&scoreL[gg], sv);
                }
            }
    }
    __syncthreads();

    // ---- Phase C: softmax alphas + outf build ----
    if (tid < 32) {
        int lw = w0 + tid; if (lw >= p.nw) lw = p.nw - 1;
        int gw = p.win0 + lw;
        const double n = (double)(NWIN_TOTAL * 2);
        float stdv = (float)sqrt((p.acc[1] - p.acc[0] * p.acc[0] / n) / (n - 1.0));
        float cutv = p.cut[gw >> 7];
        float d0 = fabsf(cutv - p.time_idx[gw * 3 + 0]);
        float d1 = fabsf(cutv - p.time_idx[gw * 3 + 1]);
        float tw0 = expf(-d0 / (stdv + 1e-6f));
        float tw1 = expf(-d1 / (stdv + 1e-6f));
        float s0 = scoreL[tid * 2 + 0] * (0.7f + 0.3f * tw0);
        float s1 = scoreL[tid * 2 + 1] * (0.7f + 0.3f * tw1);
        float m = fmaxf(s0, s1);
        float e0 = expf(s0 - m), e1 = expf(s1 - m);
        float inv = 1.f / (e0 + e1);
        aL[tid * 2 + 0] = e0 * inv;
        aL[tid * 2 + 1] = e1 * inv;
    }
    __syncthreads();
    for (int q = tid; q < 32 * 256; q += NTH) {
        int r = q >> 8, c = q & 255;
        int lw = w0 + r; if (lw >= p.nw) lw = p.nw - 1;
        float u2 = (float)p.upd[((size_t)lw * 3 + 2) * 256 + c];
        R1[r * 260 + c] = u2 + aL[r * 2] * (float)R2h[(r * 2) * 264 + c]
                             + aL[r * 2 + 1] * (float)R2h[(r * 2 + 1) * 264 + c];
    }

    // ---- Phase D: h2 = relu(outf @ at_m1W) -> R2f[32][132], hi-only A ----
    {
        f32x4 acc[2][2];
#pragma unroll
        for (int rg = 0; rg < 2; ++rg)
#pragma unroll
            for (int j = 0; j < 2; ++j)
#pragma unroll
                for (int i = 0; i < 4; ++i) acc[rg][j][i] = 0.f;
        for (int kc = 0; kc < 4; ++kc) {
            __syncthreads();
            {
                int k0 = kc * 64 + o * 8;
                float v[8];
                float4 x = *(const float4*)&R1[rr * 260 + k0];
                float4 y = *(const float4*)&R1[rr * 260 + k0 + 4];
                v[0]=x.x; v[1]=x.y; v[2]=x.z; v[3]=x.w;
                v[4]=y.x; v[5]=y.y; v[6]=y.z; v[7]=y.w;
                frag_store_hf<2>(AH, rr, o, v);
            }
            __syncthreads();
#pragma unroll
            for (int k2 = 0; k2 < 2; ++k2)
                mfma_step_h<2, 2>(AH, p.M1h, p.M1l, 8, kc * 2 + k2, k2, wv, lane, acc);
        }
        __syncthreads();
#pragma unroll
        for (int j = 0; j < 2; ++j) {
            int col = (wv * 2 + j) * 16 + (lane & 15);
            float b = p.am1b[col];
#pragma unroll
            for (int rg = 0; rg < 2; ++rg)
#pragma unroll
                for (int i = 0; i < 4; ++i) {
                    int row = rg * 16 + ((lane >> 4) << 2) + i;
                    float x = acc[rg][j][i] + b;
                    R2f[row * 132 + col] = x > 0.f ? x : 0.f;
                }
        }
    }
    __syncthreads();

    // xz extra cols (stride 196)
    for (int q = tid; q < 32 * 68; q += NTH) {
        int r = q / 68, c = 128 + q % 68;
        int lw = w0 + r; if (lw >= p.nw) lw = p.nw - 1;
        int gw = p.win0 + lw;
        R1[r * 196 + c] = (c < 140) ? p.cat[(size_t)gw * 12 + (c - 128)] : 0.f;
    }

    // ---- Phase E: h3 = h2 @ at_m2W -> R1 stride 196 cols 0..127, hi-only A ----
    {
        f32x4 acc[2][2];
#pragma unroll
        for (int rg = 0; rg < 2; ++rg)
#pragma unroll
            for (int j = 0; j < 2; ++j)
#pragma unroll
                for (int i = 0; i < 4; ++i) acc[rg][j][i] = 0.f;
        for (int kc = 0; kc < 2; ++kc) {
            __syncthreads();
            {
                int k0 = kc * 64 + o * 8;
                float v[8];
                float4 x = *(const float4*)&R2f[rr * 132 + k0];
                float4 y = *(const float4*)&R2f[rr * 132 + k0 + 4];
                v[0]=x.x; v[1]=x.y; v[2]=x.z; v[3]=x.w;
                v[4]=y.x; v[5]=y.y; v[6]=y.z; v[7]=y.w;
                frag_store_hf<2>(AH, rr, o, v);
            }
            __syncthreads();
#pragma unroll
            for (int k2 = 0; k2 < 2; ++k2)
                mfma_step_h<2, 2>(AH, p.M2h, p.M2l, 4, kc * 2 + k2, k2, wv, lane, acc);
        }
        __syncthreads();
#pragma unroll
        for (int j = 0; j < 2; ++j) {
            int col = (wv * 2 + j) * 16 + (lane & 15);
            float b = p.am2b[col];
#pragma unroll
            for (int rg = 0; rg < 2; ++rg)
#pragma unroll
                for (int i = 0; i < 4; ++i) {
                    int row = rg * 16 + ((lane >> 4) << 2) + i;
                    R1[row * 196 + col] = acc[rg][j][i] + b;
                }
        }
    }

    // ---- Phase F: z1 = relu(xz @ f_W1) -> R2f stride 196, hi-only A ----
    {
        f32x4 acc[2][3];
#pragma unroll
        for (int rg = 0; rg < 2; ++rg)
#pragma unroll
            for (int j = 0; j < 3; ++j)
#pragma unroll
                for (int i = 0; i < 4; ++i) acc[rg][j][i] = 0.f;
        for (int kc = 0; kc < 3; ++kc) {
            __syncthreads();
            {
                int k0 = kc * 64 + o * 8;
                float v[8];
                float4 x = *(const float4*)&R1[rr * 196 + k0];
                float4 y = *(const float4*)&R1[rr * 196 + k0 + 4];
                v[0]=x.x; v[1]=x.y; v[2]=x.z; v[3]=x.w;
                v[4]=y.x; v[5]=y.y; v[6]=y.z; v[7]=y.w;
                frag_store_hf<2>(AH, rr, o, v);
            }
            __syncthreads();
#pragma unroll
            for (int k2 = 0; k2 < 2; ++k2)
                mfma_step_h<2, 3>(AH, p.F1h, p.F1l, 6, kc * 2 + k2, k2, wv, lane, acc);
        }
        __syncthreads();
#pragma unroll
        for (int j = 0; j < 3; ++j) {
            int col = (wv * 3 + j) * 16 + (lane & 15);
            float b = (col < 140) ? p.fb1[col] : 0.f;
#pragma unroll
            for (int rg = 0; rg < 2; ++rg)
#pragma unroll
                for (int i = 0; i < 4; ++i) {
                    int row = rg * 16 + ((lane >> 4) << 2) + i;
                    float x = acc[rg][j][i] + b;
                    R2f[row * 196 + col] = x > 0.f ? x : 0.f;
                }
        }
    }

    // ---- Phase G: z2 = relu(z1 @ f_W2) fused with final dot, hi-only A ----
    {
        f32x4 acc[2][2];
#pragma unroll
        for (int rg = 0; rg < 2; ++rg)
#pragma unroll
            for (int j = 0; j < 2; ++j)
#pragma unroll
                for (int i = 0; i < 4; ++i) acc[rg][j][i] = 0.f;
        for (int kc = 0; kc < 3; ++kc) {
            __syncthreads();
            {
                int k0 = kc * 64 + o * 8;
                float v[8];
                float4 x = *(const float4*)&R2f[rr * 196 + k0];
                float4 y = *(const float4*)&R2f[rr * 196 + k0 + 4];
                v[0]=x.x; v[1]=x.y; v[2]=x.z; v[3]=x.w;
                v[4]=y.x; v[5]=y.y; v[6]=y.z; v[7]=y.w;
                frag_store_hf<2>(AH, rr, o, v);
            }
            __syncthreads();
#pragma unroll
            for (int k2 = 0; k2 < 2; ++k2)
                mfma_step_h<2, 2>(AH, p.F2h, p.F2l, 6, kc * 2 + k2, k2, wv, lane, acc);
        }
        float pt[2][4];
#pragma unroll
        for (int rg = 0; rg < 2; ++rg)
#pragma unroll
            for (int i = 0; i < 4; ++i) pt[rg][i] = 0.f;
#pragma unroll
        for (int j = 0; j < 2; ++j) {
            int col = (wv * 2 + j) * 16 + (lane & 15);
            float b = p.fb2[col];
            float w3 = p.fW3[col];
#pragma unroll
            for (int rg = 0; rg < 2; ++rg)
#pragma unroll
                for (int i = 0; i < 4; ++i) {
                    float x = acc[rg][j][i] + b;
                    x = x > 0.f ? x : 0.f;
                    pt[rg][i] += x * w3;
                }
        }
#pragma unroll
        for (int rg = 0; rg < 2; ++rg)
#pragma unroll
            for (int i = 0; i < 4; ++i) {
                float sv = pt[rg][i];
#pragma unroll
                for (int off = 1; off < 16; off <<= 1) sv += __shfl_xor(sv, off);
                if ((lane & 15) == 0)
                    atomicAdd(&finL[rg * 16 + ((lane >> 4) << 2) + i], sv);
            }
    }
    __syncthreads();
    if (tid < 32 && w0 + tid < p.nw)
        p.out[p.win0 + w0 + tid] = finL[tid] + p.fb3[0];
}

extern "C" void kernel_launch(void* const* d_in, const int* in_sizes, int n_in,
                              void* d_out, int out_size, void* d_ws, size_t ws_size,
                              hipStream_t stream) {
    const float* node_table    = (const float*)d_in[0];
    const float* edge_table    = (const float*)d_in[1];
    const float* basis_freq    = (const float*)d_in[2];
    const float* phase         = (const float*)d_in[3];
    const float* ev_W          = (const float*)d_in[4];
    const float* ev_b          = (const float*)d_in[5];
    const float* ev_m1W        = (const float*)d_in[6];
    const float* ev_m1b        = (const float*)d_in[7];
    const float* ev_m2W        = (const float*)d_in[8];
    const float* ev_m2b        = (const float*)d_in[9];
    const float* at_W1         = (const float*)d_in[10];
    const float* at_b1         = (const float*)d_in[11];
    const float* at_W2         = (const float*)d_in[12];
    const float* at_b2         = (const float*)d_in[13];
    const float* at_m1W        = (const float*)d_in[14];
    const float* at_m1b        = (const float*)d_in[15];
    const float* at_m2W        = (const float*)d_in[16];
    const float* at_m2b        = (const float*)d_in[17];
    const float* f_W1          = (const float*)d_in[18];
    const float* f_b1          = (const float*)d_in[19];
    const float* f_W2          = (const float*)d_in[20];
    const float* f_b2          = (const float*)d_in[21];
    const float* f_W3          = (const float*)d_in[22];
    const float* f_b3          = (const float*)d_in[23];
    const float* time_idx      = (const float*)d_in[24];
    const float* cut_time_l    = (const float*)d_in[25];
    const float* cat_feat      = (const float*)d_in[26];
    const float* edge_identify = (const float*)d_in[27];
    const int*   node_idx      = (const int*)d_in[28];
    const int*   edge_idx      = (const int*)d_in[29];

    char* wsb = (char*)d_ws;
    double* acc = (double*)wsb;

    const int   wkp[9] = {384, 192, 128, 256, 256, 256, 128, 192, 192};
    const int   wnp[9] = {192, 128, 128, 256, 256, 128, 128, 192, 128};
    const int   wkt[9] = {347, 172, 128, 256, 256, 256, 128, 140, 140};
    const int   wnt[9] = {172, 128, 128, 256, 256, 128, 128, 140, 128};
    const float* wsrc[9] = {ev_W, ev_m1W, ev_m2W, at_W1, at_W2, at_m1W, at_m2W, f_W1, f_W2};
    _Float16* wH[9]; _Float16* wL[9];
    size_t woff = 256;
    WAll wa = {};
    int cum = 0;
    for (int i = 0; i < 9; ++i) {
        size_t plane = (size_t)wkp[i] * wnp[i];
        wH[i] = (_Float16*)(wsb + woff);
        wL[i] = wH[i] + plane;
        woff += plane * 2 * sizeof(_Float16);
        woff = (woff + 15) & ~(size_t)15;
        wa.w[i].src = wsrc[i]; wa.w[i].dH = wH[i]; wa.w[i].dL = wL[i];
        wa.w[i].Kt = wkt[i]; wa.w[i].Nt = wnt[i]; wa.w[i].Kp = wkp[i]; wa.w[i].Np = wnp[i];
        wa.w[i].off = cum;
        cum += (wnp[i] / 16) * (wkp[i] / 32) * 64;
    }
    wa.grand = cum;

    hipMemsetAsync(d_ws, 0, 16, stream);
    k_std<<<64, NTH, 0, stream>>>(time_idx, cut_time_l, acc);
    k_wprep_all<<<CDIV(wa.grand, NTH), NTH, 0, stream>>>(wa);

    // per-window footprint: upd fp16 = 768 * 2B = 1536B
    size_t avail = ws_size > woff + 4096 ? ws_size - woff - 4096 : 0;
    size_t nwc_s = avail / 1536;
    int nwc = (int)(nwc_s > NWIN_TOTAL ? NWIN_TOTAL : nwc_s);
    if (nwc < 1) nwc = 1;
    _Float16* updB = (_Float16*)(wsb + ((woff + 255) & ~(size_t)255));

    for (int c0 = 0; c0 < NWIN_TOTAL; c0 += nwc) {
        int nw = NWIN_TOTAL - c0 < nwc ? NWIN_TOTAL - c0 : nwc;
        int M3 = nw * 3;

        GCP gc = {};
        gc.W0h = wH[0]; gc.W0l = wL[0]; gc.W1h = wH[1]; gc.W1l = wL[1];
        gc.W2h = wH[2]; gc.W2l = wL[2];
        gc.b0 = ev_b; gc.b1 = ev_m1b; gc.b2 = ev_m2b;
        gc.upd = updB; gc.M = M3; gc.win0 = c0;
        gc.edge_table = edge_table; gc.node_table = node_table;
        gc.basis_freq = basis_freq; gc.phase = phase;
        gc.time_idx = time_idx; gc.cut = cut_time_l;
        gc.edge_idx = edge_idx; gc.node_idx = node_idx; gc.eid = edge_identify;
        k_gc<<<CDIV(M3, 32), NTH, 0, stream>>>(gc);

        AttnP ap = {};
        ap.upd = updB;
        ap.W1h = wH[3]; ap.W1l = wL[3]; ap.W2h = wH[4]; ap.W2l = wL[4];
        ap.M1h = wH[5]; ap.M1l = wL[5]; ap.M2h = wH[6]; ap.M2l = wL[6];
        ap.F1h = wH[7]; ap.F1l = wL[7]; ap.F2h = wH[8]; ap.F2l = wL[8];
        ap.ab1 = at_b1; ap.ab2 = at_b2; ap.am1b = at_m1b; ap.am2b = at_m2b;
        ap.fb1 = f_b1; ap.fb2 = f_b2; ap.fW3 = f_W3; ap.fb3 = f_b3;
        ap.time_idx = time_idx; ap.cut = cut_time_l; ap.cat = cat_feat; ap.acc = acc;
        ap.out = (float*)d_out; ap.nw = nw; ap.win0 = c0;
        k_attn<<<CDIV(nw, 32), NTH, 0, stream>>>(ap);
    }
}

// Round 16
// 257.087 us; speedup vs baseline: 1.0364x; 1.0364x over previous
//
#include <hip/hip_runtime.h>
#include <math.h>

#define NWIN_TOTAL (256 * 128)
#define NTH 256
#define CDIV(a, b) (((a) + (b) - 1) / (b))

typedef _Float16 f16x8 __attribute__((ext_vector_type(8)));
typedef float f32x4 __attribute__((ext_vector_type(4)));

__device__ __forceinline__ void mma2(f16x8 a, f16x8 bh, f16x8 bl, f32x4& c) {
    c = __builtin_amdgcn_mfma_f32_16x16x32_f16(a, bl, c, 0, 0, 0);
    c = __builtin_amdgcn_mfma_f32_16x16x32_f16(a, bh, c, 0, 0, 0);
}

__device__ __forceinline__ void mma3(f16x8 ah, f16x8 al, f16x8 bh, f16x8 bl, f32x4& c) {
    c = __builtin_amdgcn_mfma_f32_16x16x32_f16(al, bh, c, 0, 0, 0);
    c = __builtin_amdgcn_mfma_f32_16x16x32_f16(ah, bl, c, 0, 0, 0);
    c = __builtin_amdgcn_mfma_f32_16x16x32_f16(ah, bh, c, 0, 0, 0);
}

// ---------------- global std ----------------
__global__ __launch_bounds__(NTH) void k_std(const float* __restrict__ time_idx,
                                             const float* __restrict__ cut,
                                             double* __restrict__ acc) {
    int tid = threadIdx.x;
    const int n = NWIN_TOTAL * 2;
    double s = 0.0, s2 = 0.0;
    for (int i = blockIdx.x * blockDim.x + tid; i < n; i += gridDim.x * blockDim.x) {
        int j = i & 1;
        int bw = i >> 1;
        float d = fabsf(cut[bw >> 7] - time_idx[bw * 3 + j]);
        s += (double)d;
        s2 += (double)d * (double)d;
    }
    __shared__ double ls[NTH], ls2[NTH];
    ls[tid] = s; ls2[tid] = s2;
    __syncthreads();
    for (int st = NTH / 2; st > 0; st >>= 1) {
        if (tid < st) { ls[tid] += ls[tid + st]; ls2[tid] += ls2[tid + st]; }
        __syncthreads();
    }
    if (tid == 0) { atomicAdd(&acc[0], ls[0]); atomicAdd(&acc[1], ls2[0]); }
}

// ---------------- all weights -> B-fragment hi/lo planes (one launch) ----------------
struct WEnt { const float* src; _Float16* dH; _Float16* dL; int Kt, Nt, Kp, Np, off; };
struct WAll { WEnt w[9]; int grand; };

__global__ __launch_bounds__(NTH) void k_wprep_all(WAll a) {
    int idx = blockIdx.x * NTH + threadIdx.x;
    if (idx >= a.grand) return;
    int i = 0;
#pragma unroll
    for (int t = 0; t < 8; ++t)
        if (i + 1 < 9 && idx >= a.w[i + 1].off) ++i;
    const WEnt& e = a.w[i];
    int lidx = idx - e.off;
    int nks = e.Kp / 32;
    int cg = lidx / (nks * 64);
    int rem = lidx - cg * nks * 64;
    int ks = rem >> 6, lane = rem & 63;
    int col = cg * 16 + (lane & 15);
    for (int j = 0; j < 8; ++j) {
        int k = ks * 32 + ((lane >> 4) << 3) + j;
        float v = (k < e.Kt && col < e.Nt) ? e.src[(size_t)k * e.Nt + col] : 0.f;
        _Float16 h = (_Float16)v;
        float r = v - (float)h;
        e.dH[(size_t)lidx * 8 + j] = h;
        e.dL[(size_t)lidx * 8 + j] = (_Float16)r;
    }
}

// ---------------- frag helpers (swizzled: B ^= (B>>4)&7) ----------------
template <int RG>
__device__ __forceinline__ void frag_store(_Float16* AH, _Float16* AL, int r, int o,
                                           const float* v) {
    int B = ((o >> 2) * RG + (r >> 4)) * 64 + ((r & 15) | ((o & 3) << 4));
    int off = (B ^ ((B >> 4) & 7)) * 8;
    f16x8 h8, l8;
#pragma unroll
    for (int e = 0; e < 8; ++e) {
        _Float16 h = (_Float16)v[e];
        h8[e] = h;
        l8[e] = (_Float16)(v[e] - (float)h);
    }
    *(f16x8*)&AH[off] = h8;
    *(f16x8*)&AL[off] = l8;
}

template <int RG>
__device__ __forceinline__ void frag_store_h(_Float16* AH, int r, int o, f16x8 v) {
    int B = ((o >> 2) * RG + (r >> 4)) * 64 + ((r & 15) | ((o & 3) << 4));
    int off = (B ^ ((B >> 4) & 7)) * 8;
    *(f16x8*)&AH[off] = v;
}

template <int RG, int NREP>
__device__ __forceinline__ void mfma_step(const _Float16* AH, const _Float16* AL,
                                          const _Float16* __restrict__ Wh,
                                          const _Float16* __restrict__ Wl,
                                          int nks, int ks, int k2, int wv, int lane,
                                          f32x4 (&acc)[RG][NREP]) {
    f16x8 ah[RG], al[RG];
#pragma unroll
    for (int rg = 0; rg < RG; ++rg) {
        int B = (k2 * RG + rg) * 64 + lane;
        int off = (B ^ ((B >> 4) & 7)) * 8;
        ah[rg] = *(const f16x8*)&AH[off];
        al[rg] = *(const f16x8*)&AL[off];
    }
#pragma unroll
    for (int j = 0; j < NREP; ++j) {
        int cg = wv * NREP + j;
        size_t boff = ((size_t)(cg * nks + ks) * 64 + lane) * 8;
        f16x8 bh = *(const f16x8*)&Wh[boff];
        f16x8 bl = *(const f16x8*)&Wl[boff];
#pragma unroll
        for (int rg = 0; rg < RG; ++rg) mma3(ah[rg], al[rg], bh, bl, acc[rg][j]);
    }
}

// A exact fp16 staged (no lo): 2 MFMA per (rg,j)
template <int RG, int NREP>
__device__ __forceinline__ void mfma_step_h(const _Float16* AH,
                                            const _Float16* __restrict__ Wh,
                                            const _Float16* __restrict__ Wl,
                                            int nks, int ks, int k2, int wv, int lane,
                                            f32x4 (&acc)[RG][NREP]) {
    f16x8 ah[RG];
#pragma unroll
    for (int rg = 0; rg < RG; ++rg) {
        int B = (k2 * RG + rg) * 64 + lane;
        int off = (B ^ ((B >> 4) & 7)) * 8;
        ah[rg] = *(const f16x8*)&AH[off];
    }
#pragma unroll
    for (int j = 0; j < NREP; ++j) {
        int cg = wv * NREP + j;
        size_t boff = ((size_t)(cg * nks + ks) * 64 + lane) * 8;
        f16x8 bh = *(const f16x8*)&Wh[boff];
        f16x8 bl = *(const f16x8*)&Wl[boff];
#pragma unroll
        for (int rg = 0; rg < RG; ++rg) mma2(ah[rg], bh, bl, acc[rg][j]);
    }
}

// ---------------- K1: fused G1 + conv (dual-dir GEMM1, shared loads) ----------------
struct GCP {
    const _Float16 *W0h, *W0l, *W1h, *W1l, *W2h, *W2l;
    const float *b0, *b1, *b2;
    _Float16* upd; int M; int win0;
    const float* edge_table; const float* node_table;
    const float* basis_freq; const float* phase;
    const float* time_idx; const float* cut;
    const int* edge_idx; const int* node_idx; const float* eid;
};

__global__ __launch_bounds__(NTH) void k_gc(GCP p) {
    __shared__ _Float16 AH[2][2048], AL[2][2048];   // phase1: double-buffer; conv: per-dir
    __shared__ _Float16 evL[32 * 184];               // ev fp16
    __shared__ _Float16 h1L[32 * 136];               // h1 fp16 row-major = direct frag
    __shared__ float ldsBF[176], ldsPH[176];
    const int tid = threadIdx.x, wv = tid >> 6, lane = tid & 63;
    const int mtile = blockIdx.x * 32;
    const int o = tid & 7, r = tid >> 3;   // r: 0..31

    if (tid < 172) { ldsBF[tid] = p.basis_freq[tid]; ldsPH[tid] = p.phase[tid]; }

    int grow = mtile + r; if (grow >= p.M) grow = p.M - 1;
    int w3 = grow / 3, l = grow - w3 * 3;
    int gw = p.win0 + w3;
    int nb = gw * 6 + 2 * l;
    const float* er = p.edge_table + (size_t)p.edge_idx[gw * 3 + l] * 172;
    const float* S0 = p.node_table + (size_t)p.node_idx[nb] * 172;
    const float* T0 = p.node_table + (size_t)p.node_idx[nb + 1] * 172;
    float dlt = p.cut[gw >> 7] - p.time_idx[gw * 3 + l];
    float g[3][8]; float eidv[3];
#pragma unroll
    for (int kc = 0; kc < 3; ++kc) {
        int k0 = kc * 64 + o * 8;
        if (k0 + 7 < 172) {
            float4 x = *(const float4*)&er[k0];
            float4 y = *(const float4*)&er[k0 + 4];
            g[kc][0]=x.x; g[kc][1]=x.y; g[kc][2]=x.z; g[kc][3]=x.w;
            g[kc][4]=y.x; g[kc][5]=y.y; g[kc][6]=y.z; g[kc][7]=y.w;
        } else if (k0 == 168) {
            float4 x = *(const float4*)&er[168];
            g[kc][0]=x.x; g[kc][1]=x.y; g[kc][2]=x.z; g[kc][3]=x.w;
            eidv[0] = p.eid[(gw * 3 + l) * 3 + 0];
            eidv[1] = p.eid[(gw * 3 + l) * 3 + 1];
            eidv[2] = p.eid[(gw * 3 + l) * 3 + 2];
        }
    }
    __syncthreads();   // ldsBF/PH ready

    // ---- Phase 1: ev = evt @ ev_W  (K=384, N=192), double-buffered ----
    {
        f32x4 acc[2][3];
#pragma unroll
        for (int rg = 0; rg < 2; ++rg)
#pragma unroll
            for (int j = 0; j < 3; ++j)
#pragma unroll
                for (int i = 0; i < 4; ++i) acc[rg][j][i] = 0.f;
        const int ord[6] = {3, 4, 5, 0, 1, 2};
#pragma unroll
        for (int x = 0; x < 6; ++x) {
            const int kc = ord[x];
            {
                int k0 = kc * 64 + o * 8;
                float v[8];
                if (kc >= 3 || k0 >= 176) {
#pragma unroll
                    for (int e = 0; e < 8; ++e) {
                        int k = k0 + e;
                        int q = k - 175;
                        v[e] = (k < 347) ? cosf(fmaf(dlt, ldsBF[q], ldsPH[q])) : 0.f;
                    }
                } else if (k0 + 7 < 172) {
#pragma unroll
                    for (int e = 0; e < 8; ++e) v[e] = g[kc][e];
                } else {  // k0 == 168: edge[168..171], id[0..2], time_feat[0]
                    v[0]=g[2][0]; v[1]=g[2][1]; v[2]=g[2][2]; v[3]=g[2][3];
                    v[4]=eidv[0]; v[5]=eidv[1]; v[6]=eidv[2];
                    v[7]=cosf(fmaf(dlt, ldsBF[0], ldsPH[0]));
                }
                frag_store<2>(AH[x & 1], AL[x & 1], r, o, v);
            }
            __syncthreads();
#pragma unroll
            for (int k2 = 0; k2 < 2; ++k2)
                mfma_step<2, 3>(AH[x & 1], AL[x & 1], p.W0h, p.W0l, 12,
                                kc * 2 + k2, k2, wv, lane, acc);
        }
#pragma unroll
        for (int j = 0; j < 3; ++j) {
            int col = (wv * 3 + j) * 16 + (lane & 15);
            if (col < 176) {
                float b = (col < 172) ? p.b0[col] : 0.f;
#pragma unroll
                for (int rg = 0; rg < 2; ++rg)
#pragma unroll
                    for (int i = 0; i < 4; ++i) {
                        int row = rg * 16 + ((lane >> 4) << 2) + i;
                        evL[row * 184 + col] = (_Float16)(acc[rg][j][i] + b);
                    }
            }
        }
    }
    __syncthreads();

    // ---- GEMM1 dual-dir: am0 = S+relu(T+ev), am1 = T+relu(S+ev) ----
    f32x4 a1[2][2][2];   // [dir][rg][j]
#pragma unroll
    for (int d = 0; d < 2; ++d)
#pragma unroll
        for (int rg = 0; rg < 2; ++rg)
#pragma unroll
            for (int j = 0; j < 2; ++j)
#pragma unroll
                for (int i = 0; i < 4; ++i) a1[d][rg][j][i] = 0.f;
    {
        float Ps[8], Pt[8];
        auto loadST = [&](int kc) {
            int k0 = kc * 64 + o * 8;
            if (k0 + 7 < 172) {
                *(float4*)&Ps[0] = *(const float4*)&S0[k0];
                *(float4*)&Ps[4] = *(const float4*)&S0[k0 + 4];
                *(float4*)&Pt[0] = *(const float4*)&T0[k0];
                *(float4*)&Pt[4] = *(const float4*)&T0[k0 + 4];
            } else if (k0 == 168) {
                *(float4*)&Ps[0] = *(const float4*)&S0[168];
                *(float4*)&Pt[0] = *(const float4*)&T0[168];
            }
        };
        loadST(0);
#pragma unroll
        for (int kc = 0; kc < 3; ++kc) {
            {
                int k0 = kc * 64 + o * 8;
                float v0[8], v1[8];
                if (k0 + 7 < 172) {
                    f16x8 e8 = *(const f16x8*)&evL[r * 184 + k0];
#pragma unroll
                    for (int e = 0; e < 8; ++e) {
                        float ev = (float)e8[e];
                        v0[e] = Ps[e] + fmaxf(Pt[e] + ev, 0.f);
                        v1[e] = Pt[e] + fmaxf(Ps[e] + ev, 0.f);
                    }
                } else if (k0 == 168) {
                    f16x8 e8 = *(const f16x8*)&evL[r * 184 + 168];
#pragma unroll
                    for (int e = 0; e < 8; ++e) {
                        if (e < 4) {
                            float ev = (float)e8[e];
                            v0[e] = Ps[e] + fmaxf(Pt[e] + ev, 0.f);
                            v1[e] = Pt[e] + fmaxf(Ps[e] + ev, 0.f);
                        } else { v0[e] = 0.f; v1[e] = 0.f; }
                    }
                } else {
#pragma unroll
                    for (int e = 0; e < 8; ++e) { v0[e] = 0.f; v1[e] = 0.f; }
                }
                frag_store<2>(AH[0], AL[0], r, o, v0);
                frag_store<2>(AH[1], AL[1], r, o, v1);
            }
            if (kc < 2) loadST(kc + 1);
            __syncthreads();
#pragma unroll
            for (int k2 = 0; k2 < 2; ++k2) {
                const int ks = kc * 2 + k2;
                f16x8 ah[2][2], al[2][2];
#pragma unroll
                for (int d = 0; d < 2; ++d)
#pragma unroll
                    for (int rg = 0; rg < 2; ++rg) {
                        int B = (k2 * 2 + rg) * 64 + lane;
                        int off = (B ^ ((B >> 4) & 7)) * 8;
                        ah[d][rg] = *(const f16x8*)&AH[d][off];
                        al[d][rg] = *(const f16x8*)&AL[d][off];
                    }
#pragma unroll
                for (int j = 0; j < 2; ++j) {
                    size_t boff = ((size_t)((wv * 2 + j) * 6 + ks) * 64 + lane) * 8;
                    f16x8 bh = *(const f16x8*)&p.W1h[boff];
                    f16x8 bl = *(const f16x8*)&p.W1l[boff];
#pragma unroll
                    for (int d = 0; d < 2; ++d)
#pragma unroll
                        for (int rg = 0; rg < 2; ++rg)
                            mma3(ah[d][rg], al[d][rg], bh, bl, a1[d][rg][j]);
                }
            }
            __syncthreads();
        }
    }

    // ---- per dir: h1 -> LDS fp16, then GEMM2 (direct frag loads) ----
    for (int dir = 0; dir < 2; ++dir) {
#pragma unroll
        for (int j = 0; j < 2; ++j) {
            int col = (wv * 2 + j) * 16 + (lane & 15);
            float b = p.b1[col];
#pragma unroll
            for (int rg = 0; rg < 2; ++rg)
#pragma unroll
                for (int i = 0; i < 4; ++i) {
                    int row = rg * 16 + ((lane >> 4) << 2) + i;
                    float x = a1[dir][rg][j][i] + b;
                    h1L[row * 136 + col] = (_Float16)(x > 0.f ? x : 0.f);
                }
        }
        __syncthreads();

        f32x4 a2[2][2];
#pragma unroll
        for (int rg = 0; rg < 2; ++rg)
#pragma unroll
            for (int j = 0; j < 2; ++j)
#pragma unroll
                for (int i = 0; i < 4; ++i) a2[rg][j][i] = 0.f;
#pragma unroll
        for (int ks = 0; ks < 4; ++ks) {
            const int k0 = ks * 32 + ((lane >> 4) << 3);
            f16x8 a4[2];
#pragma unroll
            for (int rg = 0; rg < 2; ++rg)
                a4[rg] = *(const f16x8*)&h1L[(rg * 16 + (lane & 15)) * 136 + k0];
#pragma unroll
            for (int j = 0; j < 2; ++j) {
                size_t boff = ((size_t)((wv * 2 + j) * 4 + ks) * 64 + lane) * 8;
                f16x8 bh = *(const f16x8*)&p.W2h[boff];
                f16x8 bl = *(const f16x8*)&p.W2l[boff];
#pragma unroll
                for (int rg = 0; rg < 2; ++rg) mma2(a4[rg], bh, bl, a2[rg][j]);
            }
        }
#pragma unroll
        for (int j = 0; j < 2; ++j) {
            int col = (wv * 2 + j) * 16 + (lane & 15);
            float b = p.b2[col];
#pragma unroll
            for (int rg = 0; rg < 2; ++rg)
#pragma unroll
                for (int i = 0; i < 4; ++i) {
                    int row = mtile + rg * 16 + ((lane >> 4) << 2) + i;
                    if (row < p.M)
                        p.upd[(size_t)row * 256 + dir * 128 + col] = (_Float16)(a2[rg][j][i] + b);
                }
        }
        if (dir == 0) __syncthreads();
    }
}

// ---------------- K2: fused attention + head (32 windows / block) ----------------
struct AttnP {
    const _Float16* upd;
    const _Float16 *W1h,*W1l,*W2h,*W2l,*M1h,*M1l,*M2h,*M2l,*F1h,*F1l,*F2h,*F2l;
    const float *ab1,*ab2,*am1b,*am2b,*fb1,*fb2,*fW3,*fb3;
    const float *time_idx,*cut,*cat; const double* acc;
    float* out; int nw; int win0;
};

__global__ __launch_bounds__(NTH) void k_attn(AttnP p) {
    __shared__ float R1[32 * 260];
    __shared__ _Float16 R2h[64 * 264];
    __shared__ _Float16 AH2[2][2048];   // A/B double-buffer (exact fp16 A)
    __shared__ _Float16 AL[2048];       // lo plane for D-G (aliased use of AH2[0] as hi)
    __shared__ float scoreL[64], aL[64], finL[32];
    float* R2f = (float*)R2h;
    const int tid = threadIdx.x, wv = tid >> 6, lane = tid & 63;
    const int w0 = blockIdx.x * 32;
    const int rr = tid >> 3, o = tid & 7;
    if (tid < 64) scoreL[tid] = 0.f;
    if (tid < 32) finL[tid] = 0.f;
    __syncthreads();

    // ---- Phase A: wp = upd[w*3+2] @ at_W1 (double-buffered, 1 barrier/kc) ----
    {
        int lw = w0 + rr; if (lw >= p.nw) lw = p.nw - 1;
        const _Float16* Ar = p.upd + ((size_t)lw * 3 + 2) * 256;
        f32x4 acc[2][4];
#pragma unroll
        for (int rg = 0; rg < 2; ++rg)
#pragma unroll
            for (int j = 0; j < 4; ++j)
#pragma unroll
                for (int i = 0; i < 4; ++i) acc[rg][j][i] = 0.f;
        f16x8 P = *(const f16x8*)&Ar[o * 8];
#pragma unroll
        for (int kc = 0; kc < 4; ++kc) {
            frag_store_h<2>(AH2[kc & 1], rr, o, P);
            if (kc < 3) P = *(const f16x8*)&Ar[(kc + 1) * 64 + o * 8];
            __syncthreads();
#pragma unroll
            for (int k2 = 0; k2 < 2; ++k2)
                mfma_step_h<2, 4>(AH2[kc & 1], p.W1h, p.W1l, 8, kc * 2 + k2, k2, wv, lane, acc);
        }
#pragma unroll
        for (int j = 0; j < 4; ++j) {
            int col = (wv * 4 + j) * 16 + (lane & 15);
            float b = p.ab1[col];
#pragma unroll
            for (int rg = 0; rg < 2; ++rg)
#pragma unroll
                for (int i = 0; i < 4; ++i) {
                    int row = rg * 16 + ((lane >> 4) << 2) + i;
                    R1[row * 260 + col] = acc[rg][j][i] + b;
                }
        }
    }

    // ---- Phase B: wq (two 32-row subtiles) + score partials (double-buffered) ----
    for (int st = 0; st < 2; ++st) {
        int g = st * 32 + rr;
        int lw = w0 + (g >> 1); if (lw >= p.nw) lw = p.nw - 1;
        const _Float16* Ar = p.upd + ((size_t)lw * 3 + (g & 1)) * 256;
        f32x4 acc[2][4];
#pragma unroll
        for (int rg = 0; rg < 2; ++rg)
#pragma unroll
            for (int j = 0; j < 4; ++j)
#pragma unroll
                for (int i = 0; i < 4; ++i) acc[rg][j][i] = 0.f;
        f16x8 P = *(const f16x8*)&Ar[o * 8];
#pragma unroll
        for (int kc = 0; kc < 4; ++kc) {
            frag_store_h<2>(AH2[kc & 1], rr, o, P);
            if (kc < 3) P = *(const f16x8*)&Ar[(kc + 1) * 64 + o * 8];
            __syncthreads();
#pragma unroll
            for (int k2 = 0; k2 < 2; ++k2)
                mfma_step_h<2, 4>(AH2[kc & 1], p.W2h, p.W2l, 8, kc * 2 + k2, k2, wv, lane, acc);
        }
        float scp[2][4];
#pragma unroll
        for (int rg = 0; rg < 2; ++rg)
#pragma unroll
            for (int i = 0; i < 4; ++i) scp[rg][i] = 0.f;
#pragma unroll
        for (int j = 0; j < 4; ++j) {
            int col = (wv * 4 + j) * 16 + (lane & 15);
            float b = p.ab2[col];
#pragma unroll
            for (int rg = 0; rg < 2; ++rg)
#pragma unroll
                for (int i = 0; i < 4; ++i) {
                    int row = rg * 16 + ((lane >> 4) << 2) + i;
                    int gg = st * 32 + row;
                    float v = acc[rg][j][i] + b;
                    R2h[gg * 264 + col] = (_Float16)v;
                    scp[rg][i] += v * R1[(gg >> 1) * 260 + col];
                }
        }
#pragma unroll
        for (int rg = 0; rg < 2; ++rg)
#pragma unroll
            for (int i = 0; i < 4; ++i) {
                float sv = scp[rg][i];
#pragma unroll
                for (int off = 1; off < 16; off <<= 1) sv += __shfl_xor(sv, off);
                if ((lane & 15) == 0) {
                    int gg = st * 32 + rg * 16 + ((lane >> 4) << 2) + i;
                    atomicAdd(&scoreL[gg], sv);
                }
            }
    }
    __syncthreads();

    // ---- Phase C: softmax alphas + outf build ----
    if (tid < 32) {
        int lw = w0 + tid; if (lw >= p.nw) lw = p.nw - 1;
        int gw = p.win0 + lw;
        const double n = (double)(NWIN_TOTAL * 2);
        float stdv = (float)sqrt((p.acc[1] - p.acc[0] * p.acc[0] / n) / (n - 1.0));
        float cutv = p.cut[gw >> 7];
        float d0 = fabsf(cutv - p.time_idx[gw * 3 + 0]);
        float d1 = fabsf(cutv - p.time_idx[gw * 3 + 1]);
        float tw0 = expf(-d0 / (stdv + 1e-6f));
        float tw1 = expf(-d1 / (stdv + 1e-6f));
        float s0 = scoreL[tid * 2 + 0] * (0.7f + 0.3f * tw0);
        float s1 = scoreL[tid * 2 + 1] * (0.7f + 0.3f * tw1);
        float m = fmaxf(s0, s1);
        float e0 = expf(s0 - m), e1 = expf(s1 - m);
        float inv = 1.f / (e0 + e1);
        aL[tid * 2 + 0] = e0 * inv;
        aL[tid * 2 + 1] = e1 * inv;
    }
    __syncthreads();
    for (int q = tid; q < 32 * 256; q += NTH) {
        int r = q >> 8, c = q & 255;
        int lw = w0 + r; if (lw >= p.nw) lw = p.nw - 1;
        float u2 = (float)p.upd[((size_t)lw * 3 + 2) * 256 + c];
        R1[r * 260 + c] = u2 + aL[r * 2] * (float)R2h[(r * 2) * 264 + c]
                             + aL[r * 2 + 1] * (float)R2h[(r * 2 + 1) * 264 + c];
    }

    // ---- Phase D: h2 = relu(outf @ at_m1W) -> R2f[32][132] ----
    {
        f32x4 acc[2][2];
#pragma unroll
        for (int rg = 0; rg < 2; ++rg)
#pragma unroll
            for (int j = 0; j < 2; ++j)
#pragma unroll
                for (int i = 0; i < 4; ++i) acc[rg][j][i] = 0.f;
        for (int kc = 0; kc < 4; ++kc) {
            __syncthreads();
            {
                int k0 = kc * 64 + o * 8;
                float v[8];
                float4 x = *(const float4*)&R1[rr * 260 + k0];
                float4 y = *(const float4*)&R1[rr * 260 + k0 + 4];
                v[0]=x.x; v[1]=x.y; v[2]=x.z; v[3]=x.w;
                v[4]=y.x; v[5]=y.y; v[6]=y.z; v[7]=y.w;
                frag_store<2>(AH2[0], AL, rr, o, v);
            }
            __syncthreads();
#pragma unroll
            for (int k2 = 0; k2 < 2; ++k2)
                mfma_step<2, 2>(AH2[0], AL, p.M1h, p.M1l, 8, kc * 2 + k2, k2, wv, lane, acc);
        }
        __syncthreads();
#pragma unroll
        for (int j = 0; j < 2; ++j) {
            int col = (wv * 2 + j) * 16 + (lane & 15);
            float b = p.am1b[col];
#pragma unroll
            for (int rg = 0; rg < 2; ++rg)
#pragma unroll
                for (int i = 0; i < 4; ++i) {
                    int row = rg * 16 + ((lane >> 4) << 2) + i;
                    float x = acc[rg][j][i] + b;
                    R2f[row * 132 + col] = x > 0.f ? x : 0.f;
                }
        }
    }
    __syncthreads();

    // xz extra cols (stride 196)
    for (int q = tid; q < 32 * 68; q += NTH) {
        int r = q / 68, c = 128 + q % 68;
        int lw = w0 + r; if (lw >= p.nw) lw = p.nw - 1;
        int gw = p.win0 + lw;
        R1[r * 196 + c] = (c < 140) ? p.cat[(size_t)gw * 12 + (c - 128)] : 0.f;
    }

    // ---- Phase E: h3 = h2 @ at_m2W -> R1 stride 196 cols 0..127 ----
    {
        f32x4 acc[2][2];
#pragma unroll
        for (int rg = 0; rg < 2; ++rg)
#pragma unroll
            for (int j = 0; j < 2; ++j)
#pragma unroll
                for (int i = 0; i < 4; ++i) acc[rg][j][i] = 0.f;
        for (int kc = 0; kc < 2; ++kc) {
            __syncthreads();
            {
                int k0 = kc * 64 + o * 8;
                float v[8];
                float4 x = *(const float4*)&R2f[rr * 132 + k0];
                float4 y = *(const float4*)&R2f[rr * 132 + k0 + 4];
                v[0]=x.x; v[1]=x.y; v[2]=x.z; v[3]=x.w;
                v[4]=y.x; v[5]=y.y; v[6]=y.z; v[7]=y.w;
                frag_store<2>(AH2[0], AL, rr, o, v);
            }
            __syncthreads();
#pragma unroll
            for (int k2 = 0; k2 < 2; ++k2)
                mfma_step<2, 2>(AH2[0], AL, p.M2h, p.M2l, 4, kc * 2 + k2, k2, wv, lane, acc);
        }
        __syncthreads();
#pragma unroll
        for (int j = 0; j < 2; ++j) {
            int col = (wv * 2 + j) * 16 + (lane & 15);
            float b = p.am2b[col];
#pragma unroll
            for (int rg = 0; rg < 2; ++rg)
#pragma unroll
                for (int i = 0; i < 4; ++i) {
                    int row = rg * 16 + ((lane >> 4) << 2) + i;
                    R1[row * 196 + col] = acc[rg][j][i] + b;
                }
        }
    }

    // ---- Phase F: z1 = relu(xz @ f_W1) -> R2f stride 196 ----
    {
        f32x4 acc[2][3];
#pragma unroll
        for (int rg = 0; rg < 2; ++rg)
#pragma unroll
            for (int j = 0; j < 3; ++j)
#pragma unroll
                for (int i = 0; i < 4; ++i) acc[rg][j][i] = 0.f;
        for (int kc = 0; kc < 3; ++kc) {
            __syncthreads();
            {
                int k0 = kc * 64 + o * 8;
                float v[8];
                float4 x = *(const float4*)&R1[rr * 196 + k0];
                float4 y = *(const float4*)&R1[rr * 196 + k0 + 4];
                v[0]=x.x; v[1]=x.y; v[2]=x.z; v[3]=x.w;
                v[4]=y.x; v[5]=y.y; v[6]=y.z; v[7]=y.w;
                frag_store<2>(AH2[0], AL, rr, o, v);
            }
            __syncthreads();
#pragma unroll
            for (int k2 = 0; k2 < 2; ++k2)
                mfma_step<2, 3>(AH2[0], AL, p.F1h, p.F1l, 6, kc * 2 + k2, k2, wv, lane, acc);
        }
        __syncthreads();
#pragma unroll
        for (int j = 0; j < 3; ++j) {
            int col = (wv * 3 + j) * 16 + (lane & 15);
            float b = (col < 140) ? p.fb1[col] : 0.f;
#pragma unroll
            for (int rg = 0; rg < 2; ++rg)
#pragma unroll
                for (int i = 0; i < 4; ++i) {
                    int row = rg * 16 + ((lane >> 4) << 2) + i;
                    float x = acc[rg][j][i] + b;
                    R2f[row * 196 + col] = x > 0.f ? x : 0.f;
                }
        }
    }

    // ---- Phase G: z2 = relu(z1 @ f_W2) fused with final dot ----
    {
        f32x4 acc[2][2];
#pragma unroll
        for (int rg = 0; rg < 2; ++rg)
#pragma unroll
            for (int j = 0; j < 2; ++j)
#pragma unroll
                for (int i = 0; i < 4; ++i) acc[rg][j][i] = 0.f;
        for (int kc = 0; kc < 3; ++kc) {
            __syncthreads();
            {
                int k0 = kc * 64 + o * 8;
                float v[8];
                float4 x = *(const float4*)&R2f[rr * 196 + k0];
                float4 y = *(const float4*)&R2f[rr * 196 + k0 + 4];
                v[0]=x.x; v[1]=x.y; v[2]=x.z; v[3]=x.w;
                v[4]=y.x; v[5]=y.y; v[6]=y.z; v[7]=y.w;
                frag_store<2>(AH2[0], AL, rr, o, v);
            }
            __syncthreads();
#pragma unroll
            for (int k2 = 0; k2 < 2; ++k2)
                mfma_step<2, 2>(AH2[0], AL, p.F2h, p.F2l, 6, kc * 2 + k2, k2, wv, lane, acc);
        }
        float pt[2][4];
#pragma unroll
        for (int rg = 0; rg < 2; ++rg)
#pragma unroll
            for (int i = 0; i < 4; ++i) pt[rg][i] = 0.f;
#pragma unroll
        for (int j = 0; j < 2; ++j) {
            int col = (wv * 2 + j) * 16 + (lane & 15);
            float b = p.fb2[col];
            float w3 = p.fW3[col];
#pragma unroll
            for (int rg = 0; rg < 2; ++rg)
#pragma unroll
                for (int i = 0; i < 4; ++i) {
                    float x = acc[rg][j][i] + b;
                    x = x > 0.f ? x : 0.f;
                    pt[rg][i] += x * w3;
                }
        }
#pragma unroll
        for (int rg = 0; rg < 2; ++rg)
#pragma unroll
            for (int i = 0; i < 4; ++i) {
                float sv = pt[rg][i];
#pragma unroll
                for (int off = 1; off < 16; off <<= 1) sv += __shfl_xor(sv, off);
                if ((lane & 15) == 0)
                    atomicAdd(&finL[rg * 16 + ((lane >> 4) << 2) + i], sv);
            }
    }
    __syncthreads();
    if (tid < 32 && w0 + tid < p.nw)
        p.out[p.win0 + w0 + tid] = finL[tid] + p.fb3[0];
}

extern "C" void kernel_launch(void* const* d_in, const int* in_sizes, int n_in,
                              void* d_out, int out_size, void* d_ws, size_t ws_size,
                              hipStream_t stream) {
    const float* node_table    = (const float*)d_in[0];
    const float* edge_table    = (const float*)d_in[1];
    const float* basis_freq    = (const float*)d_in[2];
    const float* phase         = (const float*)d_in[3];
    const float* ev_W          = (const float*)d_in[4];
    const float* ev_b          = (const float*)d_in[5];
    const float* ev_m1W        = (const float*)d_in[6];
    const float* ev_m1b        = (const float*)d_in[7];
    const float* ev_m2W        = (const float*)d_in[8];
    const float* ev_m2b        = (const float*)d_in[9];
    const float* at_W1         = (const float*)d_in[10];
    const float* at_b1         = (const float*)d_in[11];
    const float* at_W2         = (const float*)d_in[12];
    const float* at_b2         = (const float*)d_in[13];
    const float* at_m1W        = (const float*)d_in[14];
    const float* at_m1b        = (const float*)d_in[15];
    const float* at_m2W        = (const float*)d_in[16];
    const float* at_m2b        = (const float*)d_in[17];
    const float* f_W1          = (const float*)d_in[18];
    const float* f_b1          = (const float*)d_in[19];
    const float* f_W2          = (const float*)d_in[20];
    const float* f_b2          = (const float*)d_in[21];
    const float* f_W3          = (const float*)d_in[22];
    const float* f_b3          = (const float*)d_in[23];
    const float* time_idx      = (const float*)d_in[24];
    const float* cut_time_l    = (const float*)d_in[25];
    const float* cat_feat      = (const float*)d_in[26];
    const float* edge_identify = (const float*)d_in[27];
    const int*   node_idx      = (const int*)d_in[28];
    const int*   edge_idx      = (const int*)d_in[29];

    char* wsb = (char*)d_ws;
    double* acc = (double*)wsb;

    const int   wkp[9] = {384, 192, 128, 256, 256, 256, 128, 192, 192};
    const int   wnp[9] = {192, 128, 128, 256, 256, 128, 128, 192, 128};
    const int   wkt[9] = {347, 172, 128, 256, 256, 256, 128, 140, 140};
    const int   wnt[9] = {172, 128, 128, 256, 256, 128, 128, 140, 128};
    const float* wsrc[9] = {ev_W, ev_m1W, ev_m2W, at_W1, at_W2, at_m1W, at_m2W, f_W1, f_W2};
    _Float16* wH[9]; _Float16* wL[9];
    size_t woff = 256;
    WAll wa = {};
    int cum = 0;
    for (int i = 0; i < 9; ++i) {
        size_t plane = (size_t)wkp[i] * wnp[i];
        wH[i] = (_Float16*)(wsb + woff);
        wL[i] = wH[i] + plane;
        woff += plane * 2 * sizeof(_Float16);
        woff = (woff + 15) & ~(size_t)15;
        wa.w[i].src = wsrc[i]; wa.w[i].dH = wH[i]; wa.w[i].dL = wL[i];
        wa.w[i].Kt = wkt[i]; wa.w[i].Nt = wnt[i]; wa.w[i].Kp = wkp[i]; wa.w[i].Np = wnp[i];
        wa.w[i].off = cum;
        cum += (wnp[i] / 16) * (wkp[i] / 32) * 64;
    }
    wa.grand = cum;

    hipMemsetAsync(d_ws, 0, 16, stream);
    k_std<<<64, NTH, 0, stream>>>(time_idx, cut_time_l, acc);
    k_wprep_all<<<CDIV(wa.grand, NTH), NTH, 0, stream>>>(wa);

    size_t avail = ws_size > woff + 4096 ? ws_size - woff - 4096 : 0;
    size_t nwc_s = avail / 1536;
    int nwc = (int)(nwc_s > NWIN_TOTAL ? NWIN_TOTAL : nwc_s);
    if (nwc < 1) nwc = 1;
    _Float16* updB = (_Float16*)(wsb + ((woff + 255) & ~(size_t)255));

    for (int c0 = 0; c0 < NWIN_TOTAL; c0 += nwc) {
        int nw = NWIN_TOTAL - c0 < nwc ? NWIN_TOTAL - c0 : nwc;
        int M3 = nw * 3;

        GCP gc = {};
        gc.W0h = wH[0]; gc.W0l = wL[0]; gc.W1h = wH[1]; gc.W1l = wL[1];
        gc.W2h = wH[2]; gc.W2l = wL[2];
        gc.b0 = ev_b; gc.b1 = ev_m1b; gc.b2 = ev_m2b;
        gc.upd = updB; gc.M = M3; gc.win0 = c0;
        gc.edge_table = edge_table; gc.node_table = node_table;
        gc.basis_freq = basis_freq; gc.phase = phase;
        gc.time_idx = time_idx; gc.cut = cut_time_l;
        gc.edge_idx = edge_idx; gc.node_idx = node_idx; gc.eid = edge_identify;
        k_gc<<<CDIV(M3, 32), NTH, 0, stream>>>(gc);

        AttnP ap = {};
        ap.upd = updB;
        ap.W1h = wH[3]; ap.W1l = wL[3]; ap.W2h = wH[4]; ap.W2l = wL[4];
        ap.M1h = wH[5]; ap.M1l = wL[5]; ap.M2h = wH[6]; ap.M2l = wL[6];
        ap.F1h = wH[7]; ap.F1l = wL[7]; ap.F2h = wH[8]; ap.F2l = wL[8];
        ap.ab1 = at_b1; ap.ab2 = at_b2; ap.am1b = at_m1b; ap.am2b = at_m2b;
        ap.fb1 = f_b1; ap.fb2 = f_b2; ap.fW3 = f_W3; ap.fb3 = f_b3;
        ap.time_idx = time_idx; ap.cut = cut_time_l; ap.cat = cat_feat; ap.acc = acc;
        ap.out = (float*)d_out; ap.nw = nw; ap.win0 = c0;
        k_attn<<<CDIV(nw, 32), NTH, 0, stream>>>(ap);
    }
}

// Round 17
// 247.040 us; speedup vs baseline: 1.0785x; 1.0407x over previous
//
#include <hip/hip_runtime.h>
#include <math.h>

#define NWIN_TOTAL (256 * 128)
#define NTH 256
#define CDIV(a, b) (((a) + (b) - 1) / (b))

typedef _Float16 f16x8 __attribute__((ext_vector_type(8)));
typedef float f32x4 __attribute__((ext_vector_type(4)));

__device__ __forceinline__ void mma2(f16x8 a, f16x8 bh, f16x8 bl, f32x4& c) {
    c = __builtin_amdgcn_mfma_f32_16x16x32_f16(a, bl, c, 0, 0, 0);
    c = __builtin_amdgcn_mfma_f32_16x16x32_f16(a, bh, c, 0, 0, 0);
}

__device__ __forceinline__ void mma3(f16x8 ah, f16x8 al, f16x8 bh, f16x8 bl, f32x4& c) {
    c = __builtin_amdgcn_mfma_f32_16x16x32_f16(al, bh, c, 0, 0, 0);
    c = __builtin_amdgcn_mfma_f32_16x16x32_f16(ah, bl, c, 0, 0, 0);
    c = __builtin_amdgcn_mfma_f32_16x16x32_f16(ah, bh, c, 0, 0, 0);
}

// ---------------- global std ----------------
__global__ __launch_bounds__(NTH) void k_std(const float* __restrict__ time_idx,
                                             const float* __restrict__ cut,
                                             double* __restrict__ acc) {
    int tid = threadIdx.x;
    const int n = NWIN_TOTAL * 2;
    double s = 0.0, s2 = 0.0;
    for (int i = blockIdx.x * blockDim.x + tid; i < n; i += gridDim.x * blockDim.x) {
        int j = i & 1;
        int bw = i >> 1;
        float d = fabsf(cut[bw >> 7] - time_idx[bw * 3 + j]);
        s += (double)d;
        s2 += (double)d * (double)d;
    }
    __shared__ double ls[NTH], ls2[NTH];
    ls[tid] = s; ls2[tid] = s2;
    __syncthreads();
    for (int st = NTH / 2; st > 0; st >>= 1) {
        if (tid < st) { ls[tid] += ls[tid + st]; ls2[tid] += ls2[tid + st]; }
        __syncthreads();
    }
    if (tid == 0) { atomicAdd(&acc[0], ls[0]); atomicAdd(&acc[1], ls2[0]); }
}

// ---------------- all weights -> B-fragment hi/lo planes (one launch) ----------------
struct WEnt { const float* src; _Float16* dH; _Float16* dL; int Kt, Nt, Kp, Np, off; };
struct WAll { WEnt w[9]; int grand; };

__global__ __launch_bounds__(NTH) void k_wprep_all(WAll a) {
    int idx = blockIdx.x * NTH + threadIdx.x;
    if (idx >= a.grand) return;
    int i = 0;
#pragma unroll
    for (int t = 0; t < 8; ++t)
        if (i + 1 < 9 && idx >= a.w[i + 1].off) ++i;
    const WEnt& e = a.w[i];
    int lidx = idx - e.off;
    int nks = e.Kp / 32;
    int cg = lidx / (nks * 64);
    int rem = lidx - cg * nks * 64;
    int ks = rem >> 6, lane = rem & 63;
    int col = cg * 16 + (lane & 15);
    for (int j = 0; j < 8; ++j) {
        int k = ks * 32 + ((lane >> 4) << 3) + j;
        float v = (k < e.Kt && col < e.Nt) ? e.src[(size_t)k * e.Nt + col] : 0.f;
        _Float16 h = (_Float16)v;
        float r = v - (float)h;
        e.dH[(size_t)lidx * 8 + j] = h;
        e.dL[(size_t)lidx * 8 + j] = (_Float16)r;
    }
}

// ---------------- frag helpers (swizzled: B ^= (B>>4)&7) ----------------
template <int RG>
__device__ __forceinline__ void frag_store(_Float16* AH, _Float16* AL, int r, int o,
                                           const float* v) {
    int B = ((o >> 2) * RG + (r >> 4)) * 64 + ((r & 15) | ((o & 3) << 4));
    int off = (B ^ ((B >> 4) & 7)) * 8;
    f16x8 h8, l8;
#pragma unroll
    for (int e = 0; e < 8; ++e) {
        _Float16 h = (_Float16)v[e];
        h8[e] = h;
        l8[e] = (_Float16)(v[e] - (float)h);
    }
    *(f16x8*)&AH[off] = h8;
    *(f16x8*)&AL[off] = l8;
}

template <int RG>
__device__ __forceinline__ void frag_store_h(_Float16* AH, int r, int o, f16x8 v) {
    int B = ((o >> 2) * RG + (r >> 4)) * 64 + ((r & 15) | ((o & 3) << 4));
    int off = (B ^ ((B >> 4) & 7)) * 8;
    *(f16x8*)&AH[off] = v;
}

template <int RG, int NREP>
__device__ __forceinline__ void mfma_step(const _Float16* AH, const _Float16* AL,
                                          const _Float16* __restrict__ Wh,
                                          const _Float16* __restrict__ Wl,
                                          int nks, int ks, int k2, int wv, int lane,
                                          f32x4 (&acc)[RG][NREP]) {
    f16x8 ah[RG], al[RG];
#pragma unroll
    for (int rg = 0; rg < RG; ++rg) {
        int B = (k2 * RG + rg) * 64 + lane;
        int off = (B ^ ((B >> 4) & 7)) * 8;
        ah[rg] = *(const f16x8*)&AH[off];
        al[rg] = *(const f16x8*)&AL[off];
    }
#pragma unroll
    for (int j = 0; j < NREP; ++j) {
        int cg = wv * NREP + j;
        size_t boff = ((size_t)(cg * nks + ks) * 64 + lane) * 8;
        f16x8 bh = *(const f16x8*)&Wh[boff];
        f16x8 bl = *(const f16x8*)&Wl[boff];
#pragma unroll
        for (int rg = 0; rg < RG; ++rg) mma3(ah[rg], al[rg], bh, bl, acc[rg][j]);
    }
}

// A exact fp16 staged (no lo): 2 MFMA per (rg,j)
template <int RG, int NREP>
__device__ __forceinline__ void mfma_step_h(const _Float16* AH,
                                            const _Float16* __restrict__ Wh,
                                            const _Float16* __restrict__ Wl,
                                            int nks, int ks, int k2, int wv, int lane,
                                            f32x4 (&acc)[RG][NREP]) {
    f16x8 ah[RG];
#pragma unroll
    for (int rg = 0; rg < RG; ++rg) {
        int B = (k2 * RG + rg) * 64 + lane;
        int off = (B ^ ((B >> 4) & 7)) * 8;
        ah[rg] = *(const f16x8*)&AH[off];
    }
#pragma unroll
    for (int j = 0; j < NREP; ++j) {
        int cg = wv * NREP + j;
        size_t boff = ((size_t)(cg * nks + ks) * 64 + lane) * 8;
        f16x8 bh = *(const f16x8*)&Wh[boff];
        f16x8 bl = *(const f16x8*)&Wl[boff];
#pragma unroll
        for (int rg = 0; rg < RG; ++rg) mma2(ah[rg], bh, bl, acc[rg][j]);
    }
}

// ---------------- K1: fused G1 + conv (dual-dir GEMM1, shared loads) ----------------
struct GCP {
    const _Float16 *W0h, *W0l, *W1h, *W1l, *W2h, *W2l;
    const float *b0, *b1, *b2;
    _Float16* upd; int M; int win0;
    const float* edge_table; const float* node_table;
    const float* basis_freq; const float* phase;
    const float* time_idx; const float* cut;
    const int* edge_idx; const int* node_idx; const float* eid;
};

__global__ __launch_bounds__(NTH) void k_gc(GCP p) {
    __shared__ _Float16 AH[2][2048], AL[2][2048];
    __shared__ _Float16 evL[32 * 184];
    __shared__ _Float16 h1L[32 * 136];
    __shared__ float ldsBF[176], ldsPH[176];
    const int tid = threadIdx.x, wv = tid >> 6, lane = tid & 63;
    const int mtile = blockIdx.x * 32;
    const int o = tid & 7, r = tid >> 3;

    if (tid < 172) { ldsBF[tid] = p.basis_freq[tid]; ldsPH[tid] = p.phase[tid]; }

    int grow = mtile + r; if (grow >= p.M) grow = p.M - 1;
    int w3 = grow / 3, l = grow - w3 * 3;
    int gw = p.win0 + w3;
    int nb = gw * 6 + 2 * l;
    const float* er = p.edge_table + (size_t)p.edge_idx[gw * 3 + l] * 172;
    const float* S0 = p.node_table + (size_t)p.node_idx[nb] * 172;
    const float* T0 = p.node_table + (size_t)p.node_idx[nb + 1] * 172;
    float dlt = p.cut[gw >> 7] - p.time_idx[gw * 3 + l];
    float g[3][8]; float eidv[3];
#pragma unroll
    for (int kc = 0; kc < 3; ++kc) {
        int k0 = kc * 64 + o * 8;
        if (k0 + 7 < 172) {
            float4 x = *(const float4*)&er[k0];
            float4 y = *(const float4*)&er[k0 + 4];
            g[kc][0]=x.x; g[kc][1]=x.y; g[kc][2]=x.z; g[kc][3]=x.w;
            g[kc][4]=y.x; g[kc][5]=y.y; g[kc][6]=y.z; g[kc][7]=y.w;
        } else if (k0 == 168) {
            float4 x = *(const float4*)&er[168];
            g[kc][0]=x.x; g[kc][1]=x.y; g[kc][2]=x.z; g[kc][3]=x.w;
            eidv[0] = p.eid[(gw * 3 + l) * 3 + 0];
            eidv[1] = p.eid[(gw * 3 + l) * 3 + 1];
            eidv[2] = p.eid[(gw * 3 + l) * 3 + 2];
        }
    }
    __syncthreads();   // ldsBF/PH ready

    // ---- Phase 1: ev = evt @ ev_W  (K=384, N=192), double-buffered ----
    {
        f32x4 acc[2][3];
#pragma unroll
        for (int rg = 0; rg < 2; ++rg)
#pragma unroll
            for (int j = 0; j < 3; ++j)
#pragma unroll
                for (int i = 0; i < 4; ++i) acc[rg][j][i] = 0.f;
        const int ord[6] = {3, 4, 5, 0, 1, 2};
#pragma unroll
        for (int x = 0; x < 6; ++x) {
            const int kc = ord[x];
            {
                int k0 = kc * 64 + o * 8;
                float v[8];
                if (kc >= 3 || k0 >= 176) {
#pragma unroll
                    for (int e = 0; e < 8; ++e) {
                        int k = k0 + e;
                        int q = k - 175;
                        v[e] = (k < 347) ? __cosf(fmaf(dlt, ldsBF[q], ldsPH[q])) : 0.f;
                    }
                } else if (k0 + 7 < 172) {
#pragma unroll
                    for (int e = 0; e < 8; ++e) v[e] = g[kc][e];
                } else {  // k0 == 168: edge[168..171], id[0..2], time_feat[0]
                    v[0]=g[2][0]; v[1]=g[2][1]; v[2]=g[2][2]; v[3]=g[2][3];
                    v[4]=eidv[0]; v[5]=eidv[1]; v[6]=eidv[2];
                    v[7]=__cosf(fmaf(dlt, ldsBF[0], ldsPH[0]));
                }
                frag_store<2>(AH[x & 1], AL[x & 1], r, o, v);
            }
            __syncthreads();
#pragma unroll
            for (int k2 = 0; k2 < 2; ++k2)
                mfma_step<2, 3>(AH[x & 1], AL[x & 1], p.W0h, p.W0l, 12,
                                kc * 2 + k2, k2, wv, lane, acc);
        }
#pragma unroll
        for (int j = 0; j < 3; ++j) {
            int col = (wv * 3 + j) * 16 + (lane & 15);
            if (col < 176) {
                float b = (col < 172) ? p.b0[col] : 0.f;
#pragma unroll
                for (int rg = 0; rg < 2; ++rg)
#pragma unroll
                    for (int i = 0; i < 4; ++i) {
                        int row = rg * 16 + ((lane >> 4) << 2) + i;
                        evL[row * 184 + col] = (_Float16)(acc[rg][j][i] + b);
                    }
            }
        }
    }
    __syncthreads();

    // ---- GEMM1 dual-dir: am0 = S+relu(T+ev), am1 = T+relu(S+ev) ----
    f32x4 a1[2][2][2];   // [dir][rg][j]
#pragma unroll
    for (int d = 0; d < 2; ++d)
#pragma unroll
        for (int rg = 0; rg < 2; ++rg)
#pragma unroll
            for (int j = 0; j < 2; ++j)
#pragma unroll
                for (int i = 0; i < 4; ++i) a1[d][rg][j][i] = 0.f;
    {
        float Ps[8], Pt[8];
        auto loadST = [&](int kc) {
            int k0 = kc * 64 + o * 8;
            if (k0 + 7 < 172) {
                *(float4*)&Ps[0] = *(const float4*)&S0[k0];
                *(float4*)&Ps[4] = *(const float4*)&S0[k0 + 4];
                *(float4*)&Pt[0] = *(const float4*)&T0[k0];
                *(float4*)&Pt[4] = *(const float4*)&T0[k0 + 4];
            } else if (k0 == 168) {
                *(float4*)&Ps[0] = *(const float4*)&S0[168];
                *(float4*)&Pt[0] = *(const float4*)&T0[168];
            }
        };
        loadST(0);
#pragma unroll
        for (int kc = 0; kc < 3; ++kc) {
            {
                int k0 = kc * 64 + o * 8;
                float v0[8], v1[8];
                if (k0 + 7 < 172) {
                    f16x8 e8 = *(const f16x8*)&evL[r * 184 + k0];
#pragma unroll
                    for (int e = 0; e < 8; ++e) {
                        float ev = (float)e8[e];
                        v0[e] = Ps[e] + fmaxf(Pt[e] + ev, 0.f);
                        v1[e] = Pt[e] + fmaxf(Ps[e] + ev, 0.f);
                    }
                } else if (k0 == 168) {
                    f16x8 e8 = *(const f16x8*)&evL[r * 184 + 168];
#pragma unroll
                    for (int e = 0; e < 8; ++e) {
                        if (e < 4) {
                            float ev = (float)e8[e];
                            v0[e] = Ps[e] + fmaxf(Pt[e] + ev, 0.f);
                            v1[e] = Pt[e] + fmaxf(Ps[e] + ev, 0.f);
                        } else { v0[e] = 0.f; v1[e] = 0.f; }
                    }
                } else {
#pragma unroll
                    for (int e = 0; e < 8; ++e) { v0[e] = 0.f; v1[e] = 0.f; }
                }
                frag_store<2>(AH[0], AL[0], r, o, v0);
                frag_store<2>(AH[1], AL[1], r, o, v1);
            }
            if (kc < 2) loadST(kc + 1);
            __syncthreads();
#pragma unroll
            for (int k2 = 0; k2 < 2; ++k2) {
                const int ks = kc * 2 + k2;
                f16x8 ah[2][2], al[2][2];
#pragma unroll
                for (int d = 0; d < 2; ++d)
#pragma unroll
                    for (int rg = 0; rg < 2; ++rg) {
                        int B = (k2 * 2 + rg) * 64 + lane;
                        int off = (B ^ ((B >> 4) & 7)) * 8;
                        ah[d][rg] = *(const f16x8*)&AH[d][off];
                        al[d][rg] = *(const f16x8*)&AL[d][off];
                    }
#pragma unroll
                for (int j = 0; j < 2; ++j) {
                    size_t boff = ((size_t)((wv * 2 + j) * 6 + ks) * 64 + lane) * 8;
                    f16x8 bh = *(const f16x8*)&p.W1h[boff];
                    f16x8 bl = *(const f16x8*)&p.W1l[boff];
#pragma unroll
                    for (int d = 0; d < 2; ++d)
#pragma unroll
                        for (int rg = 0; rg < 2; ++rg)
                            mma3(ah[d][rg], al[d][rg], bh, bl, a1[d][rg][j]);
                }
            }
            __syncthreads();
        }
    }

    // ---- per dir: h1 -> LDS fp16, then GEMM2 (direct frag loads) ----
    for (int dir = 0; dir < 2; ++dir) {
#pragma unroll
        for (int j = 0; j < 2; ++j) {
            int col = (wv * 2 + j) * 16 + (lane & 15);
            float b = p.b1[col];
#pragma unroll
            for (int rg = 0; rg < 2; ++rg)
#pragma unroll
                for (int i = 0; i < 4; ++i) {
                    int row = rg * 16 + ((lane >> 4) << 2) + i;
                    float x = a1[dir][rg][j][i] + b;
                    h1L[row * 136 + col] = (_Float16)(x > 0.f ? x : 0.f);
                }
        }
        __syncthreads();

        f32x4 a2[2][2];
#pragma unroll
        for (int rg = 0; rg < 2; ++rg)
#pragma unroll
            for (int j = 0; j < 2; ++j)
#pragma unroll
                for (int i = 0; i < 4; ++i) a2[rg][j][i] = 0.f;
#pragma unroll
        for (int ks = 0; ks < 4; ++ks) {
            const int k0 = ks * 32 + ((lane >> 4) << 3);
            f16x8 a4[2];
#pragma unroll
            for (int rg = 0; rg < 2; ++rg)
                a4[rg] = *(const f16x8*)&h1L[(rg * 16 + (lane & 15)) * 136 + k0];
#pragma unroll
            for (int j = 0; j < 2; ++j) {
                size_t boff = ((size_t)((wv * 2 + j) * 4 + ks) * 64 + lane) * 8;
                f16x8 bh = *(const f16x8*)&p.W2h[boff];
                f16x8 bl = *(const f16x8*)&p.W2l[boff];
#pragma unroll
                for (int rg = 0; rg < 2; ++rg) mma2(a4[rg], bh, bl, a2[rg][j]);
            }
        }
#pragma unroll
        for (int j = 0; j < 2; ++j) {
            int col = (wv * 2 + j) * 16 + (lane & 15);
            float b = p.b2[col];
#pragma unroll
            for (int rg = 0; rg < 2; ++rg)
#pragma unroll
                for (int i = 0; i < 4; ++i) {
                    int row = mtile + rg * 16 + ((lane >> 4) << 2) + i;
                    if (row < p.M)
                        p.upd[(size_t)row * 256 + dir * 128 + col] = (_Float16)(a2[rg][j][i] + b);
                }
        }
        if (dir == 0) __syncthreads();
    }
}

// ---------------- K2: fused attention + head (32 windows / block) ----------------
struct AttnP {
    const _Float16* upd;
    const _Float16 *W1h,*W1l,*W2h,*W2l,*M1h,*M1l,*M2h,*M2l,*F1h,*F1l,*F2h,*F2l;
    const float *ab1,*ab2,*am1b,*am2b,*fb1,*fb2,*fW3,*fb3;
    const float *time_idx,*cut,*cat; const double* acc;
    float* out; int nw; int win0;
};

__global__ __launch_bounds__(NTH) void k_attn(AttnP p) {
    __shared__ float R1[32 * 260];
    __shared__ _Float16 R2h[64 * 264];
    __shared__ _Float16 AH2[2][2048];
    __shared__ _Float16 AL[2048];
    __shared__ float scoreL[64], aL[64], finL[32];
    float* R2f = (float*)R2h;
    const int tid = threadIdx.x, wv = tid >> 6, lane = tid & 63;
    const int w0 = blockIdx.x * 32;
    const int rr = tid >> 3, o = tid & 7;
    if (tid < 64) scoreL[tid] = 0.f;
    if (tid < 32) finL[tid] = 0.f;
    __syncthreads();

    // ---- Phase A: wp = upd[w*3+2] @ at_W1 (double-buffered, 1 barrier/kc) ----
    {
        int lw = w0 + rr; if (lw >= p.nw) lw = p.nw - 1;
        const _Float16* Ar = p.upd + ((size_t)lw * 3 + 2) * 256;
        f32x4 acc[2][4];
#pragma unroll
        for (int rg = 0; rg < 2; ++rg)
#pragma unroll
            for (int j = 0; j < 4; ++j)
#pragma unroll
                for (int i = 0; i < 4; ++i) acc[rg][j][i] = 0.f;
        f16x8 P = *(const f16x8*)&Ar[o * 8];
#pragma unroll
        for (int kc = 0; kc < 4; ++kc) {
            frag_store_h<2>(AH2[kc & 1], rr, o, P);
            if (kc < 3) P = *(const f16x8*)&Ar[(kc + 1) * 64 + o * 8];
            __syncthreads();
#pragma unroll
            for (int k2 = 0; k2 < 2; ++k2)
                mfma_step_h<2, 4>(AH2[kc & 1], p.W1h, p.W1l, 8, kc * 2 + k2, k2, wv, lane, acc);
        }
#pragma unroll
        for (int j = 0; j < 4; ++j) {
            int col = (wv * 4 + j) * 16 + (lane & 15);
            float b = p.ab1[col];
#pragma unroll
            for (int rg = 0; rg < 2; ++rg)
#pragma unroll
                for (int i = 0; i < 4; ++i) {
                    int row = rg * 16 + ((lane >> 4) << 2) + i;
                    R1[row * 260 + col] = acc[rg][j][i] + b;
                }
        }
    }

    // ---- Phase B: wq (two 32-row subtiles) + score partials ----
    for (int st = 0; st < 2; ++st) {
        int g = st * 32 + rr;
        int lw = w0 + (g >> 1); if (lw >= p.nw) lw = p.nw - 1;
        const _Float16* Ar = p.upd + ((size_t)lw * 3 + (g & 1)) * 256;
        f32x4 acc[2][4];
#pragma unroll
        for (int rg = 0; rg < 2; ++rg)
#pragma unroll
            for (int j = 0; j < 4; ++j)
#pragma unroll
                for (int i = 0; i < 4; ++i) acc[rg][j][i] = 0.f;
        f16x8 P = *(const f16x8*)&Ar[o * 8];
#pragma unroll
        for (int kc = 0; kc < 4; ++kc) {
            frag_store_h<2>(AH2[kc & 1], rr, o, P);
            if (kc < 3) P = *(const f16x8*)&Ar[(kc + 1) * 64 + o * 8];
            __syncthreads();
#pragma unroll
            for (int k2 = 0; k2 < 2; ++k2)
                mfma_step_h<2, 4>(AH2[kc & 1], p.W2h, p.W2l, 8, kc * 2 + k2, k2, wv, lane, acc);
        }
        float scp[2][4];
#pragma unroll
        for (int rg = 0; rg < 2; ++rg)
#pragma unroll
            for (int i = 0; i < 4; ++i) scp[rg][i] = 0.f;
#pragma unroll
        for (int j = 0; j < 4; ++j) {
            int col = (wv * 4 + j) * 16 + (lane & 15);
            float b = p.ab2[col];
#pragma unroll
            for (int rg = 0; rg < 2; ++rg)
#pragma unroll
                for (int i = 0; i < 4; ++i) {
                    int row = rg * 16 + ((lane >> 4) << 2) + i;
                    int gg = st * 32 + row;
                    float v = acc[rg][j][i] + b;
                    R2h[gg * 264 + col] = (_Float16)v;
                    scp[rg][i] += v * R1[(gg >> 1) * 260 + col];
                }
        }
#pragma unroll
        for (int rg = 0; rg < 2; ++rg)
#pragma unroll
            for (int i = 0; i < 4; ++i) {
                float sv = scp[rg][i];
#pragma unroll
                for (int off = 1; off < 16; off <<= 1) sv += __shfl_xor(sv, off);
                if ((lane & 15) == 0) {
                    int gg = st * 32 + rg * 16 + ((lane >> 4) << 2) + i;
                    atomicAdd(&scoreL[gg], sv);
                }
            }
    }
    __syncthreads();

    // ---- Phase C: softmax alphas + outf build ----
    if (tid < 32) {
        int lw = w0 + tid; if (lw >= p.nw) lw = p.nw - 1;
        int gw = p.win0 + lw;
        const double n = (double)(NWIN_TOTAL * 2);
        float stdv = (float)sqrt((p.acc[1] - p.acc[0] * p.acc[0] / n) / (n - 1.0));
        float cutv = p.cut[gw >> 7];
        float d0 = fabsf(cutv - p.time_idx[gw * 3 + 0]);
        float d1 = fabsf(cutv - p.time_idx[gw * 3 + 1]);
        float tw0 = expf(-d0 / (stdv + 1e-6f));
        float tw1 = expf(-d1 / (stdv + 1e-6f));
        float s0 = scoreL[tid * 2 + 0] * (0.7f + 0.3f * tw0);
        float s1 = scoreL[tid * 2 + 1] * (0.7f + 0.3f * tw1);
        float m = fmaxf(s0, s1);
        float e0 = expf(s0 - m), e1 = expf(s1 - m);
        float inv = 1.f / (e0 + e1);
        aL[tid * 2 + 0] = e0 * inv;
        aL[tid * 2 + 1] = e1 * inv;
    }
    __syncthreads();
    for (int q = tid; q < 32 * 256; q += NTH) {
        int r = q >> 8, c = q & 255;
        int lw = w0 + r; if (lw >= p.nw) lw = p.nw - 1;
        float u2 = (float)p.upd[((size_t)lw * 3 + 2) * 256 + c];
        R1[r * 260 + c] = u2 + aL[r * 2] * (float)R2h[(r * 2) * 264 + c]
                             + aL[r * 2 + 1] * (float)R2h[(r * 2 + 1) * 264 + c];
    }

    // ---- Phase D: h2 = relu(outf @ at_m1W) -> R2f[32][132] ----
    {
        f32x4 acc[2][2];
#pragma unroll
        for (int rg = 0; rg < 2; ++rg)
#pragma unroll
            for (int j = 0; j < 2; ++j)
#pragma unroll
                for (int i = 0; i < 4; ++i) acc[rg][j][i] = 0.f;
        for (int kc = 0; kc < 4; ++kc) {
            __syncthreads();
            {
                int k0 = kc * 64 + o * 8;
                float v[8];
                float4 x = *(const float4*)&R1[rr * 260 + k0];
                float4 y = *(const float4*)&R1[rr * 260 + k0 + 4];
                v[0]=x.x; v[1]=x.y; v[2]=x.z; v[3]=x.w;
                v[4]=y.x; v[5]=y.y; v[6]=y.z; v[7]=y.w;
                frag_store<2>(AH2[0], AL, rr, o, v);
            }
            __syncthreads();
#pragma unroll
            for (int k2 = 0; k2 < 2; ++k2)
                mfma_step<2, 2>(AH2[0], AL, p.M1h, p.M1l, 8, kc * 2 + k2, k2, wv, lane, acc);
        }
        __syncthreads();
#pragma unroll
        for (int j = 0; j < 2; ++j) {
            int col = (wv * 2 + j) * 16 + (lane & 15);
            float b = p.am1b[col];
#pragma unroll
            for (int rg = 0; rg < 2; ++rg)
#pragma unroll
                for (int i = 0; i < 4; ++i) {
                    int row = rg * 16 + ((lane >> 4) << 2) + i;
                    float x = acc[rg][j][i] + b;
                    R2f[row * 132 + col] = x > 0.f ? x : 0.f;
                }
        }
    }
    __syncthreads();

    // xz extra cols (stride 196)
    for (int q = tid; q < 32 * 68; q += NTH) {
        int r = q / 68, c = 128 + q % 68;
        int lw = w0 + r; if (lw >= p.nw) lw = p.nw - 1;
        int gw = p.win0 + lw;
        R1[r * 196 + c] = (c < 140) ? p.cat[(size_t)gw * 12 + (c - 128)] : 0.f;
    }

    // ---- Phase E: h3 = h2 @ at_m2W -> R1 stride 196 cols 0..127 ----
    {
        f32x4 acc[2][2];
#pragma unroll
        for (int rg = 0; rg < 2; ++rg)
#pragma unroll
            for (int j = 0; j < 2; ++j)
#pragma unroll
                for (int i = 0; i < 4; ++i) acc[rg][j][i] = 0.f;
        for (int kc = 0; kc < 2; ++kc) {
            __syncthreads();
            {
                int k0 = kc * 64 + o * 8;
                float v[8];
                float4 x = *(const float4*)&R2f[rr * 132 + k0];
                float4 y = *(const float4*)&R2f[rr * 132 + k0 + 4];
                v[0]=x.x; v[1]=x.y; v[2]=x.z; v[3]=x.w;
                v[4]=y.x; v[5]=y.y; v[6]=y.z; v[7]=y.w;
                frag_store<2>(AH2[0], AL, rr, o, v);
            }
            __syncthreads();
#pragma unroll
            for (int k2 = 0; k2 < 2; ++k2)
                mfma_step<2, 2>(AH2[0], AL, p.M2h, p.M2l, 4, kc * 2 + k2, k2, wv, lane, acc);
        }
        __syncthreads();
#pragma unroll
        for (int j = 0; j < 2; ++j) {
            int col = (wv * 2 + j) * 16 + (lane & 15);
            float b = p.am2b[col];
#pragma unroll
            for (int rg = 0; rg < 2; ++rg)
#pragma unroll
                for (int i = 0; i < 4; ++i) {
                    int row = rg * 16 + ((lane >> 4) << 2) + i;
                    R1[row * 196 + col] = acc[rg][j][i] + b;
                }
        }
    }

    // ---- Phase F: z1 = relu(xz @ f_W1) -> R2f stride 196 ----
    {
        f32x4 acc[2][3];
#pragma unroll
        for (int rg = 0; rg < 2; ++rg)
#pragma unroll
            for (int j = 0; j < 3; ++j)
#pragma unroll
                for (int i = 0; i < 4; ++i) acc[rg][j][i] = 0.f;
        for (int kc = 0; kc < 3; ++kc) {
            __syncthreads();
            {
                int k0 = kc * 64 + o * 8;
                float v[8];
                float4 x = *(const float4*)&R1[rr * 196 + k0];
                float4 y = *(const float4*)&R1[rr * 196 + k0 + 4];
                v[0]=x.x; v[1]=x.y; v[2]=x.z; v[3]=x.w;
                v[4]=y.x; v[5]=y.y; v[6]=y.z; v[7]=y.w;
                frag_store<2>(AH2[0], AL, rr, o, v);
            }
            __syncthreads();
#pragma unroll
            for (int k2 = 0; k2 < 2; ++k2)
                mfma_step<2, 3>(AH2[0], AL, p.F1h, p.F1l, 6, kc * 2 + k2, k2, wv, lane, acc);
        }
        __syncthreads();
#pragma unroll
        for (int j = 0; j < 3; ++j) {
            int col = (wv * 3 + j) * 16 + (lane & 15);
            float b = (col < 140) ? p.fb1[col] : 0.f;
#pragma unroll
            for (int rg = 0; rg < 2; ++rg)
#pragma unroll
                for (int i = 0; i < 4; ++i) {
                    int row = rg * 16 + ((lane >> 4) << 2) + i;
                    float x = acc[rg][j][i] + b;
                    R2f[row * 196 + col] = x > 0.f ? x : 0.f;
                }
        }
    }

    // ---- Phase G: z2 = relu(z1 @ f_W2) fused with final dot ----
    {
        f32x4 acc[2][2];
#pragma unroll
        for (int rg = 0; rg < 2; ++rg)
#pragma unroll
            for (int j = 0; j < 2; ++j)
#pragma unroll
                for (int i = 0; i < 4; ++i) acc[rg][j][i] = 0.f;
        for (int kc = 0; kc < 3; ++kc) {
            __syncthreads();
            {
                int k0 = kc * 64 + o * 8;
                float v[8];
                float4 x = *(const float4*)&R2f[rr * 196 + k0];
                float4 y = *(const float4*)&R2f[rr * 196 + k0 + 4];
                v[0]=x.x; v[1]=x.y; v[2]=x.z; v[3]=x.w;
                v[4]=y.x; v[5]=y.y; v[6]=y.z; v[7]=y.w;
                frag_store<2>(AH2[0], AL, rr, o, v);
            }
            __syncthreads();
#pragma unroll
            for (int k2 = 0; k2 < 2; ++k2)
                mfma_step<2, 2>(AH2[0], AL, p.F2h, p.F2l, 6, kc * 2 + k2, k2, wv, lane, acc);
        }
        float pt[2][4];
#pragma unroll
        for (int rg = 0; rg < 2; ++rg)
#pragma unroll
            for (int i = 0; i < 4; ++i) pt[rg][i] = 0.f;
#pragma unroll
        for (int j = 0; j < 2; ++j) {
            int col = (wv * 2 + j) * 16 + (lane & 15);
            float b = p.fb2[col];
            float w3 = p.fW3[col];
#pragma unroll
            for (int rg = 0; rg < 2; ++rg)
#pragma unroll
                for (int i = 0; i < 4; ++i) {
                    float x = acc[rg][j][i] + b;
                    x = x > 0.f ? x : 0.f;
                    pt[rg][i] += x * w3;
                }
        }
#pragma unroll
        for (int rg = 0; rg < 2; ++rg)
#pragma unroll
            for (int i = 0; i < 4; ++i) {
                float sv = pt[rg][i];
#pragma unroll
                for (int off = 1; off < 16; off <<= 1) sv += __shfl_xor(sv, off);
                if ((lane & 15) == 0)
                    atomicAdd(&finL[rg * 16 + ((lane >> 4) << 2) + i], sv);
            }
    }
    __syncthreads();
    if (tid < 32 && w0 + tid < p.nw)
        p.out[p.win0 + w0 + tid] = finL[tid] + p.fb3[0];
}

extern "C" void kernel_launch(void* const* d_in, const int* in_sizes, int n_in,
                              void* d_out, int out_size, void* d_ws, size_t ws_size,
                              hipStream_t stream) {
    const float* node_table    = (const float*)d_in[0];
    const float* edge_table    = (const float*)d_in[1];
    const float* basis_freq    = (const float*)d_in[2];
    const float* phase         = (const float*)d_in[3];
    const float* ev_W          = (const float*)d_in[4];
    const float* ev_b          = (const float*)d_in[5];
    const float* ev_m1W        = (const float*)d_in[6];
    const float* ev_m1b        = (const float*)d_in[7];
    const float* ev_m2W        = (const float*)d_in[8];
    const float* ev_m2b        = (const float*)d_in[9];
    const float* at_W1         = (const float*)d_in[10];
    const float* at_b1         = (const float*)d_in[11];
    const float* at_W2         = (const float*)d_in[12];
    const float* at_b2         = (const float*)d_in[13];
    const float* at_m1W        = (const float*)d_in[14];
    const float* at_m1b        = (const float*)d_in[15];
    const float* at_m2W        = (const float*)d_in[16];
    const float* at_m2b        = (const float*)d_in[17];
    const float* f_W1          = (const float*)d_in[18];
    const float* f_b1          = (const float*)d_in[19];
    const float* f_W2          = (const float*)d_in[20];
    const float* f_b2          = (const float*)d_in[21];
    const float* f_W3          = (const float*)d_in[22];
    const float* f_b3          = (const float*)d_in[23];
    const float* time_idx      = (const float*)d_in[24];
    const float* cut_time_l    = (const float*)d_in[25];
    const float* cat_feat      = (const float*)d_in[26];
    const float* edge_identify = (const float*)d_in[27];
    const int*   node_idx      = (const int*)d_in[28];
    const int*   edge_idx      = (const int*)d_in[29];

    char* wsb = (char*)d_ws;
    double* acc = (double*)wsb;

    const int   wkp[9] = {384, 192, 128, 256, 256, 256, 128, 192, 192};
    const int   wnp[9] = {192, 128, 128, 256, 256, 128, 128, 192, 128};
    const int   wkt[9] = {347, 172, 128, 256, 256, 256, 128, 140, 140};
    const int   wnt[9] = {172, 128, 128, 256, 256, 128, 128, 140, 128};
    const float* wsrc[9] = {ev_W, ev_m1W, ev_m2W, at_W1, at_W2, at_m1W, at_m2W, f_W1, f_W2};
    _Float16* wH[9]; _Float16* wL[9];
    size_t woff = 256;
    WAll wa = {};
    int cum = 0;
    for (int i = 0; i < 9; ++i) {
        size_t plane = (size_t)wkp[i] * wnp[i];
        wH[i] = (_Float16*)(wsb + woff);
        wL[i] = wH[i] + plane;
        woff += plane * 2 * sizeof(_Float16);
        woff = (woff + 15) & ~(size_t)15;
        wa.w[i].src = wsrc[i]; wa.w[i].dH = wH[i]; wa.w[i].dL = wL[i];
        wa.w[i].Kt = wkt[i]; wa.w[i].Nt = wnt[i]; wa.w[i].Kp = wkp[i]; wa.w[i].Np = wnp[i];
        wa.w[i].off = cum;
        cum += (wnp[i] / 16) * (wkp[i] / 32) * 64;
    }
    wa.grand = cum;

    hipMemsetAsync(d_ws, 0, 16, stream);
    k_std<<<64, NTH, 0, stream>>>(time_idx, cut_time_l, acc);
    k_wprep_all<<<CDIV(wa.grand, NTH), NTH, 0, stream>>>(wa);

    size_t avail = ws_size > woff + 4096 ? ws_size - woff - 4096 : 0;
    size_t nwc_s = avail / 1536;
    int nwc = (int)(nwc_s > NWIN_TOTAL ? NWIN_TOTAL : nwc_s);
    if (nwc < 1) nwc = 1;
    _Float16* updB = (_Float16*)(wsb + ((woff + 255) & ~(size_t)255));

    for (int c0 = 0; c0 < NWIN_TOTAL; c0 += nwc) {
        int nw = NWIN_TOTAL - c0 < nwc ? NWIN_TOTAL - c0 : nwc;
        int M3 = nw * 3;

        GCP gc = {};
        gc.W0h = wH[0]; gc.W0l = wL[0]; gc.W1h = wH[1]; gc.W1l = wL[1];
        gc.W2h = wH[2]; gc.W2l = wL[2];
        gc.b0 = ev_b; gc.b1 = ev_m1b; gc.b2 = ev_m2b;
        gc.upd = updB; gc.M = M3; gc.win0 = c0;
        gc.edge_table = edge_table; gc.node_table = node_table;
        gc.basis_freq = basis_freq; gc.phase = phase;
        gc.time_idx = time_idx; gc.cut = cut_time_l;
        gc.edge_idx = edge_idx; gc.node_idx = node_idx; gc.eid = edge_identify;
        k_gc<<<CDIV(M3, 32), NTH, 0, stream>>>(gc);

        AttnP ap = {};
        ap.upd = updB;
        ap.W1h = wH[3]; ap.W1l = wL[3]; ap.W2h = wH[4]; ap.W2l = wL[4];
        ap.M1h = wH[5]; ap.M1l = wL[5]; ap.M2h = wH[6]; ap.M2l = wL[6];
        ap.F1h = wH[7]; ap.F1l = wL[7]; ap.F2h = wH[8]; ap.F2l = wL[8];
        ap.ab1 = at_b1; ap.ab2 = at_b2; ap.am1b = at_m1b; ap.am2b = at_m2b;
        ap.fb1 = f_b1; ap.fb2 = f_b2; ap.fW3 = f_W3; ap.fb3 = f_b3;
        ap.time_idx = time_idx; ap.cut = cut_time_l; ap.cat = cat_feat; ap.acc = acc;
        ap.out = (float*)d_out; ap.nw = nw; ap.win0 = c0;
        k_attn<<<CDIV(nw, 32), NTH, 0, stream>>>(ap);
    }
}

// Round 18
// 184.789 us; speedup vs baseline: 1.4418x; 1.3369x over previous
//
#include <hip/hip_runtime.h>
#include <math.h>

#define NWIN_TOTAL (256 * 128)
#define NTH 256
#define CDIV(a, b) (((a) + (b) - 1) / (b))

typedef _Float16 f16x8 __attribute__((ext_vector_type(8)));
typedef float f32x4 __attribute__((ext_vector_type(4)));

// B hi-only (W-lo dropped; error budget: a*deltaB == deltaA*b term which measured free)
__device__ __forceinline__ void mma1(f16x8 a, f16x8 bh, f32x4& c) {
    c = __builtin_amdgcn_mfma_f32_16x16x32_f16(a, bh, c, 0, 0, 0);
}

__device__ __forceinline__ void mma2a(f16x8 ah, f16x8 al, f16x8 bh, f32x4& c) {
    c = __builtin_amdgcn_mfma_f32_16x16x32_f16(al, bh, c, 0, 0, 0);
    c = __builtin_amdgcn_mfma_f32_16x16x32_f16(ah, bh, c, 0, 0, 0);
}

// ---------------- global std ----------------
__global__ __launch_bounds__(NTH) void k_std(const float* __restrict__ time_idx,
                                             const float* __restrict__ cut,
                                             double* __restrict__ acc) {
    int tid = threadIdx.x;
    const int n = NWIN_TOTAL * 2;
    double s = 0.0, s2 = 0.0;
    for (int i = blockIdx.x * blockDim.x + tid; i < n; i += gridDim.x * blockDim.x) {
        int j = i & 1;
        int bw = i >> 1;
        float d = fabsf(cut[bw >> 7] - time_idx[bw * 3 + j]);
        s += (double)d;
        s2 += (double)d * (double)d;
    }
    __shared__ double ls[NTH], ls2[NTH];
    ls[tid] = s; ls2[tid] = s2;
    __syncthreads();
    for (int st = NTH / 2; st > 0; st >>= 1) {
        if (tid < st) { ls[tid] += ls[tid + st]; ls2[tid] += ls2[tid + st]; }
        __syncthreads();
    }
    if (tid == 0) { atomicAdd(&acc[0], ls[0]); atomicAdd(&acc[1], ls2[0]); }
}

// ---------------- all weights -> B-fragment hi plane only (one launch) ----------------
struct WEnt { const float* src; _Float16* dH; int Kt, Nt, Kp, Np, off; };
struct WAll { WEnt w[9]; int grand; };

__global__ __launch_bounds__(NTH) void k_wprep_all(WAll a) {
    int idx = blockIdx.x * NTH + threadIdx.x;
    if (idx >= a.grand) return;
    int i = 0;
#pragma unroll
    for (int t = 0; t < 8; ++t)
        if (i + 1 < 9 && idx >= a.w[i + 1].off) ++i;
    const WEnt& e = a.w[i];
    int lidx = idx - e.off;
    int nks = e.Kp / 32;
    int cg = lidx / (nks * 64);
    int rem = lidx - cg * nks * 64;
    int ks = rem >> 6, lane = rem & 63;
    int col = cg * 16 + (lane & 15);
    for (int j = 0; j < 8; ++j) {
        int k = ks * 32 + ((lane >> 4) << 3) + j;
        float v = (k < e.Kt && col < e.Nt) ? e.src[(size_t)k * e.Nt + col] : 0.f;
        e.dH[(size_t)lidx * 8 + j] = (_Float16)v;
    }
}

// ---------------- frag helpers (swizzled: B ^= (B>>4)&7) ----------------
template <int RG>
__device__ __forceinline__ void frag_store(_Float16* AH, _Float16* AL, int r, int o,
                                           const float* v) {
    int B = ((o >> 2) * RG + (r >> 4)) * 64 + ((r & 15) | ((o & 3) << 4));
    int off = (B ^ ((B >> 4) & 7)) * 8;
    f16x8 h8, l8;
#pragma unroll
    for (int e = 0; e < 8; ++e) {
        _Float16 h = (_Float16)v[e];
        h8[e] = h;
        l8[e] = (_Float16)(v[e] - (float)h);
    }
    *(f16x8*)&AH[off] = h8;
    *(f16x8*)&AL[off] = l8;
}

template <int RG>
__device__ __forceinline__ void frag_store_h(_Float16* AH, int r, int o, f16x8 v) {
    int B = ((o >> 2) * RG + (r >> 4)) * 64 + ((r & 15) | ((o & 3) << 4));
    int off = (B ^ ((B >> 4) & 7)) * 8;
    *(f16x8*)&AH[off] = v;
}

// A split (hi+lo), B hi-only: 2 MFMA per (rg,j)
template <int RG, int NREP>
__device__ __forceinline__ void mfma_step(const _Float16* AH, const _Float16* AL,
                                          const _Float16* __restrict__ Wh,
                                          int nks, int ks, int k2, int wv, int lane,
                                          f32x4 (&acc)[RG][NREP]) {
    f16x8 ah[RG], al[RG];
#pragma unroll
    for (int rg = 0; rg < RG; ++rg) {
        int B = (k2 * RG + rg) * 64 + lane;
        int off = (B ^ ((B >> 4) & 7)) * 8;
        ah[rg] = *(const f16x8*)&AH[off];
        al[rg] = *(const f16x8*)&AL[off];
    }
#pragma unroll
    for (int j = 0; j < NREP; ++j) {
        int cg = wv * NREP + j;
        size_t boff = ((size_t)(cg * nks + ks) * 64 + lane) * 8;
        f16x8 bh = *(const f16x8*)&Wh[boff];
#pragma unroll
        for (int rg = 0; rg < RG; ++rg) mma2a(ah[rg], al[rg], bh, acc[rg][j]);
    }
}

// A exact fp16 staged, B hi-only: 1 MFMA per (rg,j)
template <int RG, int NREP>
__device__ __forceinline__ void mfma_step_h(const _Float16* AH,
                                            const _Float16* __restrict__ Wh,
                                            int nks, int ks, int k2, int wv, int lane,
                                            f32x4 (&acc)[RG][NREP]) {
    f16x8 ah[RG];
#pragma unroll
    for (int rg = 0; rg < RG; ++rg) {
        int B = (k2 * RG + rg) * 64 + lane;
        int off = (B ^ ((B >> 4) & 7)) * 8;
        ah[rg] = *(const f16x8*)&AH[off];
    }
#pragma unroll
    for (int j = 0; j < NREP; ++j) {
        int cg = wv * NREP + j;
        size_t boff = ((size_t)(cg * nks + ks) * 64 + lane) * 8;
        f16x8 bh = *(const f16x8*)&Wh[boff];
#pragma unroll
        for (int rg = 0; rg < RG; ++rg) mma1(ah[rg], bh, acc[rg][j]);
    }
}

// ---------------- K1: fused G1 + conv (dual-dir GEMM1, shared loads) ----------------
struct GCP {
    const _Float16 *W0h, *W1h, *W2h;
    const float *b0, *b1, *b2;
    _Float16* upd; int M; int win0;
    const float* edge_table; const float* node_table;
    const float* basis_freq; const float* phase;
    const float* time_idx; const float* cut;
    const int* edge_idx; const int* node_idx; const float* eid;
};

__global__ __launch_bounds__(NTH) void k_gc(GCP p) {
    __shared__ _Float16 AH[2][2048], AL[2][2048];
    __shared__ _Float16 evL[32 * 184];
    __shared__ _Float16 h1L[32 * 136];
    __shared__ float ldsBF[176], ldsPH[176];
    const int tid = threadIdx.x, wv = tid >> 6, lane = tid & 63;
    const int mtile = blockIdx.x * 32;
    const int o = tid & 7, r = tid >> 3;

    if (tid < 172) { ldsBF[tid] = p.basis_freq[tid]; ldsPH[tid] = p.phase[tid]; }

    int grow = mtile + r; if (grow >= p.M) grow = p.M - 1;
    int w3 = grow / 3, l = grow - w3 * 3;
    int gw = p.win0 + w3;
    int nb = gw * 6 + 2 * l;
    const float* er = p.edge_table + (size_t)p.edge_idx[gw * 3 + l] * 172;
    const float* S0 = p.node_table + (size_t)p.node_idx[nb] * 172;
    const float* T0 = p.node_table + (size_t)p.node_idx[nb + 1] * 172;
    float dlt = p.cut[gw >> 7] - p.time_idx[gw * 3 + l];
    float g[3][8]; float eidv[3];
#pragma unroll
    for (int kc = 0; kc < 3; ++kc) {
        int k0 = kc * 64 + o * 8;
        if (k0 + 7 < 172) {
            float4 x = *(const float4*)&er[k0];
            float4 y = *(const float4*)&er[k0 + 4];
            g[kc][0]=x.x; g[kc][1]=x.y; g[kc][2]=x.z; g[kc][3]=x.w;
            g[kc][4]=y.x; g[kc][5]=y.y; g[kc][6]=y.z; g[kc][7]=y.w;
        } else if (k0 == 168) {
            float4 x = *(const float4*)&er[168];
            g[kc][0]=x.x; g[kc][1]=x.y; g[kc][2]=x.z; g[kc][3]=x.w;
            eidv[0] = p.eid[(gw * 3 + l) * 3 + 0];
            eidv[1] = p.eid[(gw * 3 + l) * 3 + 1];
            eidv[2] = p.eid[(gw * 3 + l) * 3 + 2];
        }
    }
    __syncthreads();   // ldsBF/PH ready

    // ---- Phase 1: ev = evt @ ev_W  (K=384, N=192), double-buffered ----
    {
        f32x4 acc[2][3];
#pragma unroll
        for (int rg = 0; rg < 2; ++rg)
#pragma unroll
            for (int j = 0; j < 3; ++j)
#pragma unroll
                for (int i = 0; i < 4; ++i) acc[rg][j][i] = 0.f;
        const int ord[6] = {3, 4, 5, 0, 1, 2};
#pragma unroll
        for (int x = 0; x < 6; ++x) {
            const int kc = ord[x];
            {
                int k0 = kc * 64 + o * 8;
                float v[8];
                if (kc >= 3 || k0 >= 176) {
#pragma unroll
                    for (int e = 0; e < 8; ++e) {
                        int k = k0 + e;
                        int q = k - 175;
                        v[e] = (k < 347) ? __cosf(fmaf(dlt, ldsBF[q], ldsPH[q])) : 0.f;
                    }
                } else if (k0 + 7 < 172) {
#pragma unroll
                    for (int e = 0; e < 8; ++e) v[e] = g[kc][e];
                } else {  // k0 == 168: edge[168..171], id[0..2], time_feat[0]
                    v[0]=g[2][0]; v[1]=g[2][1]; v[2]=g[2][2]; v[3]=g[2][3];
                    v[4]=eidv[0]; v[5]=eidv[1]; v[6]=eidv[2];
                    v[7]=__cosf(fmaf(dlt, ldsBF[0], ldsPH[0]));
                }
                frag_store<2>(AH[x & 1], AL[x & 1], r, o, v);
            }
            __syncthreads();
#pragma unroll
            for (int k2 = 0; k2 < 2; ++k2)
                mfma_step<2, 3>(AH[x & 1], AL[x & 1], p.W0h, 12,
                                kc * 2 + k2, k2, wv, lane, acc);
        }
#pragma unroll
        for (int j = 0; j < 3; ++j) {
            int col = (wv * 3 + j) * 16 + (lane & 15);
            if (col < 176) {
                float b = (col < 172) ? p.b0[col] : 0.f;
#pragma unroll
                for (int rg = 0; rg < 2; ++rg)
#pragma unroll
                    for (int i = 0; i < 4; ++i) {
                        int row = rg * 16 + ((lane >> 4) << 2) + i;
                        evL[row * 184 + col] = (_Float16)(acc[rg][j][i] + b);
                    }
            }
        }
    }
    __syncthreads();

    // ---- GEMM1 dual-dir: am0 = S+relu(T+ev), am1 = T+relu(S+ev) ----
    f32x4 a1[2][2][2];   // [dir][rg][j]
#pragma unroll
    for (int d = 0; d < 2; ++d)
#pragma unroll
        for (int rg = 0; rg < 2; ++rg)
#pragma unroll
            for (int j = 0; j < 2; ++j)
#pragma unroll
                for (int i = 0; i < 4; ++i) a1[d][rg][j][i] = 0.f;
    {
        float Ps[8], Pt[8];
        auto loadST = [&](int kc) {
            int k0 = kc * 64 + o * 8;
            if (k0 + 7 < 172) {
                *(float4*)&Ps[0] = *(const float4*)&S0[k0];
                *(float4*)&Ps[4] = *(const float4*)&S0[k0 + 4];
                *(float4*)&Pt[0] = *(const float4*)&T0[k0];
                *(float4*)&Pt[4] = *(const float4*)&T0[k0 + 4];
            } else if (k0 == 168) {
                *(float4*)&Ps[0] = *(const float4*)&S0[168];
                *(float4*)&Pt[0] = *(const float4*)&T0[168];
            }
        };
        loadST(0);
#pragma unroll
        for (int kc = 0; kc < 3; ++kc) {
            {
                int k0 = kc * 64 + o * 8;
                float v0[8], v1[8];
                if (k0 + 7 < 172) {
                    f16x8 e8 = *(const f16x8*)&evL[r * 184 + k0];
#pragma unroll
                    for (int e = 0; e < 8; ++e) {
                        float ev = (float)e8[e];
                        v0[e] = Ps[e] + fmaxf(Pt[e] + ev, 0.f);
                        v1[e] = Pt[e] + fmaxf(Ps[e] + ev, 0.f);
                    }
                } else if (k0 == 168) {
                    f16x8 e8 = *(const f16x8*)&evL[r * 184 + 168];
#pragma unroll
                    for (int e = 0; e < 8; ++e) {
                        if (e < 4) {
                            float ev = (float)e8[e];
                            v0[e] = Ps[e] + fmaxf(Pt[e] + ev, 0.f);
                            v1[e] = Pt[e] + fmaxf(Ps[e] + ev, 0.f);
                        } else { v0[e] = 0.f; v1[e] = 0.f; }
                    }
                } else {
#pragma unroll
                    for (int e = 0; e < 8; ++e) { v0[e] = 0.f; v1[e] = 0.f; }
                }
                frag_store<2>(AH[0], AL[0], r, o, v0);
                frag_store<2>(AH[1], AL[1], r, o, v1);
            }
            if (kc < 2) loadST(kc + 1);
            __syncthreads();
#pragma unroll
            for (int k2 = 0; k2 < 2; ++k2) {
                const int ks = kc * 2 + k2;
                f16x8 ah[2][2], al[2][2];
#pragma unroll
                for (int d = 0; d < 2; ++d)
#pragma unroll
                    for (int rg = 0; rg < 2; ++rg) {
                        int B = (k2 * 2 + rg) * 64 + lane;
                        int off = (B ^ ((B >> 4) & 7)) * 8;
                        ah[d][rg] = *(const f16x8*)&AH[d][off];
                        al[d][rg] = *(const f16x8*)&AL[d][off];
                    }
#pragma unroll
                for (int j = 0; j < 2; ++j) {
                    size_t boff = ((size_t)((wv * 2 + j) * 6 + ks) * 64 + lane) * 8;
                    f16x8 bh = *(const f16x8*)&p.W1h[boff];
#pragma unroll
                    for (int d = 0; d < 2; ++d)
#pragma unroll
                        for (int rg = 0; rg < 2; ++rg)
                            mma2a(ah[d][rg], al[d][rg], bh, a1[d][rg][j]);
                }
            }
            __syncthreads();
        }
    }

    // ---- per dir: h1 -> LDS fp16, then GEMM2 (direct frag loads, B hi-only) ----
    for (int dir = 0; dir < 2; ++dir) {
#pragma unroll
        for (int j = 0; j < 2; ++j) {
            int col = (wv * 2 + j) * 16 + (lane & 15);
            float b = p.b1[col];
#pragma unroll
            for (int rg = 0; rg < 2; ++rg)
#pragma unroll
                for (int i = 0; i < 4; ++i) {
                    int row = rg * 16 + ((lane >> 4) << 2) + i;
                    float x = a1[dir][rg][j][i] + b;
                    h1L[row * 136 + col] = (_Float16)(x > 0.f ? x : 0.f);
                }
        }
        __syncthreads();

        f32x4 a2[2][2];
#pragma unroll
        for (int rg = 0; rg < 2; ++rg)
#pragma unroll
            for (int j = 0; j < 2; ++j)
#pragma unroll
                for (int i = 0; i < 4; ++i) a2[rg][j][i] = 0.f;
#pragma unroll
        for (int ks = 0; ks < 4; ++ks) {
            const int k0 = ks * 32 + ((lane >> 4) << 3);
            f16x8 a4[2];
#pragma unroll
            for (int rg = 0; rg < 2; ++rg)
                a4[rg] = *(const f16x8*)&h1L[(rg * 16 + (lane & 15)) * 136 + k0];
#pragma unroll
            for (int j = 0; j < 2; ++j) {
                size_t boff = ((size_t)((wv * 2 + j) * 4 + ks) * 64 + lane) * 8;
                f16x8 bh = *(const f16x8*)&p.W2h[boff];
#pragma unroll
                for (int rg = 0; rg < 2; ++rg) mma1(a4[rg], bh, a2[rg][j]);
            }
        }
#pragma unroll
        for (int j = 0; j < 2; ++j) {
            int col = (wv * 2 + j) * 16 + (lane & 15);
            float b = p.b2[col];
#pragma unroll
            for (int rg = 0; rg < 2; ++rg)
#pragma unroll
                for (int i = 0; i < 4; ++i) {
                    int row = mtile + rg * 16 + ((lane >> 4) << 2) + i;
                    if (row < p.M)
                        p.upd[(size_t)row * 256 + dir * 128 + col] = (_Float16)(a2[rg][j][i] + b);
                }
        }
        if (dir == 0) __syncthreads();
    }
}

// ---------------- K2: fused attention + head (32 windows / block) ----------------
struct AttnP {
    const _Float16* upd;
    const _Float16 *W1h,*W2h,*M1h,*M2h,*F1h,*F2h;
    const float *ab1,*ab2,*am1b,*am2b,*fb1,*fb2,*fW3,*fb3;
    const float *time_idx,*cut,*cat; const double* acc;
    float* out; int nw; int win0;
};

__global__ __launch_bounds__(NTH) void k_attn(AttnP p) {
    __shared__ float R1[32 * 260];
    __shared__ _Float16 R2h[64 * 264];
    __shared__ _Float16 AH2[2][2048];
    __shared__ _Float16 AL[2048];
    __shared__ float scoreL[64], aL[64], finL[32];
    float* R2f = (float*)R2h;
    const int tid = threadIdx.x, wv = tid >> 6, lane = tid & 63;
    const int w0 = blockIdx.x * 32;
    const int rr = tid >> 3, o = tid & 7;
    if (tid < 64) scoreL[tid] = 0.f;
    if (tid < 32) finL[tid] = 0.f;
    __syncthreads();

    // ---- Phase A: wp = upd[w*3+2] @ at_W1 (double-buffered, B hi-only) ----
    {
        int lw = w0 + rr; if (lw >= p.nw) lw = p.nw - 1;
        const _Float16* Ar = p.upd + ((size_t)lw * 3 + 2) * 256;
        f32x4 acc[2][4];
#pragma unroll
        for (int rg = 0; rg < 2; ++rg)
#pragma unroll
            for (int j = 0; j < 4; ++j)
#pragma unroll
                for (int i = 0; i < 4; ++i) acc[rg][j][i] = 0.f;
        f16x8 P = *(const f16x8*)&Ar[o * 8];
#pragma unroll
        for (int kc = 0; kc < 4; ++kc) {
            frag_store_h<2>(AH2[kc & 1], rr, o, P);
            if (kc < 3) P = *(const f16x8*)&Ar[(kc + 1) * 64 + o * 8];
            __syncthreads();
#pragma unroll
            for (int k2 = 0; k2 < 2; ++k2)
                mfma_step_h<2, 4>(AH2[kc & 1], p.W1h, 8, kc * 2 + k2, k2, wv, lane, acc);
        }
#pragma unroll
        for (int j = 0; j < 4; ++j) {
            int col = (wv * 4 + j) * 16 + (lane & 15);
            float b = p.ab1[col];
#pragma unroll
            for (int rg = 0; rg < 2; ++rg)
#pragma unroll
                for (int i = 0; i < 4; ++i) {
                    int row = rg * 16 + ((lane >> 4) << 2) + i;
                    R1[row * 260 + col] = acc[rg][j][i] + b;
                }
        }
    }

    // ---- Phase B: wq (two 32-row subtiles) + score partials ----
    for (int st = 0; st < 2; ++st) {
        int g = st * 32 + rr;
        int lw = w0 + (g >> 1); if (lw >= p.nw) lw = p.nw - 1;
        const _Float16* Ar = p.upd + ((size_t)lw * 3 + (g & 1)) * 256;
        f32x4 acc[2][4];
#pragma unroll
        for (int rg = 0; rg < 2; ++rg)
#pragma unroll
            for (int j = 0; j < 4; ++j)
#pragma unroll
                for (int i = 0; i < 4; ++i) acc[rg][j][i] = 0.f;
        f16x8 P = *(const f16x8*)&Ar[o * 8];
#pragma unroll
        for (int kc = 0; kc < 4; ++kc) {
            frag_store_h<2>(AH2[kc & 1], rr, o, P);
            if (kc < 3) P = *(const f16x8*)&Ar[(kc + 1) * 64 + o * 8];
            __syncthreads();
#pragma unroll
            for (int k2 = 0; k2 < 2; ++k2)
                mfma_step_h<2, 4>(AH2[kc & 1], p.W2h, 8, kc * 2 + k2, k2, wv, lane, acc);
        }
        float scp[2][4];
#pragma unroll
        for (int rg = 0; rg < 2; ++rg)
#pragma unroll
            for (int i = 0; i < 4; ++i) scp[rg][i] = 0.f;
#pragma unroll
        for (int j = 0; j < 4; ++j) {
            int col = (wv * 4 + j) * 16 + (lane & 15);
            float b = p.ab2[col];
#pragma unroll
            for (int rg = 0; rg < 2; ++rg)
#pragma unroll
                for (int i = 0; i < 4; ++i) {
                    int row = rg * 16 + ((lane >> 4) << 2) + i;
                    int gg = st * 32 + row;
                    float v = acc[rg][j][i] + b;
                    R2h[gg * 264 + col] = (_Float16)v;
                    scp[rg][i] += v * R1[(gg >> 1) * 260 + col];
                }
        }
#pragma unroll
        for (int rg = 0; rg < 2; ++rg)
#pragma unroll
            for (int i = 0; i < 4; ++i) {
                float sv = scp[rg][i];
#pragma unroll
                for (int off = 1; off < 16; off <<= 1) sv += __shfl_xor(sv, off);
                if ((lane & 15) == 0) {
                    int gg = st * 32 + rg * 16 + ((lane >> 4) << 2) + i;
                    atomicAdd(&scoreL[gg], sv);
                }
            }
    }
    __syncthreads();

    // ---- Phase C: softmax alphas + outf build ----
    if (tid < 32) {
        int lw = w0 + tid; if (lw >= p.nw) lw = p.nw - 1;
        int gw = p.win0 + lw;
        const double n = (double)(NWIN_TOTAL * 2);
        float stdv = (float)sqrt((p.acc[1] - p.acc[0] * p.acc[0] / n) / (n - 1.0));
        float cutv = p.cut[gw >> 7];
        float d0 = fabsf(cutv - p.time_idx[gw * 3 + 0]);
        float d1 = fabsf(cutv - p.time_idx[gw * 3 + 1]);
        float tw0 = expf(-d0 / (stdv + 1e-6f));
        float tw1 = expf(-d1 / (stdv + 1e-6f));
        float s0 = scoreL[tid * 2 + 0] * (0.7f + 0.3f * tw0);
        float s1 = scoreL[tid * 2 + 1] * (0.7f + 0.3f * tw1);
        float m = fmaxf(s0, s1);
        float e0 = expf(s0 - m), e1 = expf(s1 - m);
        float inv = 1.f / (e0 + e1);
        aL[tid * 2 + 0] = e0 * inv;
        aL[tid * 2 + 1] = e1 * inv;
    }
    __syncthreads();
    for (int q = tid; q < 32 * 256; q += NTH) {
        int r = q >> 8, c = q & 255;
        int lw = w0 + r; if (lw >= p.nw) lw = p.nw - 1;
        float u2 = (float)p.upd[((size_t)lw * 3 + 2) * 256 + c];
        R1[r * 260 + c] = u2 + aL[r * 2] * (float)R2h[(r * 2) * 264 + c]
                             + aL[r * 2 + 1] * (float)R2h[(r * 2 + 1) * 264 + c];
    }

    // ---- Phase D: h2 = relu(outf @ at_m1W) -> R2f[32][132] ----
    {
        f32x4 acc[2][2];
#pragma unroll
        for (int rg = 0; rg < 2; ++rg)
#pragma unroll
            for (int j = 0; j < 2; ++j)
#pragma unroll
                for (int i = 0; i < 4; ++i) acc[rg][j][i] = 0.f;
        for (int kc = 0; kc < 4; ++kc) {
            __syncthreads();
            {
                int k0 = kc * 64 + o * 8;
                float v[8];
                float4 x = *(const float4*)&R1[rr * 260 + k0];
                float4 y = *(const float4*)&R1[rr * 260 + k0 + 4];
                v[0]=x.x; v[1]=x.y; v[2]=x.z; v[3]=x.w;
                v[4]=y.x; v[5]=y.y; v[6]=y.z; v[7]=y.w;
                frag_store<2>(AH2[0], AL, rr, o, v);
            }
            __syncthreads();
#pragma unroll
            for (int k2 = 0; k2 < 2; ++k2)
                mfma_step<2, 2>(AH2[0], AL, p.M1h, 8, kc * 2 + k2, k2, wv, lane, acc);
        }
        __syncthreads();
#pragma unroll
        for (int j = 0; j < 2; ++j) {
            int col = (wv * 2 + j) * 16 + (lane & 15);
            float b = p.am1b[col];
#pragma unroll
            for (int rg = 0; rg < 2; ++rg)
#pragma unroll
                for (int i = 0; i < 4; ++i) {
                    int row = rg * 16 + ((lane >> 4) << 2) + i;
                    float x = acc[rg][j][i] + b;
                    R2f[row * 132 + col] = x > 0.f ? x : 0.f;
                }
        }
    }
    __syncthreads();

    // xz extra cols (stride 196)
    for (int q = tid; q < 32 * 68; q += NTH) {
        int r = q / 68, c = 128 + q % 68;
        int lw = w0 + r; if (lw >= p.nw) lw = p.nw - 1;
        int gw = p.win0 + lw;
        R1[r * 196 + c] = (c < 140) ? p.cat[(size_t)gw * 12 + (c - 128)] : 0.f;
    }

    // ---- Phase E: h3 = h2 @ at_m2W -> R1 stride 196 cols 0..127 ----
    {
        f32x4 acc[2][2];
#pragma unroll
        for (int rg = 0; rg < 2; ++rg)
#pragma unroll
            for (int j = 0; j < 2; ++j)
#pragma unroll
                for (int i = 0; i < 4; ++i) acc[rg][j][i] = 0.f;
        for (int kc = 0; kc < 2; ++kc) {
            __syncthreads();
            {
                int k0 = kc * 64 + o * 8;
                float v[8];
                float4 x = *(const float4*)&R2f[rr * 132 + k0];
                float4 y = *(const float4*)&R2f[rr * 132 + k0 + 4];
                v[0]=x.x; v[1]=x.y; v[2]=x.z; v[3]=x.w;
                v[4]=y.x; v[5]=y.y; v[6]=y.z; v[7]=y.w;
                frag_store<2>(AH2[0], AL, rr, o, v);
            }
            __syncthreads();
#pragma unroll
            for (int k2 = 0; k2 < 2; ++k2)
                mfma_step<2, 2>(AH2[0], AL, p.M2h, 4, kc * 2 + k2, k2, wv, lane, acc);
        }
        __syncthreads();
#pragma unroll
        for (int j = 0; j < 2; ++j) {
            int col = (wv * 2 + j) * 16 + (lane & 15);
            float b = p.am2b[col];
#pragma unroll
            for (int rg = 0; rg < 2; ++rg)
#pragma unroll
                for (int i = 0; i < 4; ++i) {
                    int row = rg * 16 + ((lane >> 4) << 2) + i;
                    R1[row * 196 + col] = acc[rg][j][i] + b;
                }
        }
    }

    // ---- Phase F: z1 = relu(xz @ f_W1) -> R2f stride 196 ----
    {
        f32x4 acc[2][3];
#pragma unroll
        for (int rg = 0; rg < 2; ++rg)
#pragma unroll
            for (int j = 0; j < 3; ++j)
#pragma unroll
                for (int i = 0; i < 4; ++i) acc[rg][j][i] = 0.f;
        for (int kc = 0; kc < 3; ++kc) {
            __syncthreads();
            {
                int k0 = kc * 64 + o * 8;
                float v[8];
                float4 x = *(const float4*)&R1[rr * 196 + k0];
                float4 y = *(const float4*)&R1[rr * 196 + k0 + 4];
                v[0]=x.x; v[1]=x.y; v[2]=x.z; v[3]=x.w;
                v[4]=y.x; v[5]=y.y; v[6]=y.z; v[7]=y.w;
                frag_store<2>(AH2[0], AL, rr, o, v);
            }
            __syncthreads();
#pragma unroll
            for (int k2 = 0; k2 < 2; ++k2)
                mfma_step<2, 3>(AH2[0], AL, p.F1h, 6, kc * 2 + k2, k2, wv, lane, acc);
        }
        __syncthreads();
#pragma unroll
        for (int j = 0; j < 3; ++j) {
            int col = (wv * 3 + j) * 16 + (lane & 15);
            float b = (col < 140) ? p.fb1[col] : 0.f;
#pragma unroll
            for (int rg = 0; rg < 2; ++rg)
#pragma unroll
                for (int i = 0; i < 4; ++i) {
                    int row = rg * 16 + ((lane >> 4) << 2) + i;
                    float x = acc[rg][j][i] + b;
                    R2f[row * 196 + col] = x > 0.f ? x : 0.f;
                }
        }
    }

    // ---- Phase G: z2 = relu(z1 @ f_W2) fused with final dot ----
    {
        f32x4 acc[2][2];
#pragma unroll
        for (int rg = 0; rg < 2; ++rg)
#pragma unroll
            for (int j = 0; j < 2; ++j)
#pragma unroll
                for (int i = 0; i < 4; ++i) acc[rg][j][i] = 0.f;
        for (int kc = 0; kc < 3; ++kc) {
            __syncthreads();
            {
                int k0 = kc * 64 + o * 8;
                float v[8];
                float4 x = *(const float4*)&R2f[rr * 196 + k0];
                float4 y = *(const float4*)&R2f[rr * 196 + k0 + 4];
                v[0]=x.x; v[1]=x.y; v[2]=x.z; v[3]=x.w;
                v[4]=y.x; v[5]=y.y; v[6]=y.z; v[7]=y.w;
                frag_store<2>(AH2[0], AL, rr, o, v);
            }
            __syncthreads();
#pragma unroll
            for (int k2 = 0; k2 < 2; ++k2)
                mfma_step<2, 2>(AH2[0], AL, p.F2h, 6, kc * 2 + k2, k2, wv, lane, acc);
        }
        float pt[2][4];
#pragma unroll
        for (int rg = 0; rg < 2; ++rg)
#pragma unroll
            for (int i = 0; i < 4; ++i) pt[rg][i] = 0.f;
#pragma unroll
        for (int j = 0; j < 2; ++j) {
            int col = (wv * 2 + j) * 16 + (lane & 15);
            float b = p.fb2[col];
            float w3 = p.fW3[col];
#pragma unroll
            for (int rg = 0; rg < 2; ++rg)
#pragma unroll
                for (int i = 0; i < 4; ++i) {
                    float x = acc[rg][j][i] + b;
                    x = x > 0.f ? x : 0.f;
                    pt[rg][i] += x * w3;
                }
        }
#pragma unroll
        for (int rg = 0; rg < 2; ++rg)
#pragma unroll
            for (int i = 0; i < 4; ++i) {
                float sv = pt[rg][i];
#pragma unroll
                for (int off = 1; off < 16; off <<= 1) sv += __shfl_xor(sv, off);
                if ((lane & 15) == 0)
                    atomicAdd(&finL[rg * 16 + ((lane >> 4) << 2) + i], sv);
            }
    }
    __syncthreads();
    if (tid < 32 && w0 + tid < p.nw)
        p.out[p.win0 + w0 + tid] = finL[tid] + p.fb3[0];
}

extern "C" void kernel_launch(void* const* d_in, const int* in_sizes, int n_in,
                              void* d_out, int out_size, void* d_ws, size_t ws_size,
                              hipStream_t stream) {
    const float* node_table    = (const float*)d_in[0];
    const float* edge_table    = (const float*)d_in[1];
    const float* basis_freq    = (const float*)d_in[2];
    const float* phase         = (const float*)d_in[3];
    const float* ev_W          = (const float*)d_in[4];
    const float* ev_b          = (const float*)d_in[5];
    const float* ev_m1W        = (const float*)d_in[6];
    const float* ev_m1b        = (const float*)d_in[7];
    const float* ev_m2W        = (const float*)d_in[8];
    const float* ev_m2b        = (const float*)d_in[9];
    const float* at_W1         = (const float*)d_in[10];
    const float* at_b1         = (const float*)d_in[11];
    const float* at_W2         = (const float*)d_in[12];
    const float* at_b2         = (const float*)d_in[13];
    const float* at_m1W        = (const float*)d_in[14];
    const float* at_m1b        = (const float*)d_in[15];
    const float* at_m2W        = (const float*)d_in[16];
    const float* at_m2b        = (const float*)d_in[17];
    const float* f_W1          = (const float*)d_in[18];
    const float* f_b1          = (const float*)d_in[19];
    const float* f_W2          = (const float*)d_in[20];
    const float* f_b2          = (const float*)d_in[21];
    const float* f_W3          = (const float*)d_in[22];
    const float* f_b3          = (const float*)d_in[23];
    const float* time_idx      = (const float*)d_in[24];
    const float* cut_time_l    = (const float*)d_in[25];
    const float* cat_feat      = (const float*)d_in[26];
    const float* edge_identify = (const float*)d_in[27];
    const int*   node_idx      = (const int*)d_in[28];
    const int*   edge_idx      = (const int*)d_in[29];

    char* wsb = (char*)d_ws;
    double* acc = (double*)wsb;

    const int   wkp[9] = {384, 192, 128, 256, 256, 256, 128, 192, 192};
    const int   wnp[9] = {192, 128, 128, 256, 256, 128, 128, 192, 128};
    const int   wkt[9] = {347, 172, 128, 256, 256, 256, 128, 140, 140};
    const int   wnt[9] = {172, 128, 128, 256, 256, 128, 128, 140, 128};
    const float* wsrc[9] = {ev_W, ev_m1W, ev_m2W, at_W1, at_W2, at_m1W, at_m2W, f_W1, f_W2};
    _Float16* wH[9];
    size_t woff = 256;
    WAll wa = {};
    int cum = 0;
    for (int i = 0; i < 9; ++i) {
        size_t plane = (size_t)wkp[i] * wnp[i];
        wH[i] = (_Float16*)(wsb + woff);
        woff += plane * sizeof(_Float16);
        woff = (woff + 15) & ~(size_t)15;
        wa.w[i].src = wsrc[i]; wa.w[i].dH = wH[i];
        wa.w[i].Kt = wkt[i]; wa.w[i].Nt = wnt[i]; wa.w[i].Kp = wkp[i]; wa.w[i].Np = wnp[i];
        wa.w[i].off = cum;
        cum += (wnp[i] / 16) * (wkp[i] / 32) * 64;
    }
    wa.grand = cum;

    hipMemsetAsync(d_ws, 0, 16, stream);
    k_std<<<64, NTH, 0, stream>>>(time_idx, cut_time_l, acc);
    k_wprep_all<<<CDIV(wa.grand, NTH), NTH, 0, stream>>>(wa);

    size_t avail = ws_size > woff + 4096 ? ws_size - woff - 4096 : 0;
    size_t nwc_s = avail / 1536;
    int nwc = (int)(nwc_s > NWIN_TOTAL ? NWIN_TOTAL : nwc_s);
    if (nwc < 1) nwc = 1;
    _Float16* updB = (_Float16*)(wsb + ((woff + 255) & ~(size_t)255));

    for (int c0 = 0; c0 < NWIN_TOTAL; c0 += nwc) {
        int nw = NWIN_TOTAL - c0 < nwc ? NWIN_TOTAL - c0 : nwc;
        int M3 = nw * 3;

        GCP gc = {};
        gc.W0h = wH[0]; gc.W1h = wH[1]; gc.W2h = wH[2];
        gc.b0 = ev_b; gc.b1 = ev_m1b; gc.b2 = ev_m2b;
        gc.upd = updB; gc.M = M3; gc.win0 = c0;
        gc.edge_table = edge_table; gc.node_table = node_table;
        gc.basis_freq = basis_freq; gc.phase = phase;
        gc.time_idx = time_idx; gc.cut = cut_time_l;
        gc.edge_idx = edge_idx; gc.node_idx = node_idx; gc.eid = edge_identify;
        k_gc<<<CDIV(M3, 32), NTH, 0, stream>>>(gc);

        AttnP ap = {};
        ap.upd = updB;
        ap.W1h = wH[3]; ap.W2h = wH[4];
        ap.M1h = wH[5]; ap.M2h = wH[6];
        ap.F1h = wH[7]; ap.F2h = wH[8];
        ap.ab1 = at_b1; ap.ab2 = at_b2; ap.am1b = at_m1b; ap.am2b = at_m2b;
        ap.fb1 = f_b1; ap.fb2 = f_b2; ap.fW3 = f_W3; ap.fb3 = f_b3;
        ap.time_idx = time_idx; ap.cut = cut_time_l; ap.cat = cat_feat; ap.acc = acc;
        ap.out = (float*)d_out; ap.nw = nw; ap.win0 = c0;
        k_attn<<<CDIV(nw, 32), NTH, 0, stream>>>(ap);
    }
}

// Round 19
// 167.045 us; speedup vs baseline: 1.5950x; 1.1062x over previous
//
#include <hip/hip_runtime.h>
#include <math.h>

#define NWIN_TOTAL (256 * 128)
#define NTH 256
#define CDIV(a, b) (((a) + (b) - 1) / (b))

typedef _Float16 f16x8 __attribute__((ext_vector_type(8)));
typedef float f32x4 __attribute__((ext_vector_type(4)));

// hi-only A and B (both lo-planes measured below fp16-storage error floor)
__device__ __forceinline__ void mma1(f16x8 a, f16x8 bh, f32x4& c) {
    c = __builtin_amdgcn_mfma_f32_16x16x32_f16(a, bh, c, 0, 0, 0);
}

__device__ __forceinline__ void mma2a(f16x8 ah, f16x8 al, f16x8 bh, f32x4& c) {
    c = __builtin_amdgcn_mfma_f32_16x16x32_f16(al, bh, c, 0, 0, 0);
    c = __builtin_amdgcn_mfma_f32_16x16x32_f16(ah, bh, c, 0, 0, 0);
}

// ---------------- global std ----------------
__global__ __launch_bounds__(NTH) void k_std(const float* __restrict__ time_idx,
                                             const float* __restrict__ cut,
                                             double* __restrict__ acc) {
    int tid = threadIdx.x;
    const int n = NWIN_TOTAL * 2;
    double s = 0.0, s2 = 0.0;
    for (int i = blockIdx.x * blockDim.x + tid; i < n; i += gridDim.x * blockDim.x) {
        int j = i & 1;
        int bw = i >> 1;
        float d = fabsf(cut[bw >> 7] - time_idx[bw * 3 + j]);
        s += (double)d;
        s2 += (double)d * (double)d;
    }
    __shared__ double ls[NTH], ls2[NTH];
    ls[tid] = s; ls2[tid] = s2;
    __syncthreads();
    for (int st = NTH / 2; st > 0; st >>= 1) {
        if (tid < st) { ls[tid] += ls[tid + st]; ls2[tid] += ls2[tid + st]; }
        __syncthreads();
    }
    if (tid == 0) { atomicAdd(&acc[0], ls[0]); atomicAdd(&acc[1], ls2[0]); }
}

// ---------------- all weights -> B-fragment hi plane only (one launch) ----------------
struct WEnt { const float* src; _Float16* dH; int Kt, Nt, Kp, Np, off; };
struct WAll { WEnt w[9]; int grand; };

__global__ __launch_bounds__(NTH) void k_wprep_all(WAll a) {
    int idx = blockIdx.x * NTH + threadIdx.x;
    if (idx >= a.grand) return;
    int i = 0;
#pragma unroll
    for (int t = 0; t < 8; ++t)
        if (i + 1 < 9 && idx >= a.w[i + 1].off) ++i;
    const WEnt& e = a.w[i];
    int lidx = idx - e.off;
    int nks = e.Kp / 32;
    int cg = lidx / (nks * 64);
    int rem = lidx - cg * nks * 64;
    int ks = rem >> 6, lane = rem & 63;
    int col = cg * 16 + (lane & 15);
    for (int j = 0; j < 8; ++j) {
        int k = ks * 32 + ((lane >> 4) << 3) + j;
        float v = (k < e.Kt && col < e.Nt) ? e.src[(size_t)k * e.Nt + col] : 0.f;
        e.dH[(size_t)lidx * 8 + j] = (_Float16)v;
    }
}

// ---------------- frag helpers (swizzled: B ^= (B>>4)&7) ----------------
template <int RG>
__device__ __forceinline__ void frag_store(_Float16* AH, _Float16* AL, int r, int o,
                                           const float* v) {
    int B = ((o >> 2) * RG + (r >> 4)) * 64 + ((r & 15) | ((o & 3) << 4));
    int off = (B ^ ((B >> 4) & 7)) * 8;
    f16x8 h8, l8;
#pragma unroll
    for (int e = 0; e < 8; ++e) {
        _Float16 h = (_Float16)v[e];
        h8[e] = h;
        l8[e] = (_Float16)(v[e] - (float)h);
    }
    *(f16x8*)&AH[off] = h8;
    *(f16x8*)&AL[off] = l8;
}

template <int RG>
__device__ __forceinline__ void frag_store_hf(_Float16* AH, int r, int o,
                                              const float* v) {
    int B = ((o >> 2) * RG + (r >> 4)) * 64 + ((r & 15) | ((o & 3) << 4));
    int off = (B ^ ((B >> 4) & 7)) * 8;
    f16x8 h8;
#pragma unroll
    for (int e = 0; e < 8; ++e) h8[e] = (_Float16)v[e];
    *(f16x8*)&AH[off] = h8;
}

template <int RG>
__device__ __forceinline__ void frag_store_h(_Float16* AH, int r, int o, f16x8 v) {
    int B = ((o >> 2) * RG + (r >> 4)) * 64 + ((r & 15) | ((o & 3) << 4));
    int off = (B ^ ((B >> 4) & 7)) * 8;
    *(f16x8*)&AH[off] = v;
}

// A split (hi+lo), B hi-only: 2 MFMA per (rg,j) — used in k_attn D-G
template <int RG, int NREP>
__device__ __forceinline__ void mfma_step(const _Float16* AH, const _Float16* AL,
                                          const _Float16* __restrict__ Wh,
                                          int nks, int ks, int k2, int wv, int lane,
                                          f32x4 (&acc)[RG][NREP]) {
    f16x8 ah[RG], al[RG];
#pragma unroll
    for (int rg = 0; rg < RG; ++rg) {
        int B = (k2 * RG + rg) * 64 + lane;
        int off = (B ^ ((B >> 4) & 7)) * 8;
        ah[rg] = *(const f16x8*)&AH[off];
        al[rg] = *(const f16x8*)&AL[off];
    }
#pragma unroll
    for (int j = 0; j < NREP; ++j) {
        int cg = wv * NREP + j;
        size_t boff = ((size_t)(cg * nks + ks) * 64 + lane) * 8;
        f16x8 bh = *(const f16x8*)&Wh[boff];
#pragma unroll
        for (int rg = 0; rg < RG; ++rg) mma2a(ah[rg], al[rg], bh, acc[rg][j]);
    }
}

// A hi-only staged, B hi-only: 1 MFMA per (rg,j)
template <int RG, int NREP>
__device__ __forceinline__ void mfma_step_h(const _Float16* AH,
                                            const _Float16* __restrict__ Wh,
                                            int nks, int ks, int k2, int wv, int lane,
                                            f32x4 (&acc)[RG][NREP]) {
    f16x8 ah[RG];
#pragma unroll
    for (int rg = 0; rg < RG; ++rg) {
        int B = (k2 * RG + rg) * 64 + lane;
        int off = (B ^ ((B >> 4) & 7)) * 8;
        ah[rg] = *(const f16x8*)&AH[off];
    }
#pragma unroll
    for (int j = 0; j < NREP; ++j) {
        int cg = wv * NREP + j;
        size_t boff = ((size_t)(cg * nks + ks) * 64 + lane) * 8;
        f16x8 bh = *(const f16x8*)&Wh[boff];
#pragma unroll
        for (int rg = 0; rg < RG; ++rg) mma1(ah[rg], bh, acc[rg][j]);
    }
}

// ---------------- K1: fused G1 + conv (dual-dir GEMM1, hi-only A and B) ----------------
struct GCP {
    const _Float16 *W0h, *W1h, *W2h;
    const float *b0, *b1, *b2;
    _Float16* upd; int M; int win0;
    const float* edge_table; const float* node_table;
    const float* basis_freq; const float* phase;
    const float* time_idx; const float* cut;
    const int* edge_idx; const int* node_idx; const float* eid;
};

__global__ __launch_bounds__(NTH) void k_gc(GCP p) {
    __shared__ _Float16 AH[2][2048];     // phase1: double-buffer; conv: per-dir
    __shared__ _Float16 evL[32 * 184];
    __shared__ _Float16 h1L[32 * 136];
    __shared__ float ldsBF[176], ldsPH[176];
    const int tid = threadIdx.x, wv = tid >> 6, lane = tid & 63;
    const int mtile = blockIdx.x * 32;
    const int o = tid & 7, r = tid >> 3;

    if (tid < 172) { ldsBF[tid] = p.basis_freq[tid]; ldsPH[tid] = p.phase[tid]; }

    int grow = mtile + r; if (grow >= p.M) grow = p.M - 1;
    int w3 = grow / 3, l = grow - w3 * 3;
    int gw = p.win0 + w3;
    int nb = gw * 6 + 2 * l;
    const float* er = p.edge_table + (size_t)p.edge_idx[gw * 3 + l] * 172;
    const float* S0 = p.node_table + (size_t)p.node_idx[nb] * 172;
    const float* T0 = p.node_table + (size_t)p.node_idx[nb + 1] * 172;
    float dlt = p.cut[gw >> 7] - p.time_idx[gw * 3 + l];
    float g[3][8]; float eidv[3];
#pragma unroll
    for (int kc = 0; kc < 3; ++kc) {
        int k0 = kc * 64 + o * 8;
        if (k0 + 7 < 172) {
            float4 x = *(const float4*)&er[k0];
            float4 y = *(const float4*)&er[k0 + 4];
            g[kc][0]=x.x; g[kc][1]=x.y; g[kc][2]=x.z; g[kc][3]=x.w;
            g[kc][4]=y.x; g[kc][5]=y.y; g[kc][6]=y.z; g[kc][7]=y.w;
        } else if (k0 == 168) {
            float4 x = *(const float4*)&er[168];
            g[kc][0]=x.x; g[kc][1]=x.y; g[kc][2]=x.z; g[kc][3]=x.w;
            eidv[0] = p.eid[(gw * 3 + l) * 3 + 0];
            eidv[1] = p.eid[(gw * 3 + l) * 3 + 1];
            eidv[2] = p.eid[(gw * 3 + l) * 3 + 2];
        }
    }
    __syncthreads();   // ldsBF/PH ready

    // ---- Phase 1: ev = evt @ ev_W  (K=384, N=192), double-buffered, hi-only ----
    {
        f32x4 acc[2][3];
#pragma unroll
        for (int rg = 0; rg < 2; ++rg)
#pragma unroll
            for (int j = 0; j < 3; ++j)
#pragma unroll
                for (int i = 0; i < 4; ++i) acc[rg][j][i] = 0.f;
        const int ord[6] = {3, 4, 5, 0, 1, 2};
#pragma unroll
        for (int x = 0; x < 6; ++x) {
            const int kc = ord[x];
            {
                int k0 = kc * 64 + o * 8;
                float v[8];
                if (kc >= 3 || k0 >= 176) {
#pragma unroll
                    for (int e = 0; e < 8; ++e) {
                        int k = k0 + e;
                        int q = k - 175;
                        v[e] = (k < 347) ? __cosf(fmaf(dlt, ldsBF[q], ldsPH[q])) : 0.f;
                    }
                } else if (k0 + 7 < 172) {
#pragma unroll
                    for (int e = 0; e < 8; ++e) v[e] = g[kc][e];
                } else {  // k0 == 168: edge[168..171], id[0..2], time_feat[0]
                    v[0]=g[2][0]; v[1]=g[2][1]; v[2]=g[2][2]; v[3]=g[2][3];
                    v[4]=eidv[0]; v[5]=eidv[1]; v[6]=eidv[2];
                    v[7]=__cosf(fmaf(dlt, ldsBF[0], ldsPH[0]));
                }
                frag_store_hf<2>(AH[x & 1], r, o, v);
            }
            __syncthreads();
#pragma unroll
            for (int k2 = 0; k2 < 2; ++k2)
                mfma_step_h<2, 3>(AH[x & 1], p.W0h, 12,
                                  kc * 2 + k2, k2, wv, lane, acc);
        }
#pragma unroll
        for (int j = 0; j < 3; ++j) {
            int col = (wv * 3 + j) * 16 + (lane & 15);
            if (col < 176) {
                float b = (col < 172) ? p.b0[col] : 0.f;
#pragma unroll
                for (int rg = 0; rg < 2; ++rg)
#pragma unroll
                    for (int i = 0; i < 4; ++i) {
                        int row = rg * 16 + ((lane >> 4) << 2) + i;
                        evL[row * 184 + col] = (_Float16)(acc[rg][j][i] + b);
                    }
            }
        }
    }
    __syncthreads();

    // ---- GEMM1 dual-dir: am0 = S+relu(T+ev), am1 = T+relu(S+ev), hi-only ----
    f32x4 a1[2][2][2];   // [dir][rg][j]
#pragma unroll
    for (int d = 0; d < 2; ++d)
#pragma unroll
        for (int rg = 0; rg < 2; ++rg)
#pragma unroll
            for (int j = 0; j < 2; ++j)
#pragma unroll
                for (int i = 0; i < 4; ++i) a1[d][rg][j][i] = 0.f;
    {
        float Ps[8], Pt[8];
        auto loadST = [&](int kc) {
            int k0 = kc * 64 + o * 8;
            if (k0 + 7 < 172) {
                *(float4*)&Ps[0] = *(const float4*)&S0[k0];
                *(float4*)&Ps[4] = *(const float4*)&S0[k0 + 4];
                *(float4*)&Pt[0] = *(const float4*)&T0[k0];
                *(float4*)&Pt[4] = *(const float4*)&T0[k0 + 4];
            } else if (k0 == 168) {
                *(float4*)&Ps[0] = *(const float4*)&S0[168];
                *(float4*)&Pt[0] = *(const float4*)&T0[168];
            }
        };
        loadST(0);
#pragma unroll
        for (int kc = 0; kc < 3; ++kc) {
            {
                int k0 = kc * 64 + o * 8;
                float v0[8], v1[8];
                if (k0 + 7 < 172) {
                    f16x8 e8 = *(const f16x8*)&evL[r * 184 + k0];
#pragma unroll
                    for (int e = 0; e < 8; ++e) {
                        float ev = (float)e8[e];
                        v0[e] = Ps[e] + fmaxf(Pt[e] + ev, 0.f);
                        v1[e] = Pt[e] + fmaxf(Ps[e] + ev, 0.f);
                    }
                } else if (k0 == 168) {
                    f16x8 e8 = *(const f16x8*)&evL[r * 184 + 168];
#pragma unroll
                    for (int e = 0; e < 8; ++e) {
                        if (e < 4) {
                            float ev = (float)e8[e];
                            v0[e] = Ps[e] + fmaxf(Pt[e] + ev, 0.f);
                            v1[e] = Pt[e] + fmaxf(Ps[e] + ev, 0.f);
                        } else { v0[e] = 0.f; v1[e] = 0.f; }
                    }
                } else {
#pragma unroll
                    for (int e = 0; e < 8; ++e) { v0[e] = 0.f; v1[e] = 0.f; }
                }
                frag_store_hf<2>(AH[0], r, o, v0);
                frag_store_hf<2>(AH[1], r, o, v1);
            }
            if (kc < 2) loadST(kc + 1);
            __syncthreads();
#pragma unroll
            for (int k2 = 0; k2 < 2; ++k2) {
                const int ks = kc * 2 + k2;
                f16x8 ah[2][2];
#pragma unroll
                for (int d = 0; d < 2; ++d)
#pragma unroll
                    for (int rg = 0; rg < 2; ++rg) {
                        int B = (k2 * 2 + rg) * 64 + lane;
                        int off = (B ^ ((B >> 4) & 7)) * 8;
                        ah[d][rg] = *(const f16x8*)&AH[d][off];
                    }
#pragma unroll
                for (int j = 0; j < 2; ++j) {
                    size_t boff = ((size_t)((wv * 2 + j) * 6 + ks) * 64 + lane) * 8;
                    f16x8 bh = *(const f16x8*)&p.W1h[boff];
#pragma unroll
                    for (int d = 0; d < 2; ++d)
#pragma unroll
                        for (int rg = 0; rg < 2; ++rg)
                            mma1(ah[d][rg], bh, a1[d][rg][j]);
                }
            }
            __syncthreads();
        }
    }

    // ---- per dir: h1 -> LDS fp16, then GEMM2 (direct frag loads, hi-only) ----
    for (int dir = 0; dir < 2; ++dir) {
#pragma unroll
        for (int j = 0; j < 2; ++j) {
            int col = (wv * 2 + j) * 16 + (lane & 15);
            float b = p.b1[col];
#pragma unroll
            for (int rg = 0; rg < 2; ++rg)
#pragma unroll
                for (int i = 0; i < 4; ++i) {
                    int row = rg * 16 + ((lane >> 4) << 2) + i;
                    float x = a1[dir][rg][j][i] + b;
                    h1L[row * 136 + col] = (_Float16)(x > 0.f ? x : 0.f);
                }
        }
        __syncthreads();

        f32x4 a2[2][2];
#pragma unroll
        for (int rg = 0; rg < 2; ++rg)
#pragma unroll
            for (int j = 0; j < 2; ++j)
#pragma unroll
                for (int i = 0; i < 4; ++i) a2[rg][j][i] = 0.f;
#pragma unroll
        for (int ks = 0; ks < 4; ++ks) {
            const int k0 = ks * 32 + ((lane >> 4) << 3);
            f16x8 a4[2];
#pragma unroll
            for (int rg = 0; rg < 2; ++rg)
                a4[rg] = *(const f16x8*)&h1L[(rg * 16 + (lane & 15)) * 136 + k0];
#pragma unroll
            for (int j = 0; j < 2; ++j) {
                size_t boff = ((size_t)((wv * 2 + j) * 4 + ks) * 64 + lane) * 8;
                f16x8 bh = *(const f16x8*)&p.W2h[boff];
#pragma unroll
                for (int rg = 0; rg < 2; ++rg) mma1(a4[rg], bh, a2[rg][j]);
            }
        }
#pragma unroll
        for (int j = 0; j < 2; ++j) {
            int col = (wv * 2 + j) * 16 + (lane & 15);
            float b = p.b2[col];
#pragma unroll
            for (int rg = 0; rg < 2; ++rg)
#pragma unroll
                for (int i = 0; i < 4; ++i) {
                    int row = mtile + rg * 16 + ((lane >> 4) << 2) + i;
                    if (row < p.M)
                        p.upd[(size_t)row * 256 + dir * 128 + col] = (_Float16)(a2[rg][j][i] + b);
                }
        }
        if (dir == 0) __syncthreads();
    }
}

// ---------------- K2: fused attention + head (32 windows / block) ----------------
struct AttnP {
    const _Float16* upd;
    const _Float16 *W1h,*W2h,*M1h,*M2h,*F1h,*F2h;
    const float *ab1,*ab2,*am1b,*am2b,*fb1,*fb2,*fW3,*fb3;
    const float *time_idx,*cut,*cat; const double* acc;
    float* out; int nw; int win0;
};

__global__ __launch_bounds__(NTH) void k_attn(AttnP p) {
    __shared__ float R1[32 * 260];
    __shared__ _Float16 R2h[64 * 264];
    __shared__ _Float16 AH2[2][2048];
    __shared__ _Float16 AL[2048];
    __shared__ float scoreL[64], aL[64], finL[32];
    float* R2f = (float*)R2h;
    const int tid = threadIdx.x, wv = tid >> 6, lane = tid & 63;
    const int w0 = blockIdx.x * 32;
    const int rr = tid >> 3, o = tid & 7;
    if (tid < 64) scoreL[tid] = 0.f;
    if (tid < 32) finL[tid] = 0.f;
    __syncthreads();

    // ---- Phase A: wp = upd[w*3+2] @ at_W1 (double-buffered, B hi-only) ----
    {
        int lw = w0 + rr; if (lw >= p.nw) lw = p.nw - 1;
        const _Float16* Ar = p.upd + ((size_t)lw * 3 + 2) * 256;
        f32x4 acc[2][4];
#pragma unroll
        for (int rg = 0; rg < 2; ++rg)
#pragma unroll
            for (int j = 0; j < 4; ++j)
#pragma unroll
                for (int i = 0; i < 4; ++i) acc[rg][j][i] = 0.f;
        f16x8 P = *(const f16x8*)&Ar[o * 8];
#pragma unroll
        for (int kc = 0; kc < 4; ++kc) {
            frag_store_h<2>(AH2[kc & 1], rr, o, P);
            if (kc < 3) P = *(const f16x8*)&Ar[(kc + 1) * 64 + o * 8];
            __syncthreads();
#pragma unroll
            for (int k2 = 0; k2 < 2; ++k2)
                mfma_step_h<2, 4>(AH2[kc & 1], p.W1h, 8, kc * 2 + k2, k2, wv, lane, acc);
        }
#pragma unroll
        for (int j = 0; j < 4; ++j) {
            int col = (wv * 4 + j) * 16 + (lane & 15);
            float b = p.ab1[col];
#pragma unroll
            for (int rg = 0; rg < 2; ++rg)
#pragma unroll
                for (int i = 0; i < 4; ++i) {
                    int row = rg * 16 + ((lane >> 4) << 2) + i;
                    R1[row * 260 + col] = acc[rg][j][i] + b;
                }
        }
    }

    // ---- Phase B: wq (two 32-row subtiles) + score partials ----
    for (int st = 0; st < 2; ++st) {
        int g = st * 32 + rr;
        int lw = w0 + (g >> 1); if (lw >= p.nw) lw = p.nw - 1;
        const _Float16* Ar = p.upd + ((size_t)lw * 3 + (g & 1)) * 256;
        f32x4 acc[2][4];
#pragma unroll
        for (int rg = 0; rg < 2; ++rg)
#pragma unroll
            for (int j = 0; j < 4; ++j)
#pragma unroll
                for (int i = 0; i < 4; ++i) acc[rg][j][i] = 0.f;
        f16x8 P = *(const f16x8*)&Ar[o * 8];
#pragma unroll
        for (int kc = 0; kc < 4; ++kc) {
            frag_store_h<2>(AH2[kc & 1], rr, o, P);
            if (kc < 3) P = *(const f16x8*)&Ar[(kc + 1) * 64 + o * 8];
            __syncthreads();
#pragma unroll
            for (int k2 = 0; k2 < 2; ++k2)
                mfma_step_h<2, 4>(AH2[kc & 1], p.W2h, 8, kc * 2 + k2, k2, wv, lane, acc);
        }
        float scp[2][4];
#pragma unroll
        for (int rg = 0; rg < 2; ++rg)
#pragma unroll
            for (int i = 0; i < 4; ++i) scp[rg][i] = 0.f;
#pragma unroll
        for (int j = 0; j < 4; ++j) {
            int col = (wv * 4 + j) * 16 + (lane & 15);
            float b = p.ab2[col];
#pragma unroll
            for (int rg = 0; rg < 2; ++rg)
#pragma unroll
                for (int i = 0; i < 4; ++i) {
                    int row = rg * 16 + ((lane >> 4) << 2) + i;
                    int gg = st * 32 + row;
                    float v = acc[rg][j][i] + b;
                    R2h[gg * 264 + col] = (_Float16)v;
                    scp[rg][i] += v * R1[(gg >> 1) * 260 + col];
                }
        }
#pragma unroll
        for (int rg = 0; rg < 2; ++rg)
#pragma unroll
            for (int i = 0; i < 4; ++i) {
                float sv = scp[rg][i];
#pragma unroll
                for (int off = 1; off < 16; off <<= 1) sv += __shfl_xor(sv, off);
                if ((lane & 15) == 0) {
                    int gg = st * 32 + rg * 16 + ((lane >> 4) << 2) + i;
                    atomicAdd(&scoreL[gg], sv);
                }
            }
    }
    __syncthreads();

    // ---- Phase C: softmax alphas + outf build ----
    if (tid < 32) {
        int lw = w0 + tid; if (lw >= p.nw) lw = p.nw - 1;
        int gw = p.win0 + lw;
        const double n = (double)(NWIN_TOTAL * 2);
        float stdv = (float)sqrt((p.acc[1] - p.acc[0] * p.acc[0] / n) / (n - 1.0));
        float cutv = p.cut[gw >> 7];
        float d0 = fabsf(cutv - p.time_idx[gw * 3 + 0]);
        float d1 = fabsf(cutv - p.time_idx[gw * 3 + 1]);
        float tw0 = expf(-d0 / (stdv + 1e-6f));
        float tw1 = expf(-d1 / (stdv + 1e-6f));
        float s0 = scoreL[tid * 2 + 0] * (0.7f + 0.3f * tw0);
        float s1 = scoreL[tid * 2 + 1] * (0.7f + 0.3f * tw1);
        float m = fmaxf(s0, s1);
        float e0 = expf(s0 - m), e1 = expf(s1 - m);
        float inv = 1.f / (e0 + e1);
        aL[tid * 2 + 0] = e0 * inv;
        aL[tid * 2 + 1] = e1 * inv;
    }
    __syncthreads();
    for (int q = tid; q < 32 * 256; q += NTH) {
        int r = q >> 8, c = q & 255;
        int lw = w0 + r; if (lw >= p.nw) lw = p.nw - 1;
        float u2 = (float)p.upd[((size_t)lw * 3 + 2) * 256 + c];
        R1[r * 260 + c] = u2 + aL[r * 2] * (float)R2h[(r * 2) * 264 + c]
                             + aL[r * 2 + 1] * (float)R2h[(r * 2 + 1) * 264 + c];
    }

    // ---- Phase D: h2 = relu(outf @ at_m1W) -> R2f[32][132] ----
    {
        f32x4 acc[2][2];
#pragma unroll
        for (int rg = 0; rg < 2; ++rg)
#pragma unroll
            for (int j = 0; j < 2; ++j)
#pragma unroll
                for (int i = 0; i < 4; ++i) acc[rg][j][i] = 0.f;
        for (int kc = 0; kc < 4; ++kc) {
            __syncthreads();
            {
                int k0 = kc * 64 + o * 8;
                float v[8];
                float4 x = *(const float4*)&R1[rr * 260 + k0];
                float4 y = *(const float4*)&R1[rr * 260 + k0 + 4];
                v[0]=x.x; v[1]=x.y; v[2]=x.z; v[3]=x.w;
                v[4]=y.x; v[5]=y.y; v[6]=y.z; v[7]=y.w;
                frag_store<2>(AH2[0], AL, rr, o, v);
            }
            __syncthreads();
#pragma unroll
            for (int k2 = 0; k2 < 2; ++k2)
                mfma_step<2, 2>(AH2[0], AL, p.M1h, 8, kc * 2 + k2, k2, wv, lane, acc);
        }
        __syncthreads();
#pragma unroll
        for (int j = 0; j < 2; ++j) {
            int col = (wv * 2 + j) * 16 + (lane & 15);
            float b = p.am1b[col];
#pragma unroll
            for (int rg = 0; rg < 2; ++rg)
#pragma unroll
                for (int i = 0; i < 4; ++i) {
                    int row = rg * 16 + ((lane >> 4) << 2) + i;
                    float x = acc[rg][j][i] + b;
                    R2f[row * 132 + col] = x > 0.f ? x : 0.f;
                }
        }
    }
    __syncthreads();

    // xz extra cols (stride 196)
    for (int q = tid; q < 32 * 68; q += NTH) {
        int r = q / 68, c = 128 + q % 68;
        int lw = w0 + r; if (lw >= p.nw) lw = p.nw - 1;
        int gw = p.win0 + lw;
        R1[r * 196 + c] = (c < 140) ? p.cat[(size_t)gw * 12 + (c - 128)] : 0.f;
    }

    // ---- Phase E: h3 = h2 @ at_m2W -> R1 stride 196 cols 0..127 ----
    {
        f32x4 acc[2][2];
#pragma unroll
        for (int rg = 0; rg < 2; ++rg)
#pragma unroll
            for (int j = 0; j < 2; ++j)
#pragma unroll
                for (int i = 0; i < 4; ++i) acc[rg][j][i] = 0.f;
        for (int kc = 0; kc < 2; ++kc) {
            __syncthreads();
            {
                int k0 = kc * 64 + o * 8;
                float v[8];
                float4 x = *(const float4*)&R2f[rr * 132 + k0];
                float4 y = *(const float4*)&R2f[rr * 132 + k0 + 4];
                v[0]=x.x; v[1]=x.y; v[2]=x.z; v[3]=x.w;
                v[4]=y.x; v[5]=y.y; v[6]=y.z; v[7]=y.w;
                frag_store<2>(AH2[0], AL, rr, o, v);
            }
            __syncthreads();
#pragma unroll
            for (int k2 = 0; k2 < 2; ++k2)
                mfma_step<2, 2>(AH2[0], AL, p.M2h, 4, kc * 2 + k2, k2, wv, lane, acc);
        }
        __syncthreads();
#pragma unroll
        for (int j = 0; j < 2; ++j) {
            int col = (wv * 2 + j) * 16 + (lane & 15);
            float b = p.am2b[col];
#pragma unroll
            for (int rg = 0; rg < 2; ++rg)
#pragma unroll
                for (int i = 0; i < 4; ++i) {
                    int row = rg * 16 + ((lane >> 4) << 2) + i;
                    R1[row * 196 + col] = acc[rg][j][i] + b;
                }
        }
    }

    // ---- Phase F: z1 = relu(xz @ f_W1) -> R2f stride 196 ----
    {
        f32x4 acc[2][3];
#pragma unroll
        for (int rg = 0; rg < 2; ++rg)
#pragma unroll
            for (int j = 0; j < 3; ++j)
#pragma unroll
                for (int i = 0; i < 4; ++i) acc[rg][j][i] = 0.f;
        for (int kc = 0; kc < 3; ++kc) {
            __syncthreads();
            {
                int k0 = kc * 64 + o * 8;
                float v[8];
                float4 x = *(const float4*)&R1[rr * 196 + k0];
                float4 y = *(const float4*)&R1[rr * 196 + k0 + 4];
                v[0]=x.x; v[1]=x.y; v[2]=x.z; v[3]=x.w;
                v[4]=y.x; v[5]=y.y; v[6]=y.z; v[7]=y.w;
                frag_store<2>(AH2[0], AL, rr, o, v);
            }
            __syncthreads();
#pragma unroll
            for (int k2 = 0; k2 < 2; ++k2)
                mfma_step<2, 3>(AH2[0], AL, p.F1h, 6, kc * 2 + k2, k2, wv, lane, acc);
        }
        __syncthreads();
#pragma unroll
        for (int j = 0; j < 3; ++j) {
            int col = (wv * 3 + j) * 16 + (lane & 15);
            float b = (col < 140) ? p.fb1[col] : 0.f;
#pragma unroll
            for (int rg = 0; rg < 2; ++rg)
#pragma unroll
                for (int i = 0; i < 4; ++i) {
                    int row = rg * 16 + ((lane >> 4) << 2) + i;
                    float x = acc[rg][j][i] + b;
                    R2f[row * 196 + col] = x > 0.f ? x : 0.f;
                }
        }
    }

    // ---- Phase G: z2 = relu(z1 @ f_W2) fused with final dot ----
    {
        f32x4 acc[2][2];
#pragma unroll
        for (int rg = 0; rg < 2; ++rg)
#pragma unroll
            for (int j = 0; j < 2; ++j)
#pragma unroll
                for (int i = 0; i < 4; ++i) acc[rg][j][i] = 0.f;
        for (int kc = 0; kc < 3; ++kc) {
            __syncthreads();
            {
                int k0 = kc * 64 + o * 8;
                float v[8];
                float4 x = *(const float4*)&R2f[rr * 196 + k0];
                float4 y = *(const float4*)&R2f[rr * 196 + k0 + 4];
                v[0]=x.x; v[1]=x.y; v[2]=x.z; v[3]=x.w;
                v[4]=y.x; v[5]=y.y; v[6]=y.z; v[7]=y.w;
                frag_store<2>(AH2[0], AL, rr, o, v);
            }
            __syncthreads();
#pragma unroll
            for (int k2 = 0; k2 < 2; ++k2)
                mfma_step<2, 2>(AH2[0], AL, p.F2h, 6, kc * 2 + k2, k2, wv, lane, acc);
        }
        float pt[2][4];
#pragma unroll
        for (int rg = 0; rg < 2; ++rg)
#pragma unroll
            for (int i = 0; i < 4; ++i) pt[rg][i] = 0.f;
#pragma unroll
        for (int j = 0; j < 2; ++j) {
            int col = (wv * 2 + j) * 16 + (lane & 15);
            float b = p.fb2[col];
            float w3 = p.fW3[col];
#pragma unroll
            for (int rg = 0; rg < 2; ++rg)
#pragma unroll
                for (int i = 0; i < 4; ++i) {
                    float x = acc[rg][j][i] + b;
                    x = x > 0.f ? x : 0.f;
                    pt[rg][i] += x * w3;
                }
        }
#pragma unroll
        for (int rg = 0; rg < 2; ++rg)
#pragma unroll
            for (int i = 0; i < 4; ++i) {
                float sv = pt[rg][i];
#pragma unroll
                for (int off = 1; off < 16; off <<= 1) sv += __shfl_xor(sv, off);
                if ((lane & 15) == 0)
                    atomicAdd(&finL[rg * 16 + ((lane >> 4) << 2) + i], sv);
            }
    }
    __syncthreads();
    if (tid < 32 && w0 + tid < p.nw)
        p.out[p.win0 + w0 + tid] = finL[tid] + p.fb3[0];
}

extern "C" void kernel_launch(void* const* d_in, const int* in_sizes, int n_in,
                              void* d_out, int out_size, void* d_ws, size_t ws_size,
                              hipStream_t stream) {
    const float* node_table    = (const float*)d_in[0];
    const float* edge_table    = (const float*)d_in[1];
    const float* basis_freq    = (const float*)d_in[2];
    const float* phase         = (const float*)d_in[3];
    const float* ev_W          = (const float*)d_in[4];
    const float* ev_b          = (const float*)d_in[5];
    const float* ev_m1W        = (const float*)d_in[6];
    const float* ev_m1b        = (const float*)d_in[7];
    const float* ev_m2W        = (const float*)d_in[8];
    const float* ev_m2b        = (const float*)d_in[9];
    const float* at_W1         = (const float*)d_in[10];
    const float* at_b1         = (const float*)d_in[11];
    const float* at_W2         = (const float*)d_in[12];
    const float* at_b2         = (const float*)d_in[13];
    const float* at_m1W        = (const float*)d_in[14];
    const float* at_m1b        = (const float*)d_in[15];
    const float* at_m2W        = (const float*)d_in[16];
    const float* at_m2b        = (const float*)d_in[17];
    const float* f_W1          = (const float*)d_in[18];
    const float* f_b1          = (const float*)d_in[19];
    const float* f_W2          = (const float*)d_in[20];
    const float* f_b2          = (const float*)d_in[21];
    const float* f_W3          = (const float*)d_in[22];
    const float* f_b3          = (const float*)d_in[23];
    const float* time_idx      = (const float*)d_in[24];
    const float* cut_time_l    = (const float*)d_in[25];
    const float* cat_feat      = (const float*)d_in[26];
    const float* edge_identify = (const float*)d_in[27];
    const int*   node_idx      = (const int*)d_in[28];
    const int*   edge_idx      = (const int*)d_in[29];

    char* wsb = (char*)d_ws;
    double* acc = (double*)wsb;

    const int   wkp[9] = {384, 192, 128, 256, 256, 256, 128, 192, 192};
    const int   wnp[9] = {192, 128, 128, 256, 256, 128, 128, 192, 128};
    const int   wkt[9] = {347, 172, 128, 256, 256, 256, 128, 140, 140};
    const int   wnt[9] = {172, 128, 128, 256, 256, 128, 128, 140, 128};
    const float* wsrc[9] = {ev_W, ev_m1W, ev_m2W, at_W1, at_W2, at_m1W, at_m2W, f_W1, f_W2};
    _Float16* wH[9];
    size_t woff = 256;
    WAll wa = {};
    int cum = 0;
    for (int i = 0; i < 9; ++i) {
        size_t plane = (size_t)wkp[i] * wnp[i];
        wH[i] = (_Float16*)(wsb + woff);
        woff += plane * sizeof(_Float16);
        woff = (woff + 15) & ~(size_t)15;
        wa.w[i].src = wsrc[i]; wa.w[i].dH = wH[i];
        wa.w[i].Kt = wkt[i]; wa.w[i].Nt = wnt[i]; wa.w[i].Kp = wkp[i]; wa.w[i].Np = wnp[i];
        wa.w[i].off = cum;
        cum += (wnp[i] / 16) * (wkp[i] / 32) * 64;
    }
    wa.grand = cum;

    hipMemsetAsync(d_ws, 0, 16, stream);
    k_std<<<64, NTH, 0, stream>>>(time_idx, cut_time_l, acc);
    k_wprep_all<<<CDIV(wa.grand, NTH), NTH, 0, stream>>>(wa);

    size_t avail = ws_size > woff + 4096 ? ws_size - woff - 4096 : 0;
    size_t nwc_s = avail / 1536;
    int nwc = (int)(nwc_s > NWIN_TOTAL ? NWIN_TOTAL : nwc_s);
    if (nwc < 1) nwc = 1;
    _Float16* updB = (_Float16*)(wsb + ((woff + 255) & ~(size_t)255));

    for (int c0 = 0; c0 < NWIN_TOTAL; c0 += nwc) {
        int nw = NWIN_TOTAL - c0 < nwc ? NWIN_TOTAL - c0 : nwc;
        int M3 = nw * 3;

        GCP gc = {};
        gc.W0h = wH[0]; gc.W1h = wH[1]; gc.W2h = wH[2];
        gc.b0 = ev_b; gc.b1 = ev_m1b; gc.b2 = ev_m2b;
        gc.upd = updB; gc.M = M3; gc.win0 = c0;
        gc.edge_table = edge_table; gc.node_table = node_table;
        gc.basis_freq = basis_freq; gc.phase = phase;
        gc.time_idx = time_idx; gc.cut = cut_time_l;
        gc.edge_idx = edge_idx; gc.node_idx = node_idx; gc.eid = edge_identify;
        k_gc<<<CDIV(M3, 32), NTH, 0, stream>>>(gc);

        AttnP ap = {};
        ap.upd = updB;
        ap.W1h = wH[3]; ap.W2h = wH[4];
        ap.M1h = wH[5]; ap.M2h = wH[6];
        ap.F1h = wH[7]; ap.F2h = wH[8];
        ap.ab1 = at_b1; ap.ab2 = at_b2; ap.am1b = at_m1b; ap.am2b = at_m2b;
        ap.fb1 = f_b1; ap.fb2 = f_b2; ap.fW3 = f_W3; ap.fb3 = f_b3;
        ap.time_idx = time_idx; ap.cut = cut_time_l; ap.cat = cat_feat; ap.acc = acc;
        ap.out = (float*)d_out; ap.nw = nw; ap.win0 = c0;
        k_attn<<<CDIV(nw, 32), NTH, 0, stream>>>(ap);
    }
}

// Round 20
// 163.953 us; speedup vs baseline: 1.6251x; 1.0189x over previous
//
#include <hip/hip_runtime.h>
#include <math.h>

#define NWIN_TOTAL (256 * 128)
#define NTH 256
#define CDIV(a, b) (((a) + (b) - 1) / (b))

typedef _Float16 f16x8 __attribute__((ext_vector_type(8)));
typedef float f32x4 __attribute__((ext_vector_type(4)));

// hi-only A and B everywhere (lo-planes measured below fp16-storage error floor)
__device__ __forceinline__ void mma1(f16x8 a, f16x8 bh, f32x4& c) {
    c = __builtin_amdgcn_mfma_f32_16x16x32_f16(a, bh, c, 0, 0, 0);
}

// ---------------- global std ----------------
__global__ __launch_bounds__(NTH) void k_std(const float* __restrict__ time_idx,
                                             const float* __restrict__ cut,
                                             double* __restrict__ acc) {
    int tid = threadIdx.x;
    const int n = NWIN_TOTAL * 2;
    double s = 0.0, s2 = 0.0;
    for (int i = blockIdx.x * blockDim.x + tid; i < n; i += gridDim.x * blockDim.x) {
        int j = i & 1;
        int bw = i >> 1;
        float d = fabsf(cut[bw >> 7] - time_idx[bw * 3 + j]);
        s += (double)d;
        s2 += (double)d * (double)d;
    }
    __shared__ double ls[NTH], ls2[NTH];
    ls[tid] = s; ls2[tid] = s2;
    __syncthreads();
    for (int st = NTH / 2; st > 0; st >>= 1) {
        if (tid < st) { ls[tid] += ls[tid + st]; ls2[tid] += ls2[tid + st]; }
        __syncthreads();
    }
    if (tid == 0) { atomicAdd(&acc[0], ls[0]); atomicAdd(&acc[1], ls2[0]); }
}

// ---------------- all weights -> B-fragment hi plane only (one launch) ----------------
struct WEnt { const float* src; _Float16* dH; int Kt, Nt, Kp, Np, off; };
struct WAll { WEnt w[9]; int grand; };

__global__ __launch_bounds__(NTH) void k_wprep_all(WAll a) {
    int idx = blockIdx.x * NTH + threadIdx.x;
    if (idx >= a.grand) return;
    int i = 0;
#pragma unroll
    for (int t = 0; t < 8; ++t)
        if (i + 1 < 9 && idx >= a.w[i + 1].off) ++i;
    const WEnt& e = a.w[i];
    int lidx = idx - e.off;
    int nks = e.Kp / 32;
    int cg = lidx / (nks * 64);
    int rem = lidx - cg * nks * 64;
    int ks = rem >> 6, lane = rem & 63;
    int col = cg * 16 + (lane & 15);
    for (int j = 0; j < 8; ++j) {
        int k = ks * 32 + ((lane >> 4) << 3) + j;
        float v = (k < e.Kt && col < e.Nt) ? e.src[(size_t)k * e.Nt + col] : 0.f;
        e.dH[(size_t)lidx * 8 + j] = (_Float16)v;
    }
}

// ---------------- frag helpers (swizzled: B ^= (B>>4)&7) ----------------
template <int RG>
__device__ __forceinline__ void frag_store_hf(_Float16* AH, int r, int o,
                                              const float* v) {
    int B = ((o >> 2) * RG + (r >> 4)) * 64 + ((r & 15) | ((o & 3) << 4));
    int off = (B ^ ((B >> 4) & 7)) * 8;
    f16x8 h8;
#pragma unroll
    for (int e = 0; e < 8; ++e) h8[e] = (_Float16)v[e];
    *(f16x8*)&AH[off] = h8;
}

template <int RG>
__device__ __forceinline__ void frag_store_h(_Float16* AH, int r, int o, f16x8 v) {
    int B = ((o >> 2) * RG + (r >> 4)) * 64 + ((r & 15) | ((o & 3) << 4));
    int off = (B ^ ((B >> 4) & 7)) * 8;
    *(f16x8*)&AH[off] = v;
}

// A hi-only staged, B hi-only: 1 MFMA per (rg,j)
template <int RG, int NREP>
__device__ __forceinline__ void mfma_step_h(const _Float16* AH,
                                            const _Float16* __restrict__ Wh,
                                            int nks, int ks, int k2, int wv, int lane,
                                            f32x4 (&acc)[RG][NREP]) {
    f16x8 ah[RG];
#pragma unroll
    for (int rg = 0; rg < RG; ++rg) {
        int B = (k2 * RG + rg) * 64 + lane;
        int off = (B ^ ((B >> 4) & 7)) * 8;
        ah[rg] = *(const f16x8*)&AH[off];
    }
#pragma unroll
    for (int j = 0; j < NREP; ++j) {
        int cg = wv * NREP + j;
        size_t boff = ((size_t)(cg * nks + ks) * 64 + lane) * 8;
        f16x8 bh = *(const f16x8*)&Wh[boff];
#pragma unroll
        for (int rg = 0; rg < RG; ++rg) mma1(ah[rg], bh, acc[rg][j]);
    }
}

// ---------------- K1: fused G1 + conv (dual-dir GEMM1, hi-only A and B) ----------------
struct GCP {
    const _Float16 *W0h, *W1h, *W2h;
    const float *b0, *b1, *b2;
    _Float16* upd; int M; int win0;
    const float* edge_table; const float* node_table;
    const float* basis_freq; const float* phase;
    const float* time_idx; const float* cut;
    const int* edge_idx; const int* node_idx; const float* eid;
};

__global__ __launch_bounds__(NTH) void k_gc(GCP p) {
    __shared__ _Float16 AH[2][2048];     // phase1: double-buffer; conv: per-dir
    __shared__ _Float16 evL[32 * 184];
    __shared__ _Float16 h1L[32 * 136];
    __shared__ float ldsBF[176], ldsPH[176];
    const int tid = threadIdx.x, wv = tid >> 6, lane = tid & 63;
    const int mtile = blockIdx.x * 32;
    const int o = tid & 7, r = tid >> 3;

    if (tid < 172) { ldsBF[tid] = p.basis_freq[tid]; ldsPH[tid] = p.phase[tid]; }

    int grow = mtile + r; if (grow >= p.M) grow = p.M - 1;
    int w3 = grow / 3, l = grow - w3 * 3;
    int gw = p.win0 + w3;
    int nb = gw * 6 + 2 * l;
    const float* er = p.edge_table + (size_t)p.edge_idx[gw * 3 + l] * 172;
    const float* S0 = p.node_table + (size_t)p.node_idx[nb] * 172;
    const float* T0 = p.node_table + (size_t)p.node_idx[nb + 1] * 172;
    float dlt = p.cut[gw >> 7] - p.time_idx[gw * 3 + l];
    float g[3][8]; float eidv[3];
#pragma unroll
    for (int kc = 0; kc < 3; ++kc) {
        int k0 = kc * 64 + o * 8;
        if (k0 + 7 < 172) {
            float4 x = *(const float4*)&er[k0];
            float4 y = *(const float4*)&er[k0 + 4];
            g[kc][0]=x.x; g[kc][1]=x.y; g[kc][2]=x.z; g[kc][3]=x.w;
            g[kc][4]=y.x; g[kc][5]=y.y; g[kc][6]=y.z; g[kc][7]=y.w;
        } else if (k0 == 168) {
            float4 x = *(const float4*)&er[168];
            g[kc][0]=x.x; g[kc][1]=x.y; g[kc][2]=x.z; g[kc][3]=x.w;
            eidv[0] = p.eid[(gw * 3 + l) * 3 + 0];
            eidv[1] = p.eid[(gw * 3 + l) * 3 + 1];
            eidv[2] = p.eid[(gw * 3 + l) * 3 + 2];
        }
    }
    __syncthreads();   // ldsBF/PH ready

    // ---- Phase 1: ev = evt @ ev_W  (K=384, N=192), double-buffered, hi-only ----
    {
        f32x4 acc[2][3];
#pragma unroll
        for (int rg = 0; rg < 2; ++rg)
#pragma unroll
            for (int j = 0; j < 3; ++j)
#pragma unroll
                for (int i = 0; i < 4; ++i) acc[rg][j][i] = 0.f;
        const int ord[6] = {3, 4, 5, 0, 1, 2};
#pragma unroll
        for (int x = 0; x < 6; ++x) {
            const int kc = ord[x];
            {
                int k0 = kc * 64 + o * 8;
                float v[8];
                if (kc >= 3 || k0 >= 176) {
#pragma unroll
                    for (int e = 0; e < 8; ++e) {
                        int k = k0 + e;
                        int q = k - 175;
                        v[e] = (k < 347) ? __cosf(fmaf(dlt, ldsBF[q], ldsPH[q])) : 0.f;
                    }
                } else if (k0 + 7 < 172) {
#pragma unroll
                    for (int e = 0; e < 8; ++e) v[e] = g[kc][e];
                } else {  // k0 == 168: edge[168..171], id[0..2], time_feat[0]
                    v[0]=g[2][0]; v[1]=g[2][1]; v[2]=g[2][2]; v[3]=g[2][3];
                    v[4]=eidv[0]; v[5]=eidv[1]; v[6]=eidv[2];
                    v[7]=__cosf(fmaf(dlt, ldsBF[0], ldsPH[0]));
                }
                frag_store_hf<2>(AH[x & 1], r, o, v);
            }
            __syncthreads();
#pragma unroll
            for (int k2 = 0; k2 < 2; ++k2)
                mfma_step_h<2, 3>(AH[x & 1], p.W0h, 12,
                                  kc * 2 + k2, k2, wv, lane, acc);
        }
#pragma unroll
        for (int j = 0; j < 3; ++j) {
            int col = (wv * 3 + j) * 16 + (lane & 15);
            if (col < 176) {
                float b = (col < 172) ? p.b0[col] : 0.f;
#pragma unroll
                for (int rg = 0; rg < 2; ++rg)
#pragma unroll
                    for (int i = 0; i < 4; ++i) {
                        int row = rg * 16 + ((lane >> 4) << 2) + i;
                        evL[row * 184 + col] = (_Float16)(acc[rg][j][i] + b);
                    }
            }
        }
    }
    __syncthreads();

    // ---- GEMM1 dual-dir: am0 = S+relu(T+ev), am1 = T+relu(S+ev), hi-only ----
    f32x4 a1[2][2][2];   // [dir][rg][j]
#pragma unroll
    for (int d = 0; d < 2; ++d)
#pragma unroll
        for (int rg = 0; rg < 2; ++rg)
#pragma unroll
            for (int j = 0; j < 2; ++j)
#pragma unroll
                for (int i = 0; i < 4; ++i) a1[d][rg][j][i] = 0.f;
    {
        float Ps[8], Pt[8];
        auto loadST = [&](int kc) {
            int k0 = kc * 64 + o * 8;
            if (k0 + 7 < 172) {
                *(float4*)&Ps[0] = *(const float4*)&S0[k0];
                *(float4*)&Ps[4] = *(const float4*)&S0[k0 + 4];
                *(float4*)&Pt[0] = *(const float4*)&T0[k0];
                *(float4*)&Pt[4] = *(const float4*)&T0[k0 + 4];
            } else if (k0 == 168) {
                *(float4*)&Ps[0] = *(const float4*)&S0[168];
                *(float4*)&Pt[0] = *(const float4*)&T0[168];
            }
        };
        loadST(0);
#pragma unroll
        for (int kc = 0; kc < 3; ++kc) {
            {
                int k0 = kc * 64 + o * 8;
                float v0[8], v1[8];
                if (k0 + 7 < 172) {
                    f16x8 e8 = *(const f16x8*)&evL[r * 184 + k0];
#pragma unroll
                    for (int e = 0; e < 8; ++e) {
                        float ev = (float)e8[e];
                        v0[e] = Ps[e] + fmaxf(Pt[e] + ev, 0.f);
                        v1[e] = Pt[e] + fmaxf(Ps[e] + ev, 0.f);
                    }
                } else if (k0 == 168) {
                    f16x8 e8 = *(const f16x8*)&evL[r * 184 + 168];
#pragma unroll
                    for (int e = 0; e < 8; ++e) {
                        if (e < 4) {
                            float ev = (float)e8[e];
                            v0[e] = Ps[e] + fmaxf(Pt[e] + ev, 0.f);
                            v1[e] = Pt[e] + fmaxf(Ps[e] + ev, 0.f);
                        } else { v0[e] = 0.f; v1[e] = 0.f; }
                    }
                } else {
#pragma unroll
                    for (int e = 0; e < 8; ++e) { v0[e] = 0.f; v1[e] = 0.f; }
                }
                frag_store_hf<2>(AH[0], r, o, v0);
                frag_store_hf<2>(AH[1], r, o, v1);
            }
            if (kc < 2) loadST(kc + 1);
            __syncthreads();
#pragma unroll
            for (int k2 = 0; k2 < 2; ++k2) {
                const int ks = kc * 2 + k2;
                f16x8 ah[2][2];
#pragma unroll
                for (int d = 0; d < 2; ++d)
#pragma unroll
                    for (int rg = 0; rg < 2; ++rg) {
                        int B = (k2 * 2 + rg) * 64 + lane;
                        int off = (B ^ ((B >> 4) & 7)) * 8;
                        ah[d][rg] = *(const f16x8*)&AH[d][off];
                    }
#pragma unroll
                for (int j = 0; j < 2; ++j) {
                    size_t boff = ((size_t)((wv * 2 + j) * 6 + ks) * 64 + lane) * 8;
                    f16x8 bh = *(const f16x8*)&p.W1h[boff];
#pragma unroll
                    for (int d = 0; d < 2; ++d)
#pragma unroll
                        for (int rg = 0; rg < 2; ++rg)
                            mma1(ah[d][rg], bh, a1[d][rg][j]);
                }
            }
            __syncthreads();
        }
    }

    // ---- per dir: h1 -> LDS fp16, then GEMM2 (direct frag loads, hi-only) ----
    for (int dir = 0; dir < 2; ++dir) {
#pragma unroll
        for (int j = 0; j < 2; ++j) {
            int col = (wv * 2 + j) * 16 + (lane & 15);
            float b = p.b1[col];
#pragma unroll
            for (int rg = 0; rg < 2; ++rg)
#pragma unroll
                for (int i = 0; i < 4; ++i) {
                    int row = rg * 16 + ((lane >> 4) << 2) + i;
                    float x = a1[dir][rg][j][i] + b;
                    h1L[row * 136 + col] = (_Float16)(x > 0.f ? x : 0.f);
                }
        }
        __syncthreads();

        f32x4 a2[2][2];
#pragma unroll
        for (int rg = 0; rg < 2; ++rg)
#pragma unroll
            for (int j = 0; j < 2; ++j)
#pragma unroll
                for (int i = 0; i < 4; ++i) a2[rg][j][i] = 0.f;
#pragma unroll
        for (int ks = 0; ks < 4; ++ks) {
            const int k0 = ks * 32 + ((lane >> 4) << 3);
            f16x8 a4[2];
#pragma unroll
            for (int rg = 0; rg < 2; ++rg)
                a4[rg] = *(const f16x8*)&h1L[(rg * 16 + (lane & 15)) * 136 + k0];
#pragma unroll
            for (int j = 0; j < 2; ++j) {
                size_t boff = ((size_t)((wv * 2 + j) * 4 + ks) * 64 + lane) * 8;
                f16x8 bh = *(const f16x8*)&p.W2h[boff];
#pragma unroll
                for (int rg = 0; rg < 2; ++rg) mma1(a4[rg], bh, a2[rg][j]);
            }
        }
#pragma unroll
        for (int j = 0; j < 2; ++j) {
            int col = (wv * 2 + j) * 16 + (lane & 15);
            float b = p.b2[col];
#pragma unroll
            for (int rg = 0; rg < 2; ++rg)
#pragma unroll
                for (int i = 0; i < 4; ++i) {
                    int row = mtile + rg * 16 + ((lane >> 4) << 2) + i;
                    if (row < p.M)
                        p.upd[(size_t)row * 256 + dir * 128 + col] = (_Float16)(a2[rg][j][i] + b);
                }
        }
        if (dir == 0) __syncthreads();
    }
}

// ---------------- K2: fused attention + head (32 windows / block), hi-only ----------------
struct AttnP {
    const _Float16* upd;
    const _Float16 *W1h,*W2h,*M1h,*M2h,*F1h,*F2h;
    const float *ab1,*ab2,*am1b,*am2b,*fb1,*fb2,*fW3,*fb3;
    const float *time_idx,*cut,*cat; const double* acc;
    float* out; int nw; int win0;
};

__global__ __launch_bounds__(NTH) void k_attn(AttnP p) {
    __shared__ float R1[32 * 260];
    __shared__ _Float16 R2h[64 * 264];
    __shared__ _Float16 AH2[2][2048];
    __shared__ float scoreL[64], aL[64], finL[32];
    float* R2f = (float*)R2h;
    const int tid = threadIdx.x, wv = tid >> 6, lane = tid & 63;
    const int w0 = blockIdx.x * 32;
    const int rr = tid >> 3, o = tid & 7;
    if (tid < 64) scoreL[tid] = 0.f;
    if (tid < 32) finL[tid] = 0.f;
    __syncthreads();

    // ---- Phase A: wp = upd[w*3+2] @ at_W1 (double-buffered, hi-only) ----
    {
        int lw = w0 + rr; if (lw >= p.nw) lw = p.nw - 1;
        const _Float16* Ar = p.upd + ((size_t)lw * 3 + 2) * 256;
        f32x4 acc[2][4];
#pragma unroll
        for (int rg = 0; rg < 2; ++rg)
#pragma unroll
            for (int j = 0; j < 4; ++j)
#pragma unroll
                for (int i = 0; i < 4; ++i) acc[rg][j][i] = 0.f;
        f16x8 P = *(const f16x8*)&Ar[o * 8];
#pragma unroll
        for (int kc = 0; kc < 4; ++kc) {
            frag_store_h<2>(AH2[kc & 1], rr, o, P);
            if (kc < 3) P = *(const f16x8*)&Ar[(kc + 1) * 64 + o * 8];
            __syncthreads();
#pragma unroll
            for (int k2 = 0; k2 < 2; ++k2)
                mfma_step_h<2, 4>(AH2[kc & 1], p.W1h, 8, kc * 2 + k2, k2, wv, lane, acc);
        }
#pragma unroll
        for (int j = 0; j < 4; ++j) {
            int col = (wv * 4 + j) * 16 + (lane & 15);
            float b = p.ab1[col];
#pragma unroll
            for (int rg = 0; rg < 2; ++rg)
#pragma unroll
                for (int i = 0; i < 4; ++i) {
                    int row = rg * 16 + ((lane >> 4) << 2) + i;
                    R1[row * 260 + col] = acc[rg][j][i] + b;
                }
        }
    }

    // ---- Phase B: wq (two 32-row subtiles) + score partials ----
    for (int st = 0; st < 2; ++st) {
        int g = st * 32 + rr;
        int lw = w0 + (g >> 1); if (lw >= p.nw) lw = p.nw - 1;
        const _Float16* Ar = p.upd + ((size_t)lw * 3 + (g & 1)) * 256;
        f32x4 acc[2][4];
#pragma unroll
        for (int rg = 0; rg < 2; ++rg)
#pragma unroll
            for (int j = 0; j < 4; ++j)
#pragma unroll
                for (int i = 0; i < 4; ++i) acc[rg][j][i] = 0.f;
        f16x8 P = *(const f16x8*)&Ar[o * 8];
#pragma unroll
        for (int kc = 0; kc < 4; ++kc) {
            frag_store_h<2>(AH2[kc & 1], rr, o, P);
            if (kc < 3) P = *(const f16x8*)&Ar[(kc + 1) * 64 + o * 8];
            __syncthreads();
#pragma unroll
            for (int k2 = 0; k2 < 2; ++k2)
                mfma_step_h<2, 4>(AH2[kc & 1], p.W2h, 8, kc * 2 + k2, k2, wv, lane, acc);
        }
        float scp[2][4];
#pragma unroll
        for (int rg = 0; rg < 2; ++rg)
#pragma unroll
            for (int i = 0; i < 4; ++i) scp[rg][i] = 0.f;
#pragma unroll
        for (int j = 0; j < 4; ++j) {
            int col = (wv * 4 + j) * 16 + (lane & 15);
            float b = p.ab2[col];
#pragma unroll
            for (int rg = 0; rg < 2; ++rg)
#pragma unroll
                for (int i = 0; i < 4; ++i) {
                    int row = rg * 16 + ((lane >> 4) << 2) + i;
                    int gg = st * 32 + row;
                    float v = acc[rg][j][i] + b;
                    R2h[gg * 264 + col] = (_Float16)v;
                    scp[rg][i] += v * R1[(gg >> 1) * 260 + col];
                }
        }
#pragma unroll
        for (int rg = 0; rg < 2; ++rg)
#pragma unroll
            for (int i = 0; i < 4; ++i) {
                float sv = scp[rg][i];
#pragma unroll
                for (int off = 1; off < 16; off <<= 1) sv += __shfl_xor(sv, off);
                if ((lane & 15) == 0) {
                    int gg = st * 32 + rg * 16 + ((lane >> 4) << 2) + i;
                    atomicAdd(&scoreL[gg], sv);
                }
            }
    }
    __syncthreads();

    // ---- Phase C: softmax alphas + outf build ----
    if (tid < 32) {
        int lw = w0 + tid; if (lw >= p.nw) lw = p.nw - 1;
        int gw = p.win0 + lw;
        const double n = (double)(NWIN_TOTAL * 2);
        float stdv = (float)sqrt((p.acc[1] - p.acc[0] * p.acc[0] / n) / (n - 1.0));
        float cutv = p.cut[gw >> 7];
        float d0 = fabsf(cutv - p.time_idx[gw * 3 + 0]);
        float d1 = fabsf(cutv - p.time_idx[gw * 3 + 1]);
        float tw0 = expf(-d0 / (stdv + 1e-6f));
        float tw1 = expf(-d1 / (stdv + 1e-6f));
        float s0 = scoreL[tid * 2 + 0] * (0.7f + 0.3f * tw0);
        float s1 = scoreL[tid * 2 + 1] * (0.7f + 0.3f * tw1);
        float m = fmaxf(s0, s1);
        float e0 = expf(s0 - m), e1 = expf(s1 - m);
        float inv = 1.f / (e0 + e1);
        aL[tid * 2 + 0] = e0 * inv;
        aL[tid * 2 + 1] = e1 * inv;
    }
    __syncthreads();
    for (int q = tid; q < 32 * 256; q += NTH) {
        int r = q >> 8, c = q & 255;
        int lw = w0 + r; if (lw >= p.nw) lw = p.nw - 1;
        float u2 = (float)p.upd[((size_t)lw * 3 + 2) * 256 + c];
        R1[r * 260 + c] = u2 + aL[r * 2] * (float)R2h[(r * 2) * 264 + c]
                             + aL[r * 2 + 1] * (float)R2h[(r * 2 + 1) * 264 + c];
    }

    // ---- Phase D: h2 = relu(outf @ at_m1W) -> R2f[32][132], hi-only ----
    {
        f32x4 acc[2][2];
#pragma unroll
        for (int rg = 0; rg < 2; ++rg)
#pragma unroll
            for (int j = 0; j < 2; ++j)
#pragma unroll
                for (int i = 0; i < 4; ++i) acc[rg][j][i] = 0.f;
        for (int kc = 0; kc < 4; ++kc) {
            __syncthreads();
            {
                int k0 = kc * 64 + o * 8;
                float v[8];
                float4 x = *(const float4*)&R1[rr * 260 + k0];
                float4 y = *(const float4*)&R1[rr * 260 + k0 + 4];
                v[0]=x.x; v[1]=x.y; v[2]=x.z; v[3]=x.w;
                v[4]=y.x; v[5]=y.y; v[6]=y.z; v[7]=y.w;
                frag_store_hf<2>(AH2[0], rr, o, v);
            }
            __syncthreads();
#pragma unroll
            for (int k2 = 0; k2 < 2; ++k2)
                mfma_step_h<2, 2>(AH2[0], p.M1h, 8, kc * 2 + k2, k2, wv, lane, acc);
        }
        __syncthreads();
#pragma unroll
        for (int j = 0; j < 2; ++j) {
            int col = (wv * 2 + j) * 16 + (lane & 15);
            float b = p.am1b[col];
#pragma unroll
            for (int rg = 0; rg < 2; ++rg)
#pragma unroll
                for (int i = 0; i < 4; ++i) {
                    int row = rg * 16 + ((lane >> 4) << 2) + i;
                    float x = acc[rg][j][i] + b;
                    R2f[row * 132 + col] = x > 0.f ? x : 0.f;
                }
        }
    }
    __syncthreads();

    // xz extra cols (stride 196)
    for (int q = tid; q < 32 * 68; q += NTH) {
        int r = q / 68, c = 128 + q % 68;
        int lw = w0 + r; if (lw >= p.nw) lw = p.nw - 1;
        int gw = p.win0 + lw;
        R1[r * 196 + c] = (c < 140) ? p.cat[(size_t)gw * 12 + (c - 128)] : 0.f;
    }

    // ---- Phase E: h3 = h2 @ at_m2W -> R1 stride 196 cols 0..127, hi-only ----
    {
        f32x4 acc[2][2];
#pragma unroll
        for (int rg = 0; rg < 2; ++rg)
#pragma unroll
            for (int j = 0; j < 2; ++j)
#pragma unroll
                for (int i = 0; i < 4; ++i) acc[rg][j][i] = 0.f;
        for (int kc = 0; kc < 2; ++kc) {
            __syncthreads();
            {
                int k0 = kc * 64 + o * 8;
                float v[8];
                float4 x = *(const float4*)&R2f[rr * 132 + k0];
                float4 y = *(const float4*)&R2f[rr * 132 + k0 + 4];
                v[0]=x.x; v[1]=x.y; v[2]=x.z; v[3]=x.w;
                v[4]=y.x; v[5]=y.y; v[6]=y.z; v[7]=y.w;
                frag_store_hf<2>(AH2[0], rr, o, v);
            }
            __syncthreads();
#pragma unroll
            for (int k2 = 0; k2 < 2; ++k2)
                mfma_step_h<2, 2>(AH2[0], p.M2h, 4, kc * 2 + k2, k2, wv, lane, acc);
        }
        __syncthreads();
#pragma unroll
        for (int j = 0; j < 2; ++j) {
            int col = (wv * 2 + j) * 16 + (lane & 15);
            float b = p.am2b[col];
#pragma unroll
            for (int rg = 0; rg < 2; ++rg)
#pragma unroll
                for (int i = 0; i < 4; ++i) {
                    int row = rg * 16 + ((lane >> 4) << 2) + i;
                    R1[row * 196 + col] = acc[rg][j][i] + b;
                }
        }
    }

    // ---- Phase F: z1 = relu(xz @ f_W1) -> R2f stride 196, hi-only ----
    {
        f32x4 acc[2][3];
#pragma unroll
        for (int rg = 0; rg < 2; ++rg)
#pragma unroll
            for (int j = 0; j < 3; ++j)
#pragma unroll
                for (int i = 0; i < 4; ++i) acc[rg][j][i] = 0.f;
        for (int kc = 0; kc < 3; ++kc) {
            __syncthreads();
            {
                int k0 = kc * 64 + o * 8;
                float v[8];
                float4 x = *(const float4*)&R1[rr * 196 + k0];
                float4 y = *(const float4*)&R1[rr * 196 + k0 + 4];
                v[0]=x.x; v[1]=x.y; v[2]=x.z; v[3]=x.w;
                v[4]=y.x; v[5]=y.y; v[6]=y.z; v[7]=y.w;
                frag_store_hf<2>(AH2[0], rr, o, v);
            }
            __syncthreads();
#pragma unroll
            for (int k2 = 0; k2 < 2; ++k2)
                mfma_step_h<2, 3>(AH2[0], p.F1h, 6, kc * 2 + k2, k2, wv, lane, acc);
        }
        __syncthreads();
#pragma unroll
        for (int j = 0; j < 3; ++j) {
            int col = (wv * 3 + j) * 16 + (lane & 15);
            float b = (col < 140) ? p.fb1[col] : 0.f;
#pragma unroll
            for (int rg = 0; rg < 2; ++rg)
#pragma unroll
                for (int i = 0; i < 4; ++i) {
                    int row = rg * 16 + ((lane >> 4) << 2) + i;
                    float x = acc[rg][j][i] + b;
                    R2f[row * 196 + col] = x > 0.f ? x : 0.f;
                }
        }
    }

    // ---- Phase G: z2 = relu(z1 @ f_W2) fused with final dot, hi-only ----
    {
        f32x4 acc[2][2];
#pragma unroll
        for (int rg = 0; rg < 2; ++rg)
#pragma unroll
            for (int j = 0; j < 2; ++j)
#pragma unroll
                for (int i = 0; i < 4; ++i) acc[rg][j][i] = 0.f;
        for (int kc = 0; kc < 3; ++kc) {
            __syncthreads();
            {
                int k0 = kc * 64 + o * 8;
                float v[8];
                float4 x = *(const float4*)&R2f[rr * 196 + k0];
                float4 y = *(const float4*)&R2f[rr * 196 + k0 + 4];
                v[0]=x.x; v[1]=x.y; v[2]=x.z; v[3]=x.w;
                v[4]=y.x; v[5]=y.y; v[6]=y.z; v[7]=y.w;
                frag_store_hf<2>(AH2[0], rr, o, v);
            }
            __syncthreads();
#pragma unroll
            for (int k2 = 0; k2 < 2; ++k2)
                mfma_step_h<2, 2>(AH2[0], p.F2h, 6, kc * 2 + k2, k2, wv, lane, acc);
        }
        float pt[2][4];
#pragma unroll
        for (int rg = 0; rg < 2; ++rg)
#pragma unroll
            for (int i = 0; i < 4; ++i) pt[rg][i] = 0.f;
#pragma unroll
        for (int j = 0; j < 2; ++j) {
            int col = (wv * 2 + j) * 16 + (lane & 15);
            float b = p.fb2[col];
            float w3 = p.fW3[col];
#pragma unroll
            for (int rg = 0; rg < 2; ++rg)
#pragma unroll
                for (int i = 0; i < 4; ++i) {
                    float x = acc[rg][j][i] + b;
                    x = x > 0.f ? x : 0.f;
                    pt[rg][i] += x * w3;
                }
        }
#pragma unroll
        for (int rg = 0; rg < 2; ++rg)
#pragma unroll
            for (int i = 0; i < 4; ++i) {
                float sv = pt[rg][i];
#pragma unroll
                for (int off = 1; off < 16; off <<= 1) sv += __shfl_xor(sv, off);
                if ((lane & 15) == 0)
                    atomicAdd(&finL[rg * 16 + ((lane >> 4) << 2) + i], sv);
            }
    }
    __syncthreads();
    if (tid < 32 && w0 + tid < p.nw)
        p.out[p.win0 + w0 + tid] = finL[tid] + p.fb3[0];
}

extern "C" void kernel_launch(void* const* d_in, const int* in_sizes, int n_in,
                              void* d_out, int out_size, void* d_ws, size_t ws_size,
                              hipStream_t stream) {
    const float* node_table    = (const float*)d_in[0];
    const float* edge_table    = (const float*)d_in[1];
    const float* basis_freq    = (const float*)d_in[2];
    const float* phase         = (const float*)d_in[3];
    const float* ev_W          = (const float*)d_in[4];
    const float* ev_b          = (const float*)d_in[5];
    const float* ev_m1W        = (const float*)d_in[6];
    const float* ev_m1b        = (const float*)d_in[7];
    const float* ev_m2W        = (const float*)d_in[8];
    const float* ev_m2b        = (const float*)d_in[9];
    const float* at_W1         = (const float*)d_in[10];
    const float* at_b1         = (const float*)d_in[11];
    const float* at_W2         = (const float*)d_in[12];
    const float* at_b2         = (const float*)d_in[13];
    const float* at_m1W        = (const float*)d_in[14];
    const float* at_m1b        = (const float*)d_in[15];
    const float* at_m2W        = (const float*)d_in[16];
    const float* at_m2b        = (const float*)d_in[17];
    const float* f_W1          = (const float*)d_in[18];
    const float* f_b1          = (const float*)d_in[19];
    const float* f_W2          = (const float*)d_in[20];
    const float* f_b2          = (const float*)d_in[21];
    const float* f_W3          = (const float*)d_in[22];
    const float* f_b3          = (const float*)d_in[23];
    const float* time_idx      = (const float*)d_in[24];
    const float* cut_time_l    = (const float*)d_in[25];
    const float* cat_feat      = (const float*)d_in[26];
    const float* edge_identify = (const float*)d_in[27];
    const int*   node_idx      = (const int*)d_in[28];
    const int*   edge_idx      = (const int*)d_in[29];

    char* wsb = (char*)d_ws;
    double* acc = (double*)wsb;

    const int   wkp[9] = {384, 192, 128, 256, 256, 256, 128, 192, 192};
    const int   wnp[9] = {192, 128, 128, 256, 256, 128, 128, 192, 128};
    const int   wkt[9] = {347, 172, 128, 256, 256, 256, 128, 140, 140};
    const int   wnt[9] = {172, 128, 128, 256, 256, 128, 128, 140, 128};
    const float* wsrc[9] = {ev_W, ev_m1W, ev_m2W, at_W1, at_W2, at_m1W, at_m2W, f_W1, f_W2};
    _Float16* wH[9];
    size_t woff = 256;
    WAll wa = {};
    int cum = 0;
    for (int i = 0; i < 9; ++i) {
        size_t plane = (size_t)wkp[i] * wnp[i];
        wH[i] = (_Float16*)(wsb + woff);
        woff += plane * sizeof(_Float16);
        woff = (woff + 15) & ~(size_t)15;
        wa.w[i].src = wsrc[i]; wa.w[i].dH = wH[i];
        wa.w[i].Kt = wkt[i]; wa.w[i].Nt = wnt[i]; wa.w[i].Kp = wkp[i]; wa.w[i].Np = wnp[i];
        wa.w[i].off = cum;
        cum += (wnp[i] / 16) * (wkp[i] / 32) * 64;
    }
    wa.grand = cum;

    hipMemsetAsync(d_ws, 0, 16, stream);
    k_std<<<64, NTH, 0, stream>>>(time_idx, cut_time_l, acc);
    k_wprep_all<<<CDIV(wa.grand, NTH), NTH, 0, stream>>>(wa);

    size_t avail = ws_size > woff + 4096 ? ws_size - woff - 4096 : 0;
    size_t nwc_s = avail / 1536;
    int nwc = (int)(nwc_s > NWIN_TOTAL ? NWIN_TOTAL : nwc_s);
    if (nwc < 1) nwc = 1;
    _Float16* updB = (_Float16*)(wsb + ((woff + 255) & ~(size_t)255));

    for (int c0 = 0; c0 < NWIN_TOTAL; c0 += nwc) {
        int nw = NWIN_TOTAL - c0 < nwc ? NWIN_TOTAL - c0 : nwc;
        int M3 = nw * 3;

        GCP gc = {};
        gc.W0h = wH[0]; gc.W1h = wH[1]; gc.W2h = wH[2];
        gc.b0 = ev_b; gc.b1 = ev_m1b; gc.b2 = ev_m2b;
        gc.upd = updB; gc.M = M3; gc.win0 = c0;
        gc.edge_table = edge_table; gc.node_table = node_table;
        gc.basis_freq = basis_freq; gc.phase = phase;
        gc.time_idx = time_idx; gc.cut = cut_time_l;
        gc.edge_idx = edge_idx; gc.node_idx = node_idx; gc.eid = edge_identify;
        k_gc<<<CDIV(M3, 32), NTH, 0, stream>>>(gc);

        AttnP ap = {};
        ap.upd = updB;
        ap.W1h = wH[3]; ap.W2h = wH[4];
        ap.M1h = wH[5]; ap.M2h = wH[6];
        ap.F1h = wH[7]; ap.F2h = wH[8];
        ap.ab1 = at_b1; ap.ab2 = at_b2; ap.am1b = at_m1b; ap.am2b = at_m2b;
        ap.fb1 = f_b1; ap.fb2 = f_b2; ap.fW3 = f_W3; ap.fb3 = f_b3;
        ap.time_idx = time_idx; ap.cut = cut_time_l; ap.cat = cat_feat; ap.acc = acc;
        ap.out = (float*)d_out; ap.nw = nw; ap.win0 = c0;
        k_attn<<<CDIV(nw, 32), NTH, 0, stream>>>(ap);
    }
}

// Round 21
// 157.028 us; speedup vs baseline: 1.6968x; 1.0441x over previous
//
#include <hip/hip_runtime.h>
#include <math.h>

#define NWIN_TOTAL (256 * 128)
#define NTH 256
#define CDIV(a, b) (((a) + (b) - 1) / (b))

typedef _Float16 f16x8 __attribute__((ext_vector_type(8)));
typedef float f32x4 __attribute__((ext_vector_type(4)));

// hi-only A and B everywhere (lo-planes measured below fp16-storage error floor)
__device__ __forceinline__ void mma1(f16x8 a, f16x8 bh, f32x4& c) {
    c = __builtin_amdgcn_mfma_f32_16x16x32_f16(a, bh, c, 0, 0, 0);
}

// ---------------- global std ----------------
__global__ __launch_bounds__(NTH) void k_std(const float* __restrict__ time_idx,
                                             const float* __restrict__ cut,
                                             double* __restrict__ acc) {
    int tid = threadIdx.x;
    const int n = NWIN_TOTAL * 2;
    double s = 0.0, s2 = 0.0;
    for (int i = blockIdx.x * blockDim.x + tid; i < n; i += gridDim.x * blockDim.x) {
        int j = i & 1;
        int bw = i >> 1;
        float d = fabsf(cut[bw >> 7] - time_idx[bw * 3 + j]);
        s += (double)d;
        s2 += (double)d * (double)d;
    }
    __shared__ double ls[NTH], ls2[NTH];
    ls[tid] = s; ls2[tid] = s2;
    __syncthreads();
    for (int st = NTH / 2; st > 0; st >>= 1) {
        if (tid < st) { ls[tid] += ls[tid + st]; ls2[tid] += ls2[tid + st]; }
        __syncthreads();
    }
    if (tid == 0) { atomicAdd(&acc[0], ls[0]); atomicAdd(&acc[1], ls2[0]); }
}

// ---------------- all weights -> B-fragment hi plane only (one launch) ----------------
struct WEnt { const float* src; _Float16* dH; int Kt, Nt, Kp, Np, off; };
struct WAll { WEnt w[9]; int grand; };

__global__ __launch_bounds__(NTH) void k_wprep_all(WAll a) {
    int idx = blockIdx.x * NTH + threadIdx.x;
    if (idx >= a.grand) return;
    int i = 0;
#pragma unroll
    for (int t = 0; t < 8; ++t)
        if (i + 1 < 9 && idx >= a.w[i + 1].off) ++i;
    const WEnt& e = a.w[i];
    int lidx = idx - e.off;
    int nks = e.Kp / 32;
    int cg = lidx / (nks * 64);
    int rem = lidx - cg * nks * 64;
    int ks = rem >> 6, lane = rem & 63;
    int col = cg * 16 + (lane & 15);
    for (int j = 0; j < 8; ++j) {
        int k = ks * 32 + ((lane >> 4) << 3) + j;
        float v = (k < e.Kt && col < e.Nt) ? e.src[(size_t)k * e.Nt + col] : 0.f;
        e.dH[(size_t)lidx * 8 + j] = (_Float16)v;
    }
}

// ---------------- frag helpers (swizzled: B ^= (B>>4)&7) ----------------
template <int RG>
__device__ __forceinline__ void frag_store_hf(_Float16* AH, int r, int o,
                                              const float* v) {
    int B = ((o >> 2) * RG + (r >> 4)) * 64 + ((r & 15) | ((o & 3) << 4));
    int off = (B ^ ((B >> 4) & 7)) * 8;
    f16x8 h8;
#pragma unroll
    for (int e = 0; e < 8; ++e) h8[e] = (_Float16)v[e];
    *(f16x8*)&AH[off] = h8;
}

template <int RG>
__device__ __forceinline__ void frag_store_h(_Float16* AH, int r, int o, f16x8 v) {
    int B = ((o >> 2) * RG + (r >> 4)) * 64 + ((r & 15) | ((o & 3) << 4));
    int off = (B ^ ((B >> 4) & 7)) * 8;
    *(f16x8*)&AH[off] = v;
}

// A hi-only staged, B hi-only: 1 MFMA per (rg,j)
template <int RG, int NREP>
__device__ __forceinline__ void mfma_step_h(const _Float16* AH,
                                            const _Float16* __restrict__ Wh,
                                            int nks, int ks, int k2, int wv, int lane,
                                            f32x4 (&acc)[RG][NREP]) {
    f16x8 ah[RG];
#pragma unroll
    for (int rg = 0; rg < RG; ++rg) {
        int B = (k2 * RG + rg) * 64 + lane;
        int off = (B ^ ((B >> 4) & 7)) * 8;
        ah[rg] = *(const f16x8*)&AH[off];
    }
#pragma unroll
    for (int j = 0; j < NREP; ++j) {
        int cg = wv * NREP + j;
        size_t boff = ((size_t)(cg * nks + ks) * 64 + lane) * 8;
        f16x8 bh = *(const f16x8*)&Wh[boff];
#pragma unroll
        for (int rg = 0; rg < RG; ++rg) mma1(ah[rg], bh, acc[rg][j]);
    }
}

// ---------------- K1: fused G1 + conv (dual-dir GEMM1, hi-only A and B) ----------------
struct GCP {
    const _Float16 *W0h, *W1h, *W2h;
    const float *b0, *b1, *b2;
    _Float16* upd; int M; int win0;
    const float* edge_table; const float* node_table;
    const float* basis_freq; const float* phase;
    const float* time_idx; const float* cut;
    const int* edge_idx; const int* node_idx; const float* eid;
};

__global__ __launch_bounds__(NTH) void k_gc(GCP p) {
    __shared__ _Float16 AH[2][2048];     // phase1: double-buffer; conv: per-dir
    __shared__ _Float16 evL[32 * 184];
    __shared__ _Float16 h1L[32 * 136];
    __shared__ float ldsBF[176], ldsPH[176];
    const int tid = threadIdx.x, wv = tid >> 6, lane = tid & 63;
    const int mtile = blockIdx.x * 32;
    const int o = tid & 7, r = tid >> 3;

    if (tid < 172) { ldsBF[tid] = p.basis_freq[tid]; ldsPH[tid] = p.phase[tid]; }

    int grow = mtile + r; if (grow >= p.M) grow = p.M - 1;
    int w3 = grow / 3, l = grow - w3 * 3;
    int gw = p.win0 + w3;
    int nb = gw * 6 + 2 * l;
    const float* er = p.edge_table + (size_t)p.edge_idx[gw * 3 + l] * 172;
    const float* S0 = p.node_table + (size_t)p.node_idx[nb] * 172;
    const float* T0 = p.node_table + (size_t)p.node_idx[nb + 1] * 172;
    float dlt = p.cut[gw >> 7] - p.time_idx[gw * 3 + l];
    float g[3][8]; float eidv[3];
#pragma unroll
    for (int kc = 0; kc < 3; ++kc) {
        int k0 = kc * 64 + o * 8;
        if (k0 + 7 < 172) {
            float4 x = *(const float4*)&er[k0];
            float4 y = *(const float4*)&er[k0 + 4];
            g[kc][0]=x.x; g[kc][1]=x.y; g[kc][2]=x.z; g[kc][3]=x.w;
            g[kc][4]=y.x; g[kc][5]=y.y; g[kc][6]=y.z; g[kc][7]=y.w;
        } else if (k0 == 168) {
            float4 x = *(const float4*)&er[168];
            g[kc][0]=x.x; g[kc][1]=x.y; g[kc][2]=x.z; g[kc][3]=x.w;
            eidv[0] = p.eid[(gw * 3 + l) * 3 + 0];
            eidv[1] = p.eid[(gw * 3 + l) * 3 + 1];
            eidv[2] = p.eid[(gw * 3 + l) * 3 + 2];
        }
    }
    __syncthreads();   // ldsBF/PH ready

    // ---- Phase 1: ev = evt @ ev_W  (K=384, N=192), double-buffered, hi-only ----
    {
        f32x4 acc[2][3];
#pragma unroll
        for (int rg = 0; rg < 2; ++rg)
#pragma unroll
            for (int j = 0; j < 3; ++j)
#pragma unroll
                for (int i = 0; i < 4; ++i) acc[rg][j][i] = 0.f;
        const int ord[6] = {3, 4, 5, 0, 1, 2};
#pragma unroll
        for (int x = 0; x < 6; ++x) {
            const int kc = ord[x];
            {
                int k0 = kc * 64 + o * 8;
                float v[8];
                if (kc >= 3 || k0 >= 176) {
#pragma unroll
                    for (int e = 0; e < 8; ++e) {
                        int k = k0 + e;
                        int q = k - 175;
                        v[e] = (k < 347) ? __cosf(fmaf(dlt, ldsBF[q], ldsPH[q])) : 0.f;
                    }
                } else if (k0 + 7 < 172) {
#pragma unroll
                    for (int e = 0; e < 8; ++e) v[e] = g[kc][e];
                } else {  // k0 == 168: edge[168..171], id[0..2], time_feat[0]
                    v[0]=g[2][0]; v[1]=g[2][1]; v[2]=g[2][2]; v[3]=g[2][3];
                    v[4]=eidv[0]; v[5]=eidv[1]; v[6]=eidv[2];
                    v[7]=__cosf(fmaf(dlt, ldsBF[0], ldsPH[0]));
                }
                frag_store_hf<2>(AH[x & 1], r, o, v);
            }
            __syncthreads();
#pragma unroll
            for (int k2 = 0; k2 < 2; ++k2) {
                // ks=11 (k=352..383): A and padded W both all-zero -> skip
                if (kc == 5 && k2 == 1) continue;
                mfma_step_h<2, 3>(AH[x & 1], p.W0h, 12,
                                  kc * 2 + k2, k2, wv, lane, acc);
            }
        }
#pragma unroll
        for (int j = 0; j < 3; ++j) {
            int col = (wv * 3 + j) * 16 + (lane & 15);
            if (col < 176) {
                float b = (col < 172) ? p.b0[col] : 0.f;
#pragma unroll
                for (int rg = 0; rg < 2; ++rg)
#pragma unroll
                    for (int i = 0; i < 4; ++i) {
                        int row = rg * 16 + ((lane >> 4) << 2) + i;
                        evL[row * 184 + col] = (_Float16)(acc[rg][j][i] + b);
                    }
            }
        }
    }
    __syncthreads();

    // ---- GEMM1 dual-dir: am0 = S+relu(T+ev), am1 = T+relu(S+ev), hi-only ----
    f32x4 a1[2][2][2];   // [dir][rg][j]
#pragma unroll
    for (int d = 0; d < 2; ++d)
#pragma unroll
        for (int rg = 0; rg < 2; ++rg)
#pragma unroll
            for (int j = 0; j < 2; ++j)
#pragma unroll
                for (int i = 0; i < 4; ++i) a1[d][rg][j][i] = 0.f;
    {
        float Ps[8], Pt[8];
        auto loadST = [&](int kc) {
            int k0 = kc * 64 + o * 8;
            if (k0 + 7 < 172) {
                *(float4*)&Ps[0] = *(const float4*)&S0[k0];
                *(float4*)&Ps[4] = *(const float4*)&S0[k0 + 4];
                *(float4*)&Pt[0] = *(const float4*)&T0[k0];
                *(float4*)&Pt[4] = *(const float4*)&T0[k0 + 4];
            } else if (k0 == 168) {
                *(float4*)&Ps[0] = *(const float4*)&S0[168];
                *(float4*)&Pt[0] = *(const float4*)&T0[168];
            }
        };
        loadST(0);
#pragma unroll
        for (int kc = 0; kc < 3; ++kc) {
            {
                int k0 = kc * 64 + o * 8;
                float v0[8], v1[8];
                if (k0 + 7 < 172) {
                    f16x8 e8 = *(const f16x8*)&evL[r * 184 + k0];
#pragma unroll
                    for (int e = 0; e < 8; ++e) {
                        float ev = (float)e8[e];
                        v0[e] = Ps[e] + fmaxf(Pt[e] + ev, 0.f);
                        v1[e] = Pt[e] + fmaxf(Ps[e] + ev, 0.f);
                    }
                } else if (k0 == 168) {
                    f16x8 e8 = *(const f16x8*)&evL[r * 184 + 168];
#pragma unroll
                    for (int e = 0; e < 8; ++e) {
                        if (e < 4) {
                            float ev = (float)e8[e];
                            v0[e] = Ps[e] + fmaxf(Pt[e] + ev, 0.f);
                            v1[e] = Pt[e] + fmaxf(Ps[e] + ev, 0.f);
                        } else { v0[e] = 0.f; v1[e] = 0.f; }
                    }
                } else {
#pragma unroll
                    for (int e = 0; e < 8; ++e) { v0[e] = 0.f; v1[e] = 0.f; }
                }
                frag_store_hf<2>(AH[0], r, o, v0);
                frag_store_hf<2>(AH[1], r, o, v1);
            }
            if (kc < 2) loadST(kc + 1);
            __syncthreads();
#pragma unroll
            for (int k2 = 0; k2 < 2; ++k2) {
                const int ks = kc * 2 + k2;
                f16x8 ah[2][2];
#pragma unroll
                for (int d = 0; d < 2; ++d)
#pragma unroll
                    for (int rg = 0; rg < 2; ++rg) {
                        int B = (k2 * 2 + rg) * 64 + lane;
                        int off = (B ^ ((B >> 4) & 7)) * 8;
                        ah[d][rg] = *(const f16x8*)&AH[d][off];
                    }
#pragma unroll
                for (int j = 0; j < 2; ++j) {
                    size_t boff = ((size_t)((wv * 2 + j) * 6 + ks) * 64 + lane) * 8;
                    f16x8 bh = *(const f16x8*)&p.W1h[boff];
#pragma unroll
                    for (int d = 0; d < 2; ++d)
#pragma unroll
                        for (int rg = 0; rg < 2; ++rg)
                            mma1(ah[d][rg], bh, a1[d][rg][j]);
                }
            }
            __syncthreads();
        }
    }

    // ---- per dir: h1 -> LDS fp16, then GEMM2 (direct frag loads, hi-only) ----
    for (int dir = 0; dir < 2; ++dir) {
#pragma unroll
        for (int j = 0; j < 2; ++j) {
            int col = (wv * 2 + j) * 16 + (lane & 15);
            float b = p.b1[col];
#pragma unroll
            for (int rg = 0; rg < 2; ++rg)
#pragma unroll
                for (int i = 0; i < 4; ++i) {
                    int row = rg * 16 + ((lane >> 4) << 2) + i;
                    float x = a1[dir][rg][j][i] + b;
                    h1L[row * 136 + col] = (_Float16)(x > 0.f ? x : 0.f);
                }
        }
        __syncthreads();

        f32x4 a2[2][2];
#pragma unroll
        for (int rg = 0; rg < 2; ++rg)
#pragma unroll
            for (int j = 0; j < 2; ++j)
#pragma unroll
                for (int i = 0; i < 4; ++i) a2[rg][j][i] = 0.f;
#pragma unroll
        for (int ks = 0; ks < 4; ++ks) {
            const int k0 = ks * 32 + ((lane >> 4) << 3);
            f16x8 a4[2];
#pragma unroll
            for (int rg = 0; rg < 2; ++rg)
                a4[rg] = *(const f16x8*)&h1L[(rg * 16 + (lane & 15)) * 136 + k0];
#pragma unroll
            for (int j = 0; j < 2; ++j) {
                size_t boff = ((size_t)((wv * 2 + j) * 4 + ks) * 64 + lane) * 8;
                f16x8 bh = *(const f16x8*)&p.W2h[boff];
#pragma unroll
                for (int rg = 0; rg < 2; ++rg) mma1(a4[rg], bh, a2[rg][j]);
            }
        }
#pragma unroll
        for (int j = 0; j < 2; ++j) {
            int col = (wv * 2 + j) * 16 + (lane & 15);
            float b = p.b2[col];
#pragma unroll
            for (int rg = 0; rg < 2; ++rg)
#pragma unroll
                for (int i = 0; i < 4; ++i) {
                    int row = mtile + rg * 16 + ((lane >> 4) << 2) + i;
                    if (row < p.M)
                        p.upd[(size_t)row * 256 + dir * 128 + col] = (_Float16)(a2[rg][j][i] + b);
                }
        }
        if (dir == 0) __syncthreads();
    }
}

// ---------------- K2: fused attention + head (32 windows / block), hi-only ----------------
struct AttnP {
    const _Float16* upd;
    const _Float16 *W1h,*W2h,*M1h,*M2h,*F1h,*F2h;
    const float *ab1,*ab2,*am1b,*am2b,*fb1,*fb2,*fW3,*fb3;
    const float *time_idx,*cut,*cat; const double* acc;
    float* out; int nw; int win0;
};

__global__ __launch_bounds__(NTH) void k_attn(AttnP p) {
    __shared__ float R1[32 * 260];
    __shared__ _Float16 R2h[64 * 264];
    __shared__ _Float16 AH2[2][2048];
    __shared__ float scoreL[64], aL[64], finL[32];
    float* R2f = (float*)R2h;
    const int tid = threadIdx.x, wv = tid >> 6, lane = tid & 63;
    const int w0 = blockIdx.x * 32;
    const int rr = tid >> 3, o = tid & 7;
    if (tid < 64) scoreL[tid] = 0.f;
    if (tid < 32) finL[tid] = 0.f;
    __syncthreads();

    // ---- Phase A: wp = upd[w*3+2] @ at_W1 (double-buffered, hi-only) ----
    {
        int lw = w0 + rr; if (lw >= p.nw) lw = p.nw - 1;
        const _Float16* Ar = p.upd + ((size_t)lw * 3 + 2) * 256;
        f32x4 acc[2][4];
#pragma unroll
        for (int rg = 0; rg < 2; ++rg)
#pragma unroll
            for (int j = 0; j < 4; ++j)
#pragma unroll
                for (int i = 0; i < 4; ++i) acc[rg][j][i] = 0.f;
        f16x8 P = *(const f16x8*)&Ar[o * 8];
#pragma unroll
        for (int kc = 0; kc < 4; ++kc) {
            frag_store_h<2>(AH2[kc & 1], rr, o, P);
            if (kc < 3) P = *(const f16x8*)&Ar[(kc + 1) * 64 + o * 8];
            __syncthreads();
#pragma unroll
            for (int k2 = 0; k2 < 2; ++k2)
                mfma_step_h<2, 4>(AH2[kc & 1], p.W1h, 8, kc * 2 + k2, k2, wv, lane, acc);
        }
#pragma unroll
        for (int j = 0; j < 4; ++j) {
            int col = (wv * 4 + j) * 16 + (lane & 15);
            float b = p.ab1[col];
#pragma unroll
            for (int rg = 0; rg < 2; ++rg)
#pragma unroll
                for (int i = 0; i < 4; ++i) {
                    int row = rg * 16 + ((lane >> 4) << 2) + i;
                    R1[row * 260 + col] = acc[rg][j][i] + b;
                }
        }
    }

    // ---- Phase B: wq (two 32-row subtiles) + score partials ----
    for (int st = 0; st < 2; ++st) {
        int g = st * 32 + rr;
        int lw = w0 + (g >> 1); if (lw >= p.nw) lw = p.nw - 1;
        const _Float16* Ar = p.upd + ((size_t)lw * 3 + (g & 1)) * 256;
        f32x4 acc[2][4];
#pragma unroll
        for (int rg = 0; rg < 2; ++rg)
#pragma unroll
            for (int j = 0; j < 4; ++j)
#pragma unroll
                for (int i = 0; i < 4; ++i) acc[rg][j][i] = 0.f;
        f16x8 P = *(const f16x8*)&Ar[o * 8];
#pragma unroll
        for (int kc = 0; kc < 4; ++kc) {
            frag_store_h<2>(AH2[kc & 1], rr, o, P);
            if (kc < 3) P = *(const f16x8*)&Ar[(kc + 1) * 64 + o * 8];
            __syncthreads();
#pragma unroll
            for (int k2 = 0; k2 < 2; ++k2)
                mfma_step_h<2, 4>(AH2[kc & 1], p.W2h, 8, kc * 2 + k2, k2, wv, lane, acc);
        }
        float scp[2][4];
#pragma unroll
        for (int rg = 0; rg < 2; ++rg)
#pragma unroll
            for (int i = 0; i < 4; ++i) scp[rg][i] = 0.f;
#pragma unroll
        for (int j = 0; j < 4; ++j) {
            int col = (wv * 4 + j) * 16 + (lane & 15);
            float b = p.ab2[col];
#pragma unroll
            for (int rg = 0; rg < 2; ++rg)
#pragma unroll
                for (int i = 0; i < 4; ++i) {
                    int row = rg * 16 + ((lane >> 4) << 2) + i;
                    int gg = st * 32 + row;
                    float v = acc[rg][j][i] + b;
                    R2h[gg * 264 + col] = (_Float16)v;
                    scp[rg][i] += v * R1[(gg >> 1) * 260 + col];
                }
        }
#pragma unroll
        for (int rg = 0; rg < 2; ++rg)
#pragma unroll
            for (int i = 0; i < 4; ++i) {
                float sv = scp[rg][i];
#pragma unroll
                for (int off = 1; off < 16; off <<= 1) sv += __shfl_xor(sv, off);
                if ((lane & 15) == 0) {
                    int gg = st * 32 + rg * 16 + ((lane >> 4) << 2) + i;
                    atomicAdd(&scoreL[gg], sv);
                }
            }
    }
    __syncthreads();

    // ---- Phase C: softmax alphas only (outf fused into Phase D staging) ----
    if (tid < 32) {
        int lw = w0 + tid; if (lw >= p.nw) lw = p.nw - 1;
        int gw = p.win0 + lw;
        const double n = (double)(NWIN_TOTAL * 2);
        float stdv = (float)sqrt((p.acc[1] - p.acc[0] * p.acc[0] / n) / (n - 1.0));
        float cutv = p.cut[gw >> 7];
        float d0 = fabsf(cutv - p.time_idx[gw * 3 + 0]);
        float d1 = fabsf(cutv - p.time_idx[gw * 3 + 1]);
        float tw0 = expf(-d0 / (stdv + 1e-6f));
        float tw1 = expf(-d1 / (stdv + 1e-6f));
        float s0 = scoreL[tid * 2 + 0] * (0.7f + 0.3f * tw0);
        float s1 = scoreL[tid * 2 + 1] * (0.7f + 0.3f * tw1);
        float m = fmaxf(s0, s1);
        float e0 = expf(s0 - m), e1 = expf(s1 - m);
        float inv = 1.f / (e0 + e1);
        aL[tid * 2 + 0] = e0 * inv;
        aL[tid * 2 + 1] = e1 * inv;
    }
    __syncthreads();

    // ---- Phase D: h2 = relu(outf @ at_m1W), outf computed in-stage ----
    {
        int lw = w0 + rr; if (lw >= p.nw) lw = p.nw - 1;
        const _Float16* U2 = p.upd + ((size_t)lw * 3 + 2) * 256;
        f32x4 acc[2][2];
#pragma unroll
        for (int rg = 0; rg < 2; ++rg)
#pragma unroll
            for (int j = 0; j < 2; ++j)
#pragma unroll
                for (int i = 0; i < 4; ++i) acc[rg][j][i] = 0.f;
        for (int kc = 0; kc < 4; ++kc) {
            __syncthreads();
            {
                int k0 = kc * 64 + o * 8;
                float a0 = aL[rr * 2], a1v = aL[rr * 2 + 1];
                f16x8 u8 = *(const f16x8*)&U2[k0];
                f16x8 q0 = *(const f16x8*)&R2h[(rr * 2) * 264 + k0];
                f16x8 q1 = *(const f16x8*)&R2h[(rr * 2 + 1) * 264 + k0];
                float v[8];
#pragma unroll
                for (int e = 0; e < 8; ++e)
                    v[e] = (float)u8[e] + a0 * (float)q0[e] + a1v * (float)q1[e];
                frag_store_hf<2>(AH2[0], rr, o, v);
            }
            __syncthreads();
#pragma unroll
            for (int k2 = 0; k2 < 2; ++k2)
                mfma_step_h<2, 2>(AH2[0], p.M1h, 8, kc * 2 + k2, k2, wv, lane, acc);
        }
        __syncthreads();
#pragma unroll
        for (int j = 0; j < 2; ++j) {
            int col = (wv * 2 + j) * 16 + (lane & 15);
            float b = p.am1b[col];
#pragma unroll
            for (int rg = 0; rg < 2; ++rg)
#pragma unroll
                for (int i = 0; i < 4; ++i) {
                    int row = rg * 16 + ((lane >> 4) << 2) + i;
                    float x = acc[rg][j][i] + b;
                    R2f[row * 132 + col] = x > 0.f ? x : 0.f;
                }
        }
    }
    __syncthreads();

    // xz extra cols (stride 196)
    for (int q = tid; q < 32 * 68; q += NTH) {
        int r = q / 68, c = 128 + q % 68;
        int lw = w0 + r; if (lw >= p.nw) lw = p.nw - 1;
        int gw = p.win0 + lw;
        R1[r * 196 + c] = (c < 140) ? p.cat[(size_t)gw * 12 + (c - 128)] : 0.f;
    }

    // ---- Phase E: h3 = h2 @ at_m2W -> R1 stride 196 cols 0..127, hi-only ----
    {
        f32x4 acc[2][2];
#pragma unroll
        for (int rg = 0; rg < 2; ++rg)
#pragma unroll
            for (int j = 0; j < 2; ++j)
#pragma unroll
                for (int i = 0; i < 4; ++i) acc[rg][j][i] = 0.f;
        for (int kc = 0; kc < 2; ++kc) {
            __syncthreads();
            {
                int k0 = kc * 64 + o * 8;
                float v[8];
                float4 x = *(const float4*)&R2f[rr * 132 + k0];
                float4 y = *(const float4*)&R2f[rr * 132 + k0 + 4];
                v[0]=x.x; v[1]=x.y; v[2]=x.z; v[3]=x.w;
                v[4]=y.x; v[5]=y.y; v[6]=y.z; v[7]=y.w;
                frag_store_hf<2>(AH2[0], rr, o, v);
            }
            __syncthreads();
#pragma unroll
            for (int k2 = 0; k2 < 2; ++k2)
                mfma_step_h<2, 2>(AH2[0], p.M2h, 4, kc * 2 + k2, k2, wv, lane, acc);
        }
        __syncthreads();
#pragma unroll
        for (int j = 0; j < 2; ++j) {
            int col = (wv * 2 + j) * 16 + (lane & 15);
            float b = p.am2b[col];
#pragma unroll
            for (int rg = 0; rg < 2; ++rg)
#pragma unroll
                for (int i = 0; i < 4; ++i) {
                    int row = rg * 16 + ((lane >> 4) << 2) + i;
                    R1[row * 196 + col] = acc[rg][j][i] + b;
                }
        }
    }

    // ---- Phase F: z1 = relu(xz @ f_W1) -> R2f stride 196, hi-only ----
    {
        f32x4 acc[2][3];
#pragma unroll
        for (int rg = 0; rg < 2; ++rg)
#pragma unroll
            for (int j = 0; j < 3; ++j)
#pragma unroll
                for (int i = 0; i < 4; ++i) acc[rg][j][i] = 0.f;
        for (int kc = 0; kc < 3; ++kc) {
            __syncthreads();
            {
                int k0 = kc * 64 + o * 8;
                float v[8];
                float4 x = *(const float4*)&R1[rr * 196 + k0];
                float4 y = *(const float4*)&R1[rr * 196 + k0 + 4];
                v[0]=x.x; v[1]=x.y; v[2]=x.z; v[3]=x.w;
                v[4]=y.x; v[5]=y.y; v[6]=y.z; v[7]=y.w;
                frag_store_hf<2>(AH2[0], rr, o, v);
            }
            __syncthreads();
#pragma unroll
            for (int k2 = 0; k2 < 2; ++k2)
                mfma_step_h<2, 3>(AH2[0], p.F1h, 6, kc * 2 + k2, k2, wv, lane, acc);
        }
        __syncthreads();
#pragma unroll
        for (int j = 0; j < 3; ++j) {
            int col = (wv * 3 + j) * 16 + (lane & 15);
            float b = (col < 140) ? p.fb1[col] : 0.f;
#pragma unroll
            for (int rg = 0; rg < 2; ++rg)
#pragma unroll
                for (int i = 0; i < 4; ++i) {
                    int row = rg * 16 + ((lane >> 4) << 2) + i;
                    float x = acc[rg][j][i] + b;
                    R2f[row * 196 + col] = x > 0.f ? x : 0.f;
                }
        }
    }

    // ---- Phase G: z2 = relu(z1 @ f_W2) fused with final dot, hi-only ----
    {
        f32x4 acc[2][2];
#pragma unroll
        for (int rg = 0; rg < 2; ++rg)
#pragma unroll
            for (int j = 0; j < 2; ++j)
#pragma unroll
                for (int i = 0; i < 4; ++i) acc[rg][j][i] = 0.f;
        for (int kc = 0; kc < 3; ++kc) {
            __syncthreads();
            {
                int k0 = kc * 64 + o * 8;
                float v[8];
                float4 x = *(const float4*)&R2f[rr * 196 + k0];
                float4 y = *(const float4*)&R2f[rr * 196 + k0 + 4];
                v[0]=x.x; v[1]=x.y; v[2]=x.z; v[3]=x.w;
                v[4]=y.x; v[5]=y.y; v[6]=y.z; v[7]=y.w;
                frag_store_hf<2>(AH2[0], rr, o, v);
            }
            __syncthreads();
#pragma unroll
            for (int k2 = 0; k2 < 2; ++k2)
                mfma_step_h<2, 2>(AH2[0], p.F2h, 6, kc * 2 + k2, k2, wv, lane, acc);
        }
        float pt[2][4];
#pragma unroll
        for (int rg = 0; rg < 2; ++rg)
#pragma unroll
            for (int i = 0; i < 4; ++i) pt[rg][i] = 0.f;
#pragma unroll
        for (int j = 0; j < 2; ++j) {
            int col = (wv * 2 + j) * 16 + (lane & 15);
            float b = p.fb2[col];
            float w3 = p.fW3[col];
#pragma unroll
            for (int rg = 0; rg < 2; ++rg)
#pragma unroll
                for (int i = 0; i < 4; ++i) {
                    float x = acc[rg][j][i] + b;
                    x = x > 0.f ? x : 0.f;
                    pt[rg][i] += x * w3;
                }
        }
#pragma unroll
        for (int rg = 0; rg < 2; ++rg)
#pragma unroll
            for (int i = 0; i < 4; ++i) {
                float sv = pt[rg][i];
#pragma unroll
                for (int off = 1; off < 16; off <<= 1) sv += __shfl_xor(sv, off);
                if ((lane & 15) == 0)
                    atomicAdd(&finL[rg * 16 + ((lane >> 4) << 2) + i], sv);
            }
    }
    __syncthreads();
    if (tid < 32 && w0 + tid < p.nw)
        p.out[p.win0 + w0 + tid] = finL[tid] + p.fb3[0];
}

extern "C" void kernel_launch(void* const* d_in, const int* in_sizes, int n_in,
                              void* d_out, int out_size, void* d_ws, size_t ws_size,
                              hipStream_t stream) {
    const float* node_table    = (const float*)d_in[0];
    const float* edge_table    = (const float*)d_in[1];
    const float* basis_freq    = (const float*)d_in[2];
    const float* phase         = (const float*)d_in[3];
    const float* ev_W          = (const float*)d_in[4];
    const float* ev_b          = (const float*)d_in[5];
    const float* ev_m1W        = (const float*)d_in[6];
    const float* ev_m1b        = (const float*)d_in[7];
    const float* ev_m2W        = (const float*)d_in[8];
    const float* ev_m2b        = (const float*)d_in[9];
    const float* at_W1         = (const float*)d_in[10];
    const float* at_b1         = (const float*)d_in[11];
    const float* at_W2         = (const float*)d_in[12];
    const float* at_b2         = (const float*)d_in[13];
    const float* at_m1W        = (const float*)d_in[14];
    const float* at_m1b        = (const float*)d_in[15];
    const float* at_m2W        = (const float*)d_in[16];
    const float* at_m2b        = (const float*)d_in[17];
    const float* f_W1          = (const float*)d_in[18];
    const float* f_b1          = (const float*)d_in[19];
    const float* f_W2          = (const float*)d_in[20];
    const float* f_b2          = (const float*)d_in[21];
    const float* f_W3          = (const float*)d_in[22];
    const float* f_b3          = (const float*)d_in[23];
    const float* time_idx      = (const float*)d_in[24];
    const float* cut_time_l    = (const float*)d_in[25];
    const float* cat_feat      = (const float*)d_in[26];
    const float* edge_identify = (const float*)d_in[27];
    const int*   node_idx      = (const int*)d_in[28];
    const int*   edge_idx      = (const int*)d_in[29];

    char* wsb = (char*)d_ws;
    double* acc = (double*)wsb;

    const int   wkp[9] = {384, 192, 128, 256, 256, 256, 128, 192, 192};
    const int   wnp[9] = {192, 128, 128, 256, 256, 128, 128, 192, 128};
    const int   wkt[9] = {347, 172, 128, 256, 256, 256, 128, 140, 140};
    const int   wnt[9] = {172, 128, 128, 256, 256, 128, 128, 140, 128};
    const float* wsrc[9] = {ev_W, ev_m1W, ev_m2W, at_W1, at_W2, at_m1W, at_m2W, f_W1, f_W2};
    _Float16* wH[9];
    size_t woff = 256;
    WAll wa = {};
    int cum = 0;
    for (int i = 0; i < 9; ++i) {
        size_t plane = (size_t)wkp[i] * wnp[i];
        wH[i] = (_Float16*)(wsb + woff);
        woff += plane * sizeof(_Float16);
        woff = (woff + 15) & ~(size_t)15;
        wa.w[i].src = wsrc[i]; wa.w[i].dH = wH[i];
        wa.w[i].Kt = wkt[i]; wa.w[i].Nt = wnt[i]; wa.w[i].Kp = wkp[i]; wa.w[i].Np = wnp[i];
        wa.w[i].off = cum;
        cum += (wnp[i] / 16) * (wkp[i] / 32) * 64;
    }
    wa.grand = cum;

    hipMemsetAsync(d_ws, 0, 16, stream);
    k_std<<<64, NTH, 0, stream>>>(time_idx, cut_time_l, acc);
    k_wprep_all<<<CDIV(wa.grand, NTH), NTH, 0, stream>>>(wa);

    size_t avail = ws_size > woff + 4096 ? ws_size - woff - 4096 : 0;
    size_t nwc_s = avail / 1536;
    int nwc = (int)(nwc_s > NWIN_TOTAL ? NWIN_TOTAL : nwc_s);
    if (nwc < 1) nwc = 1;
    _Float16* updB = (_Float16*)(wsb + ((woff + 255) & ~(size_t)255));

    for (int c0 = 0; c0 < NWIN_TOTAL; c0 += nwc) {
        int nw = NWIN_TOTAL - c0 < nwc ? NWIN_TOTAL - c0 : nwc;
        int M3 = nw * 3;

        GCP gc = {};
        gc.W0h = wH[0]; gc.W1h = wH[1]; gc.W2h = wH[2];
        gc.b0 = ev_b; gc.b1 = ev_m1b; gc.b2 = ev_m2b;
        gc.upd = updB; gc.M = M3; gc.win0 = c0;
        gc.edge_table = edge_table; gc.node_table = node_table;
        gc.basis_freq = basis_freq; gc.phase = phase;
        gc.time_idx = time_idx; gc.cut = cut_time_l;
        gc.edge_idx = edge_idx; gc.node_idx = node_idx; gc.eid = edge_identify;
        k_gc<<<CDIV(M3, 32), NTH, 0, stream>>>(gc);

        AttnP ap = {};
        ap.upd = updB;
        ap.W1h = wH[3]; ap.W2h = wH[4];
        ap.M1h = wH[5]; ap.M2h = wH[6];
        ap.F1h = wH[7]; ap.F2h = wH[8];
        ap.ab1 = at_b1; ap.ab2 = at_b2; ap.am1b = at_m1b; ap.am2b = at_m2b;
        ap.fb1 = f_b1; ap.fb2 = f_b2; ap.fW3 = f_W3; ap.fb3 = f_b3;
        ap.time_idx = time_idx; ap.cut = cut_time_l; ap.cat = cat_feat; ap.acc = acc;
        ap.out = (float*)d_out; ap.nw = nw; ap.win0 = c0;
        k_attn<<<CDIV(nw, 32), NTH, 0, stream>>>(ap);
    }
}

// Round 22
// 156.124 us; speedup vs baseline: 1.7066x; 1.0058x over previous
//
#include <hip/hip_runtime.h>
#include <math.h>

#define NWIN_TOTAL (256 * 128)
#define NTH 256
#define CDIV(a, b) (((a) + (b) - 1) / (b))

typedef _Float16 f16x8 __attribute__((ext_vector_type(8)));
typedef float f32x4 __attribute__((ext_vector_type(4)));

// hi-only A and B everywhere (lo-planes measured below fp16-storage error floor)
__device__ __forceinline__ void mma1(f16x8 a, f16x8 bh, f32x4& c) {
    c = __builtin_amdgcn_mfma_f32_16x16x32_f16(a, bh, c, 0, 0, 0);
}

// ---------------- global std ----------------
__global__ __launch_bounds__(NTH) void k_std(const float* __restrict__ time_idx,
                                             const float* __restrict__ cut,
                                             double* __restrict__ acc) {
    int tid = threadIdx.x;
    const int n = NWIN_TOTAL * 2;
    double s = 0.0, s2 = 0.0;
    for (int i = blockIdx.x * blockDim.x + tid; i < n; i += gridDim.x * blockDim.x) {
        int j = i & 1;
        int bw = i >> 1;
        float d = fabsf(cut[bw >> 7] - time_idx[bw * 3 + j]);
        s += (double)d;
        s2 += (double)d * (double)d;
    }
    __shared__ double ls[NTH], ls2[NTH];
    ls[tid] = s; ls2[tid] = s2;
    __syncthreads();
    for (int st = NTH / 2; st > 0; st >>= 1) {
        if (tid < st) { ls[tid] += ls[tid + st]; ls2[tid] += ls2[tid + st]; }
        __syncthreads();
    }
    if (tid == 0) { atomicAdd(&acc[0], ls[0]); atomicAdd(&acc[1], ls2[0]); }
}

// ---------------- all weights -> B-fragment hi plane only (one launch) ----------------
struct WEnt { const float* src; _Float16* dH; int Kt, Nt, Kp, Np, off; };
struct WAll { WEnt w[9]; int grand; };

__global__ __launch_bounds__(NTH) void k_wprep_all(WAll a) {
    int idx = blockIdx.x * NTH + threadIdx.x;
    if (idx >= a.grand) return;
    int i = 0;
#pragma unroll
    for (int t = 0; t < 8; ++t)
        if (i + 1 < 9 && idx >= a.w[i + 1].off) ++i;
    const WEnt& e = a.w[i];
    int lidx = idx - e.off;
    int nks = e.Kp / 32;
    int cg = lidx / (nks * 64);
    int rem = lidx - cg * nks * 64;
    int ks = rem >> 6, lane = rem & 63;
    int col = cg * 16 + (lane & 15);
    for (int j = 0; j < 8; ++j) {
        int k = ks * 32 + ((lane >> 4) << 3) + j;
        float v = (k < e.Kt && col < e.Nt) ? e.src[(size_t)k * e.Nt + col] : 0.f;
        e.dH[(size_t)lidx * 8 + j] = (_Float16)v;
    }
}

// ---------------- frag helpers (swizzled: B ^= (B>>4)&7) ----------------
template <int RG>
__device__ __forceinline__ void frag_store_hf(_Float16* AH, int r, int o,
                                              const float* v) {
    int B = ((o >> 2) * RG + (r >> 4)) * 64 + ((r & 15) | ((o & 3) << 4));
    int off = (B ^ ((B >> 4) & 7)) * 8;
    f16x8 h8;
#pragma unroll
    for (int e = 0; e < 8; ++e) h8[e] = (_Float16)v[e];
    *(f16x8*)&AH[off] = h8;
}

template <int RG>
__device__ __forceinline__ void frag_store_h(_Float16* AH, int r, int o, f16x8 v) {
    int B = ((o >> 2) * RG + (r >> 4)) * 64 + ((r & 15) | ((o & 3) << 4));
    int off = (B ^ ((B >> 4) & 7)) * 8;
    *(f16x8*)&AH[off] = v;
}

// A hi-only staged, B hi-only: 1 MFMA per (rg,j)
template <int RG, int NREP>
__device__ __forceinline__ void mfma_step_h(const _Float16* AH,
                                            const _Float16* __restrict__ Wh,
                                            int nks, int ks, int k2, int wv, int lane,
                                            f32x4 (&acc)[RG][NREP]) {
    f16x8 ah[RG];
#pragma unroll
    for (int rg = 0; rg < RG; ++rg) {
        int B = (k2 * RG + rg) * 64 + lane;
        int off = (B ^ ((B >> 4) & 7)) * 8;
        ah[rg] = *(const f16x8*)&AH[off];
    }
#pragma unroll
    for (int j = 0; j < NREP; ++j) {
        int cg = wv * NREP + j;
        size_t boff = ((size_t)(cg * nks + ks) * 64 + lane) * 8;
        f16x8 bh = *(const f16x8*)&Wh[boff];
#pragma unroll
        for (int rg = 0; rg < RG; ++rg) mma1(ah[rg], bh, acc[rg][j]);
    }
}

// ---------------- K1: fused G1 + conv (dual-dir GEMM1, hi-only A and B) ----------------
struct GCP {
    const _Float16 *W0h, *W1h, *W2h;
    const float *b0, *b1, *b2;
    _Float16* upd; int M; int win0;
    const float* edge_table; const float* node_table;
    const float* basis_freq; const float* phase;
    const float* time_idx; const float* cut;
    const int* edge_idx; const int* node_idx; const float* eid;
};

__global__ __launch_bounds__(NTH) void k_gc(GCP p) {
    __shared__ _Float16 AH[2][2048];     // phase1: double-buffer; conv: per-dir
    __shared__ _Float16 evL[32 * 184];
    __shared__ _Float16 h1L[32 * 136];
    __shared__ float ldsBF[176], ldsPH[176];
    const int tid = threadIdx.x, wv = tid >> 6, lane = tid & 63;
    const int mtile = blockIdx.x * 32;
    const int o = tid & 7, r = tid >> 3;

    if (tid < 172) { ldsBF[tid] = p.basis_freq[tid]; ldsPH[tid] = p.phase[tid]; }

    int grow = mtile + r; if (grow >= p.M) grow = p.M - 1;
    int w3 = grow / 3, l = grow - w3 * 3;
    int gw = p.win0 + w3;
    int nb = gw * 6 + 2 * l;
    const float* er = p.edge_table + (size_t)p.edge_idx[gw * 3 + l] * 172;
    const float* S0 = p.node_table + (size_t)p.node_idx[nb] * 172;
    const float* T0 = p.node_table + (size_t)p.node_idx[nb + 1] * 172;
    float dlt = p.cut[gw >> 7] - p.time_idx[gw * 3 + l];
    float g[3][8]; float eidv[3];
#pragma unroll
    for (int kc = 0; kc < 3; ++kc) {
        int k0 = kc * 64 + o * 8;
        if (k0 + 7 < 172) {
            float4 x = *(const float4*)&er[k0];
            float4 y = *(const float4*)&er[k0 + 4];
            g[kc][0]=x.x; g[kc][1]=x.y; g[kc][2]=x.z; g[kc][3]=x.w;
            g[kc][4]=y.x; g[kc][5]=y.y; g[kc][6]=y.z; g[kc][7]=y.w;
        } else if (k0 == 168) {
            float4 x = *(const float4*)&er[168];
            g[kc][0]=x.x; g[kc][1]=x.y; g[kc][2]=x.z; g[kc][3]=x.w;
            eidv[0] = p.eid[(gw * 3 + l) * 3 + 0];
            eidv[1] = p.eid[(gw * 3 + l) * 3 + 1];
            eidv[2] = p.eid[(gw * 3 + l) * 3 + 2];
        }
    }
    __syncthreads();   // ldsBF/PH ready

    // ---- Phase 1: ev = evt @ ev_W  (K=384, N=192), double-buffered, hi-only ----
    {
        f32x4 acc[2][3];
#pragma unroll
        for (int rg = 0; rg < 2; ++rg)
#pragma unroll
            for (int j = 0; j < 3; ++j)
#pragma unroll
                for (int i = 0; i < 4; ++i) acc[rg][j][i] = 0.f;
        const int ord[6] = {3, 4, 5, 0, 1, 2};
#pragma unroll
        for (int x = 0; x < 6; ++x) {
            const int kc = ord[x];
            {
                int k0 = kc * 64 + o * 8;
                float v[8];
                if (kc >= 3 || k0 >= 176) {
#pragma unroll
                    for (int e = 0; e < 8; ++e) {
                        int k = k0 + e;
                        int q = k - 175;
                        v[e] = (k < 347) ? __cosf(fmaf(dlt, ldsBF[q], ldsPH[q])) : 0.f;
                    }
                } else if (k0 + 7 < 172) {
#pragma unroll
                    for (int e = 0; e < 8; ++e) v[e] = g[kc][e];
                } else {  // k0 == 168: edge[168..171], id[0..2], time_feat[0]
                    v[0]=g[2][0]; v[1]=g[2][1]; v[2]=g[2][2]; v[3]=g[2][3];
                    v[4]=eidv[0]; v[5]=eidv[1]; v[6]=eidv[2];
                    v[7]=__cosf(fmaf(dlt, ldsBF[0], ldsPH[0]));
                }
                frag_store_hf<2>(AH[x & 1], r, o, v);
            }
            __syncthreads();
#pragma unroll
            for (int k2 = 0; k2 < 2; ++k2) {
                if (kc == 5 && k2 == 1) continue;   // k=352..383 all-zero
                mfma_step_h<2, 3>(AH[x & 1], p.W0h, 12,
                                  kc * 2 + k2, k2, wv, lane, acc);
            }
        }
#pragma unroll
        for (int j = 0; j < 3; ++j) {
            int col = (wv * 3 + j) * 16 + (lane & 15);
            if (col < 176) {
                float b = (col < 172) ? p.b0[col] : 0.f;
#pragma unroll
                for (int rg = 0; rg < 2; ++rg)
#pragma unroll
                    for (int i = 0; i < 4; ++i) {
                        int row = rg * 16 + ((lane >> 4) << 2) + i;
                        evL[row * 184 + col] = (_Float16)(acc[rg][j][i] + b);
                    }
            }
        }
    }
    __syncthreads();

    // ---- GEMM1 dual-dir: am0 = S+relu(T+ev), am1 = T+relu(S+ev), hi-only ----
    f32x4 a1[2][2][2];   // [dir][rg][j]
#pragma unroll
    for (int d = 0; d < 2; ++d)
#pragma unroll
        for (int rg = 0; rg < 2; ++rg)
#pragma unroll
            for (int j = 0; j < 2; ++j)
#pragma unroll
                for (int i = 0; i < 4; ++i) a1[d][rg][j][i] = 0.f;
    {
        float Ps[8], Pt[8];
        auto loadST = [&](int kc) {
            int k0 = kc * 64 + o * 8;
            if (k0 + 7 < 172) {
                *(float4*)&Ps[0] = *(const float4*)&S0[k0];
                *(float4*)&Ps[4] = *(const float4*)&S0[k0 + 4];
                *(float4*)&Pt[0] = *(const float4*)&T0[k0];
                *(float4*)&Pt[4] = *(const float4*)&T0[k0 + 4];
            } else if (k0 == 168) {
                *(float4*)&Ps[0] = *(const float4*)&S0[168];
                *(float4*)&Pt[0] = *(const float4*)&T0[168];
            }
        };
        loadST(0);
#pragma unroll
        for (int kc = 0; kc < 3; ++kc) {
            {
                int k0 = kc * 64 + o * 8;
                float v0[8], v1[8];
                if (k0 + 7 < 172) {
                    f16x8 e8 = *(const f16x8*)&evL[r * 184 + k0];
#pragma unroll
                    for (int e = 0; e < 8; ++e) {
                        float ev = (float)e8[e];
                        v0[e] = Ps[e] + fmaxf(Pt[e] + ev, 0.f);
                        v1[e] = Pt[e] + fmaxf(Ps[e] + ev, 0.f);
                    }
                } else if (k0 == 168) {
                    f16x8 e8 = *(const f16x8*)&evL[r * 184 + 168];
#pragma unroll
                    for (int e = 0; e < 8; ++e) {
                        if (e < 4) {
                            float ev = (float)e8[e];
                            v0[e] = Ps[e] + fmaxf(Pt[e] + ev, 0.f);
                            v1[e] = Pt[e] + fmaxf(Ps[e] + ev, 0.f);
                        } else { v0[e] = 0.f; v1[e] = 0.f; }
                    }
                } else {
#pragma unroll
                    for (int e = 0; e < 8; ++e) { v0[e] = 0.f; v1[e] = 0.f; }
                }
                frag_store_hf<2>(AH[0], r, o, v0);
                frag_store_hf<2>(AH[1], r, o, v1);
            }
            if (kc < 2) loadST(kc + 1);
            __syncthreads();
#pragma unroll
            for (int k2 = 0; k2 < 2; ++k2) {
                const int ks = kc * 2 + k2;
                f16x8 ah[2][2];
#pragma unroll
                for (int d = 0; d < 2; ++d)
#pragma unroll
                    for (int rg = 0; rg < 2; ++rg) {
                        int B = (k2 * 2 + rg) * 64 + lane;
                        int off = (B ^ ((B >> 4) & 7)) * 8;
                        ah[d][rg] = *(const f16x8*)&AH[d][off];
                    }
#pragma unroll
                for (int j = 0; j < 2; ++j) {
                    size_t boff = ((size_t)((wv * 2 + j) * 6 + ks) * 64 + lane) * 8;
                    f16x8 bh = *(const f16x8*)&p.W1h[boff];
#pragma unroll
                    for (int d = 0; d < 2; ++d)
#pragma unroll
                        for (int rg = 0; rg < 2; ++rg)
                            mma1(ah[d][rg], bh, a1[d][rg][j]);
                }
            }
            __syncthreads();
        }
    }

    // ---- per dir: h1 -> LDS fp16, then GEMM2 (direct frag loads, hi-only) ----
    for (int dir = 0; dir < 2; ++dir) {
#pragma unroll
        for (int j = 0; j < 2; ++j) {
            int col = (wv * 2 + j) * 16 + (lane & 15);
            float b = p.b1[col];
#pragma unroll
            for (int rg = 0; rg < 2; ++rg)
#pragma unroll
                for (int i = 0; i < 4; ++i) {
                    int row = rg * 16 + ((lane >> 4) << 2) + i;
                    float x = a1[dir][rg][j][i] + b;
                    h1L[row * 136 + col] = (_Float16)(x > 0.f ? x : 0.f);
                }
        }
        __syncthreads();

        f32x4 a2[2][2];
#pragma unroll
        for (int rg = 0; rg < 2; ++rg)
#pragma unroll
            for (int j = 0; j < 2; ++j)
#pragma unroll
                for (int i = 0; i < 4; ++i) a2[rg][j][i] = 0.f;
#pragma unroll
        for (int ks = 0; ks < 4; ++ks) {
            const int k0 = ks * 32 + ((lane >> 4) << 3);
            f16x8 a4[2];
#pragma unroll
            for (int rg = 0; rg < 2; ++rg)
                a4[rg] = *(const f16x8*)&h1L[(rg * 16 + (lane & 15)) * 136 + k0];
#pragma unroll
            for (int j = 0; j < 2; ++j) {
                size_t boff = ((size_t)((wv * 2 + j) * 4 + ks) * 64 + lane) * 8;
                f16x8 bh = *(const f16x8*)&p.W2h[boff];
#pragma unroll
                for (int rg = 0; rg < 2; ++rg) mma1(a4[rg], bh, a2[rg][j]);
            }
        }
#pragma unroll
        for (int j = 0; j < 2; ++j) {
            int col = (wv * 2 + j) * 16 + (lane & 15);
            float b = p.b2[col];
#pragma unroll
            for (int rg = 0; rg < 2; ++rg)
#pragma unroll
                for (int i = 0; i < 4; ++i) {
                    int row = mtile + rg * 16 + ((lane >> 4) << 2) + i;
                    if (row < p.M)
                        p.upd[(size_t)row * 256 + dir * 128 + col] = (_Float16)(a2[rg][j][i] + b);
                }
        }
        if (dir == 0) __syncthreads();
    }
}

// ---------------- K2: fused attention + head (32 windows / block), hi-only ----------------
struct AttnP {
    const _Float16* upd;
    const _Float16 *W1h,*W2h,*M1h,*M2h,*F1h,*F2h;
    const float *ab1,*ab2,*am1b,*am2b,*fb1,*fb2,*fW3,*fb3;
    const float *time_idx,*cut,*cat; const double* acc;
    float* out; int nw; int win0;
};

__global__ __launch_bounds__(NTH) void k_attn(AttnP p) {
    __shared__ float R1[32 * 260];        // wp (A/B); then aliased fp16: H2L / XZL / Z1L
    __shared__ _Float16 R2h[64 * 264];    // wq fp16
    __shared__ _Float16 AH2[2][2048];
    __shared__ float scoreL[64], aL[64], finL[32];
    _Float16* H2L = (_Float16*)R1;                  // [32][136] fp16 (h2)
    _Float16* XZL = ((_Float16*)R1) + 8192;         // [32][200] fp16 (xz)
    _Float16* Z1L = (_Float16*)R1;                  // [32][200] fp16 (z1; h2 dead)
    const int tid = threadIdx.x, wv = tid >> 6, lane = tid & 63;
    const int w0 = blockIdx.x * 32;
    const int rr = tid >> 3, o = tid & 7;
    if (tid < 64) scoreL[tid] = 0.f;
    if (tid < 32) finL[tid] = 0.f;
    __syncthreads();

    // ---- Phase A: wp = upd[w*3+2] @ at_W1 (double-buffered, hi-only) ----
    {
        int lw = w0 + rr; if (lw >= p.nw) lw = p.nw - 1;
        const _Float16* Ar = p.upd + ((size_t)lw * 3 + 2) * 256;
        f32x4 acc[2][4];
#pragma unroll
        for (int rg = 0; rg < 2; ++rg)
#pragma unroll
            for (int j = 0; j < 4; ++j)
#pragma unroll
                for (int i = 0; i < 4; ++i) acc[rg][j][i] = 0.f;
        f16x8 P = *(const f16x8*)&Ar[o * 8];
#pragma unroll
        for (int kc = 0; kc < 4; ++kc) {
            frag_store_h<2>(AH2[kc & 1], rr, o, P);
            if (kc < 3) P = *(const f16x8*)&Ar[(kc + 1) * 64 + o * 8];
            __syncthreads();
#pragma unroll
            for (int k2 = 0; k2 < 2; ++k2)
                mfma_step_h<2, 4>(AH2[kc & 1], p.W1h, 8, kc * 2 + k2, k2, wv, lane, acc);
        }
#pragma unroll
        for (int j = 0; j < 4; ++j) {
            int col = (wv * 4 + j) * 16 + (lane & 15);
            float b = p.ab1[col];
#pragma unroll
            for (int rg = 0; rg < 2; ++rg)
#pragma unroll
                for (int i = 0; i < 4; ++i) {
                    int row = rg * 16 + ((lane >> 4) << 2) + i;
                    R1[row * 260 + col] = acc[rg][j][i] + b;
                }
        }
    }

    // ---- Phase B: wq (two 32-row subtiles) + score partials ----
    for (int st = 0; st < 2; ++st) {
        int g = st * 32 + rr;
        int lw = w0 + (g >> 1); if (lw >= p.nw) lw = p.nw - 1;
        const _Float16* Ar = p.upd + ((size_t)lw * 3 + (g & 1)) * 256;
        f32x4 acc[2][4];
#pragma unroll
        for (int rg = 0; rg < 2; ++rg)
#pragma unroll
            for (int j = 0; j < 4; ++j)
#pragma unroll
                for (int i = 0; i < 4; ++i) acc[rg][j][i] = 0.f;
        f16x8 P = *(const f16x8*)&Ar[o * 8];
#pragma unroll
        for (int kc = 0; kc < 4; ++kc) {
            frag_store_h<2>(AH2[kc & 1], rr, o, P);
            if (kc < 3) P = *(const f16x8*)&Ar[(kc + 1) * 64 + o * 8];
            __syncthreads();
#pragma unroll
            for (int k2 = 0; k2 < 2; ++k2)
                mfma_step_h<2, 4>(AH2[kc & 1], p.W2h, 8, kc * 2 + k2, k2, wv, lane, acc);
        }
        float scp[2][4];
#pragma unroll
        for (int rg = 0; rg < 2; ++rg)
#pragma unroll
            for (int i = 0; i < 4; ++i) scp[rg][i] = 0.f;
#pragma unroll
        for (int j = 0; j < 4; ++j) {
            int col = (wv * 4 + j) * 16 + (lane & 15);
            float b = p.ab2[col];
#pragma unroll
            for (int rg = 0; rg < 2; ++rg)
#pragma unroll
                for (int i = 0; i < 4; ++i) {
                    int row = rg * 16 + ((lane >> 4) << 2) + i;
                    int gg = st * 32 + row;
                    float v = acc[rg][j][i] + b;
                    R2h[gg * 264 + col] = (_Float16)v;
                    scp[rg][i] += v * R1[(gg >> 1) * 260 + col];
                }
        }
#pragma unroll
        for (int rg = 0; rg < 2; ++rg)
#pragma unroll
            for (int i = 0; i < 4; ++i) {
                float sv = scp[rg][i];
#pragma unroll
                for (int off = 1; off < 16; off <<= 1) sv += __shfl_xor(sv, off);
                if ((lane & 15) == 0) {
                    int gg = st * 32 + rg * 16 + ((lane >> 4) << 2) + i;
                    atomicAdd(&scoreL[gg], sv);
                }
            }
    }
    __syncthreads();   // wp reads done; R1 space free for fp16 aliases

    // ---- Phase C: softmax alphas ----
    if (tid < 32) {
        int lw = w0 + tid; if (lw >= p.nw) lw = p.nw - 1;
        int gw = p.win0 + lw;
        const double n = (double)(NWIN_TOTAL * 2);
        float stdv = (float)sqrt((p.acc[1] - p.acc[0] * p.acc[0] / n) / (n - 1.0));
        float cutv = p.cut[gw >> 7];
        float d0 = fabsf(cutv - p.time_idx[gw * 3 + 0]);
        float d1 = fabsf(cutv - p.time_idx[gw * 3 + 1]);
        float tw0 = expf(-d0 / (stdv + 1e-6f));
        float tw1 = expf(-d1 / (stdv + 1e-6f));
        float s0 = scoreL[tid * 2 + 0] * (0.7f + 0.3f * tw0);
        float s1 = scoreL[tid * 2 + 1] * (0.7f + 0.3f * tw1);
        float m = fmaxf(s0, s1);
        float e0 = expf(s0 - m), e1 = expf(s1 - m);
        float inv = 1.f / (e0 + e1);
        aL[tid * 2 + 0] = e0 * inv;
        aL[tid * 2 + 1] = e1 * inv;
    }
    // xz extra cols (fp16, overlaps phase D; XZL disjoint from H2L)
    for (int q = tid; q < 32 * 72; q += NTH) {
        int r2 = q / 72, c = 128 + q % 72;
        int lw = w0 + r2; if (lw >= p.nw) lw = p.nw - 1;
        int gw = p.win0 + lw;
        XZL[r2 * 200 + c] = (c < 140) ? (_Float16)p.cat[(size_t)gw * 12 + (c - 128)]
                                      : (_Float16)0.f;
    }
    __syncthreads();

    // ---- Phase D: h2 = relu(outf @ at_m1W), outf computed in-stage -> H2L fp16 ----
    {
        int lw = w0 + rr; if (lw >= p.nw) lw = p.nw - 1;
        const _Float16* U2 = p.upd + ((size_t)lw * 3 + 2) * 256;
        f32x4 acc[2][2];
#pragma unroll
        for (int rg = 0; rg < 2; ++rg)
#pragma unroll
            for (int j = 0; j < 2; ++j)
#pragma unroll
                for (int i = 0; i < 4; ++i) acc[rg][j][i] = 0.f;
        for (int kc = 0; kc < 4; ++kc) {
            __syncthreads();
            {
                int k0 = kc * 64 + o * 8;
                float a0 = aL[rr * 2], a1v = aL[rr * 2 + 1];
                f16x8 u8 = *(const f16x8*)&U2[k0];
                f16x8 q0 = *(const f16x8*)&R2h[(rr * 2) * 264 + k0];
                f16x8 q1 = *(const f16x8*)&R2h[(rr * 2 + 1) * 264 + k0];
                float v[8];
#pragma unroll
                for (int e = 0; e < 8; ++e)
                    v[e] = (float)u8[e] + a0 * (float)q0[e] + a1v * (float)q1[e];
                frag_store_hf<2>(AH2[0], rr, o, v);
            }
            __syncthreads();
#pragma unroll
            for (int k2 = 0; k2 < 2; ++k2)
                mfma_step_h<2, 2>(AH2[0], p.M1h, 8, kc * 2 + k2, k2, wv, lane, acc);
        }
        __syncthreads();
#pragma unroll
        for (int j = 0; j < 2; ++j) {
            int col = (wv * 2 + j) * 16 + (lane & 15);
            float b = p.am1b[col];
#pragma unroll
            for (int rg = 0; rg < 2; ++rg)
#pragma unroll
                for (int i = 0; i < 4; ++i) {
                    int row = rg * 16 + ((lane >> 4) << 2) + i;
                    float x = acc[rg][j][i] + b;
                    H2L[row * 136 + col] = (_Float16)(x > 0.f ? x : 0.f);
                }
        }
    }
    __syncthreads();

    // ---- Phase E: h3 = h2 @ at_m2W (direct frag from H2L) -> XZL cols 0..127 ----
    {
        f32x4 acc[2][2];
#pragma unroll
        for (int rg = 0; rg < 2; ++rg)
#pragma unroll
            for (int j = 0; j < 2; ++j)
#pragma unroll
                for (int i = 0; i < 4; ++i) acc[rg][j][i] = 0.f;
#pragma unroll
        for (int ks = 0; ks < 4; ++ks) {
            const int k0 = ks * 32 + ((lane >> 4) << 3);
            f16x8 a4[2];
#pragma unroll
            for (int rg = 0; rg < 2; ++rg)
                a4[rg] = *(const f16x8*)&H2L[(rg * 16 + (lane & 15)) * 136 + k0];
#pragma unroll
            for (int j = 0; j < 2; ++j) {
                size_t boff = ((size_t)((wv * 2 + j) * 4 + ks) * 64 + lane) * 8;
                f16x8 bh = *(const f16x8*)&p.M2h[boff];
#pragma unroll
                for (int rg = 0; rg < 2; ++rg) mma1(a4[rg], bh, acc[rg][j]);
            }
        }
#pragma unroll
        for (int j = 0; j < 2; ++j) {
            int col = (wv * 2 + j) * 16 + (lane & 15);
            float b = p.am2b[col];
#pragma unroll
            for (int rg = 0; rg < 2; ++rg)
#pragma unroll
                for (int i = 0; i < 4; ++i) {
                    int row = rg * 16 + ((lane >> 4) << 2) + i;
                    XZL[row * 200 + col] = (_Float16)(acc[rg][j][i] + b);
                }
        }
    }
    __syncthreads();   // XZL complete; H2L reads done (Z1L may overwrite)

    // ---- Phase F: z1 = relu(xz @ f_W1) (direct frag from XZL) -> Z1L ----
    {
        f32x4 acc[2][3];
#pragma unroll
        for (int rg = 0; rg < 2; ++rg)
#pragma unroll
            for (int j = 0; j < 3; ++j)
#pragma unroll
                for (int i = 0; i < 4; ++i) acc[rg][j][i] = 0.f;
#pragma unroll
        for (int ks = 0; ks < 6; ++ks) {
            const int k0 = ks * 32 + ((lane >> 4) << 3);
            f16x8 a4[2];
#pragma unroll
            for (int rg = 0; rg < 2; ++rg)
                a4[rg] = *(const f16x8*)&XZL[(rg * 16 + (lane & 15)) * 200 + k0];
#pragma unroll
            for (int j = 0; j < 3; ++j) {
                size_t boff = ((size_t)((wv * 3 + j) * 6 + ks) * 64 + lane) * 8;
                f16x8 bh = *(const f16x8*)&p.F1h[boff];
#pragma unroll
                for (int rg = 0; rg < 2; ++rg) mma1(a4[rg], bh, acc[rg][j]);
            }
        }
        __syncthreads();   // all XZL/H2L-region reads done before Z1L write
#pragma unroll
        for (int j = 0; j < 3; ++j) {
            int col = (wv * 3 + j) * 16 + (lane & 15);
            float b = (col < 140) ? p.fb1[col] : 0.f;
#pragma unroll
            for (int rg = 0; rg < 2; ++rg)
#pragma unroll
                for (int i = 0; i < 4; ++i) {
                    int row = rg * 16 + ((lane >> 4) << 2) + i;
                    float x = acc[rg][j][i] + b;
                    Z1L[row * 200 + col] = (_Float16)(x > 0.f ? x : 0.f);
                }
        }
    }
    __syncthreads();

    // ---- Phase G: z2 = relu(z1 @ f_W2) fused with final dot (direct frag) ----
    {
        f32x4 acc[2][2];
#pragma unroll
        for (int rg = 0; rg < 2; ++rg)
#pragma unroll
            for (int j = 0; j < 2; ++j)
#pragma unroll
                for (int i = 0; i < 4; ++i) acc[rg][j][i] = 0.f;
#pragma unroll
        for (int ks = 0; ks < 6; ++ks) {
            const int k0 = ks * 32 + ((lane >> 4) << 3);
            f16x8 a4[2];
#pragma unroll
            for (int rg = 0; rg < 2; ++rg)
                a4[rg] = *(const f16x8*)&Z1L[(rg * 16 + (lane & 15)) * 200 + k0];
#pragma unroll
            for (int j = 0; j < 2; ++j) {
                size_t boff = ((size_t)((wv * 2 + j) * 6 + ks) * 64 + lane) * 8;
                f16x8 bh = *(const f16x8*)&p.F2h[boff];
#pragma unroll
                for (int rg = 0; rg < 2; ++rg) mma1(a4[rg], bh, acc[rg][j]);
            }
        }
        float pt[2][4];
#pragma unroll
        for (int rg = 0; rg < 2; ++rg)
#pragma unroll
            for (int i = 0; i < 4; ++i) pt[rg][i] = 0.f;
#pragma unroll
        for (int j = 0; j < 2; ++j) {
            int col = (wv * 2 + j) * 16 + (lane & 15);
            float b = p.fb2[col];
            float w3 = p.fW3[col];
#pragma unroll
            for (int rg = 0; rg < 2; ++rg)
#pragma unroll
                for (int i = 0; i < 4; ++i) {
                    float x = acc[rg][j][i] + b;
                    x = x > 0.f ? x : 0.f;
                    pt[rg][i] += x * w3;
                }
        }
#pragma unroll
        for (int rg = 0; rg < 2; ++rg)
#pragma unroll
            for (int i = 0; i < 4; ++i) {
                float sv = pt[rg][i];
#pragma unroll
                for (int off = 1; off < 16; off <<= 1) sv += __shfl_xor(sv, off);
                if ((lane & 15) == 0)
                    atomicAdd(&finL[rg * 16 + ((lane >> 4) << 2) + i], sv);
            }
    }
    __syncthreads();
    if (tid < 32 && w0 + tid < p.nw)
        p.out[p.win0 + w0 + tid] = finL[tid] + p.fb3[0];
}

extern "C" void kernel_launch(void* const* d_in, const int* in_sizes, int n_in,
                              void* d_out, int out_size, void* d_ws, size_t ws_size,
                              hipStream_t stream) {
    const float* node_table    = (const float*)d_in[0];
    const float* edge_table    = (const float*)d_in[1];
    const float* basis_freq    = (const float*)d_in[2];
    const float* phase         = (const float*)d_in[3];
    const float* ev_W          = (const float*)d_in[4];
    const float* ev_b          = (const float*)d_in[5];
    const float* ev_m1W        = (const float*)d_in[6];
    const float* ev_m1b        = (const float*)d_in[7];
    const float* ev_m2W        = (const float*)d_in[8];
    const float* ev_m2b        = (const float*)d_in[9];
    const float* at_W1         = (const float*)d_in[10];
    const float* at_b1         = (const float*)d_in[11];
    const float* at_W2         = (const float*)d_in[12];
    const float* at_b2         = (const float*)d_in[13];
    const float* at_m1W        = (const float*)d_in[14];
    const float* at_m1b        = (const float*)d_in[15];
    const float* at_m2W        = (const float*)d_in[16];
    const float* at_m2b        = (const float*)d_in[17];
    const float* f_W1          = (const float*)d_in[18];
    const float* f_b1          = (const float*)d_in[19];
    const float* f_W2          = (const float*)d_in[20];
    const float* f_b2          = (const float*)d_in[21];
    const float* f_W3          = (const float*)d_in[22];
    const float* f_b3          = (const float*)d_in[23];
    const float* time_idx      = (const float*)d_in[24];
    const float* cut_time_l    = (const float*)d_in[25];
    const float* cat_feat      = (const float*)d_in[26];
    const float* edge_identify = (const float*)d_in[27];
    const int*   node_idx      = (const int*)d_in[28];
    const int*   edge_idx      = (const int*)d_in[29];

    char* wsb = (char*)d_ws;
    double* acc = (double*)wsb;

    const int   wkp[9] = {384, 192, 128, 256, 256, 256, 128, 192, 192};
    const int   wnp[9] = {192, 128, 128, 256, 256, 128, 128, 192, 128};
    const int   wkt[9] = {347, 172, 128, 256, 256, 256, 128, 140, 140};
    const int   wnt[9] = {172, 128, 128, 256, 256, 128, 128, 140, 128};
    const float* wsrc[9] = {ev_W, ev_m1W, ev_m2W, at_W1, at_W2, at_m1W, at_m2W, f_W1, f_W2};
    _Float16* wH[9];
    size_t woff = 256;
    WAll wa = {};
    int cum = 0;
    for (int i = 0; i < 9; ++i) {
        size_t plane = (size_t)wkp[i] * wnp[i];
        wH[i] = (_Float16*)(wsb + woff);
        woff += plane * sizeof(_Float16);
        woff = (woff + 15) & ~(size_t)15;
        wa.w[i].src = wsrc[i]; wa.w[i].dH = wH[i];
        wa.w[i].Kt = wkt[i]; wa.w[i].Nt = wnt[i]; wa.w[i].Kp = wkp[i]; wa.w[i].Np = wnp[i];
        wa.w[i].off = cum;
        cum += (wnp[i] / 16) * (wkp[i] / 32) * 64;
    }
    wa.grand = cum;

    hipMemsetAsync(d_ws, 0, 16, stream);
    k_std<<<64, NTH, 0, stream>>>(time_idx, cut_time_l, acc);
    k_wprep_all<<<CDIV(wa.grand, NTH), NTH, 0, stream>>>(wa);

    size_t avail = ws_size > woff + 4096 ? ws_size - woff - 4096 : 0;
    size_t nwc_s = avail / 1536;
    int nwc = (int)(nwc_s > NWIN_TOTAL ? NWIN_TOTAL : nwc_s);
    if (nwc < 1) nwc = 1;
    _Float16* updB = (_Float16*)(wsb + ((woff + 255) & ~(size_t)255));

    for (int c0 = 0; c0 < NWIN_TOTAL; c0 += nwc) {
        int nw = NWIN_TOTAL - c0 < nwc ? NWIN_TOTAL - c0 : nwc;
        int M3 = nw * 3;

        GCP gc = {};
        gc.W0h = wH[0]; gc.W1h = wH[1]; gc.W2h = wH[2];
        gc.b0 = ev_b; gc.b1 = ev_m1b; gc.b2 = ev_m2b;
        gc.upd = updB; gc.M = M3; gc.win0 = c0;
        gc.edge_table = edge_table; gc.node_table = node_table;
        gc.basis_freq = basis_freq; gc.phase = phase;
        gc.time_idx = time_idx; gc.cut = cut_time_l;
        gc.edge_idx = edge_idx; gc.node_idx = node_idx; gc.eid = edge_identify;
        k_gc<<<CDIV(M3, 32), NTH, 0, stream>>>(gc);

        AttnP ap = {};
        ap.upd = updB;
        ap.W1h = wH[3]; ap.W2h = wH[4];
        ap.M1h = wH[5]; ap.M2h = wH[6];
        ap.F1h = wH[7]; ap.F2h = wH[8];
        ap.ab1 = at_b1; ap.ab2 = at_b2; ap.am1b = at_m1b; ap.am2b = at_m2b;
        ap.fb1 = f_b1; ap.fb2 = f_b2; ap.fW3 = f_W3; ap.fb3 = f_b3;
        ap.time_idx = time_idx; ap.cut = cut_time_l; ap.cat = cat_feat; ap.acc = acc;
        ap.out = (float*)d_out; ap.nw = nw; ap.win0 = c0;
        k_attn<<<CDIV(nw, 32), NTH, 0, stream>>>(ap);
    }
}